// Round 1
// baseline (364.648 us; speedup 1.0000x reference)
//
#include <hip/hip_runtime.h>

typedef unsigned short u16;
typedef float f32x4 __attribute__((ext_vector_type(4)));
typedef __bf16 bf16x8 __attribute__((ext_vector_type(8)));
typedef unsigned short u16x8 __attribute__((ext_vector_type(8)));
typedef unsigned short u16x4 __attribute__((ext_vector_type(4)));

#define S_ 2048
#define DM 1024

__device__ __forceinline__ u16 f2bf(float f) {
    unsigned int u = __float_as_uint(f);
    u += 0x7fffu + ((u >> 16) & 1u);
    return (u16)(u >> 16);
}
__device__ __forceinline__ float bf2f(u16 s) {
    return __uint_as_float(((unsigned int)s) << 16);
}

// ---------------- f32 -> bf16 convert ----------------
__global__ __launch_bounds__(256) void f32_to_bf16_kernel(const float* __restrict__ in,
                                                          u16* __restrict__ o, int n) {
    int i = (blockIdx.x * 256 + threadIdx.x) << 2;
    if (i >= n) return;
    float4 f = *(const float4*)&in[i];
    u16x4 r;
    r[0] = f2bf(f.x); r[1] = f2bf(f.y); r[2] = f2bf(f.z); r[3] = f2bf(f.w);
    *(u16x4*)&o[i] = r;
}

// ---------------- W [K][N] f32 -> Wt [N][K] bf16 ----------------
__global__ __launch_bounds__(256) void transpose_w(const float* __restrict__ W,
                                                   u16* __restrict__ Wt, int K, int N) {
    __shared__ float tile[32][33];
    int nb = blockIdx.x << 5, kb = blockIdx.y << 5;
    int tx = threadIdx.x & 31, ty = threadIdx.x >> 5;
#pragma unroll
    for (int r = 0; r < 32; r += 8)
        tile[ty + r][tx] = W[(size_t)(kb + ty + r) * N + nb + tx];
    __syncthreads();
#pragma unroll
    for (int r = 0; r < 32; r += 8)
        Wt[(size_t)(nb + ty + r) * K + kb + tx] = f2bf(tile[tx][ty + r]);
}

// ---------------- GEMM: C[M][N] = A[M][K](bf16) @ Bt[N][K](bf16)^T ----------------
// MODE 0: scatter-epilogue to q,k,v  [bh][s][64] bf16.  MODE 1: fp32 C out.
template <int MODE>
__global__ __launch_bounds__(256) void gemm_bt(const u16* __restrict__ A,
                                               const u16* __restrict__ Bt,
                                               float* __restrict__ Cf,
                                               u16* __restrict__ Qp, u16* __restrict__ Kp,
                                               u16* __restrict__ Vp,
                                               int M, int N, int K) {
    __shared__ __align__(16) u16 Al[128][40];  // pad: stride 80B = 5*16B, conflict-free frag reads
    __shared__ __align__(16) u16 Bl[128][40];
    const int tid = threadIdx.x;
    const int Ntiles = N >> 7;
    const int mt = blockIdx.x / Ntiles, nt = blockIdx.x % Ntiles;
    const int m0 = mt << 7, n0 = nt << 7;
    const int wave = tid >> 6, lane = tid & 63;
    const int wm = (wave >> 1) << 6, wn = (wave & 1) << 6;
    const int lr = lane & 15, lk = (lane >> 4) << 3;
    const int srow = tid >> 2, scol = (tid & 3) << 3;

    f32x4 acc[4][4] = {};

    for (int k0 = 0; k0 < K; k0 += 32) {
        __syncthreads();
#pragma unroll
        for (int r = 0; r < 2; ++r) {
            int row = srow + (r << 6);
            *(u16x8*)&Al[row][scol] = *(const u16x8*)&A[(size_t)(m0 + row) * K + k0 + scol];
            *(u16x8*)&Bl[row][scol] = *(const u16x8*)&Bt[(size_t)(n0 + row) * K + k0 + scol];
        }
        __syncthreads();
        bf16x8 af[4], bfr[4];
#pragma unroll
        for (int i = 0; i < 4; ++i) {
            af[i]  = __builtin_bit_cast(bf16x8, *(const u16x8*)&Al[wm + (i << 4) + lr][lk]);
            bfr[i] = __builtin_bit_cast(bf16x8, *(const u16x8*)&Bl[wn + (i << 4) + lr][lk]);
        }
#pragma unroll
        for (int i = 0; i < 4; ++i)
#pragma unroll
            for (int j = 0; j < 4; ++j)
                acc[i][j] = __builtin_amdgcn_mfma_f32_16x16x32_bf16(af[i], bfr[j], acc[i][j], 0, 0, 0);
    }

#pragma unroll
    for (int i = 0; i < 4; ++i) {
#pragma unroll
        for (int j = 0; j < 4; ++j) {
            int rbase = m0 + wm + (i << 4) + ((lane >> 4) << 2);
            int col = n0 + wn + (j << 4) + lr;
#pragma unroll
            for (int jj = 0; jj < 4; ++jj) {
                float val = acc[i][j][jj];
                int row = rbase + jj;
                if (MODE == 0) {
                    int t = col >> 10, rem = col & 1023;
                    int h = rem >> 6, d = rem & 63;
                    int b = row >> 11, s = row & 2047;
                    size_t dst = ((size_t)((b << 4) + h) * S_ + s) * 64 + d;
                    u16 bv = f2bf(val);
                    if (t == 0) Qp[dst] = bv;
                    else if (t == 1) Kp[dst] = bv;
                    else Vp[dst] = bv;
                } else {
                    Cf[(size_t)row * N + col] = val;
                }
            }
        }
    }
}

// ---------------- RoPE in-place on q,k  [bh][s][64] bf16 ----------------
__global__ __launch_bounds__(256) void rope_kernel(u16* __restrict__ q, u16* __restrict__ k) {
    int idx = blockIdx.x * 256 + threadIdx.x;  // (bh*2048+s)*32 + j
    int j = idx & 31;
    int row = idx >> 5;
    int s = row & (S_ - 1);
    float invf = expf(-(float)j * (9.210340371976184f / 32.0f));  // 10000^(-j/32)
    float ang = (float)s * invf;
    float c = cosf(ang), sn = sinf(ang);
    size_t base = (size_t)row * 64;
    float q0 = bf2f(q[base + j]), q1 = bf2f(q[base + j + 32]);
    q[base + j]      = f2bf(q0 * c - q1 * sn);
    q[base + j + 32] = f2bf(q1 * c + q0 * sn);
    float k0 = bf2f(k[base + j]), k1 = bf2f(k[base + j + 32]);
    k[base + j]      = f2bf(k0 * c - k1 * sn);
    k[base + j + 32] = f2bf(k1 * c + k0 * sn);
}

// ---------------- flash attention: 64 q-rows/block (16/wave), KV tiles of 64 ----------------
__global__ __launch_bounds__(256) void attn_kernel(const u16* __restrict__ q,
                                                   const u16* __restrict__ k,
                                                   const u16* __restrict__ v,
                                                   const float* __restrict__ mask,
                                                   u16* __restrict__ outp) {
    __shared__ __align__(16) u16 Kl[64][72];      // row-major, stride 144B -> frag reads 2-way (free)
    __shared__ __align__(16) u16 Vt[64][72];      // transposed: Vt[d][kv]
    __shared__ __align__(16) u16 Pl[4][16][72];   // per-wave P round-trip
    __shared__ float madd[64];
    const int tid = threadIdx.x, wave = tid >> 6, lane = tid & 63;
    const int bh = blockIdx.x >> 5, qb = blockIdx.x & 31;  // consecutive blocks share bh -> L2 reuse
    const int b = bh >> 4, h = bh & 15;
    const size_t base = (size_t)bh * S_ * 64;
    const int q0 = (qb << 6) + (wave << 4);
    const int lr = lane & 15, lk = (lane >> 4) << 3;

    bf16x8 qf[2];
#pragma unroll
    for (int kk = 0; kk < 2; ++kk)
        qf[kk] = __builtin_bit_cast(bf16x8,
                 *(const u16x8*)&q[base + (size_t)(q0 + lr) * 64 + kk * 32 + lk]);

    f32x4 acc[4] = {};
    float mr[4] = {-1e30f, -1e30f, -1e30f, -1e30f};
    float lsum_[4] = {};

    const int ksr = tid >> 3, ksc = (tid & 7) << 3;  // K staging
    const int vd = tid & 63, vrc = (tid >> 6) << 4;  // V staging (per-lane column gather)

    for (int kv0 = 0; kv0 < S_; kv0 += 64) {
        __syncthreads();
#pragma unroll
        for (int it = 0; it < 2; ++it) {
            int r = ksr + it * 32;
            *(u16x8*)&Kl[r][ksc] = *(const u16x8*)&k[base + (size_t)(kv0 + r) * 64 + ksc];
        }
        // V transposed: lane owns column d=vd, 16 kv rows; global reads coalesced per kv row
        u16x8 v0, v1;
#pragma unroll
        for (int i = 0; i < 8; ++i)
            v0[i] = v[base + (size_t)(kv0 + vrc + i) * 64 + vd];
#pragma unroll
        for (int i = 0; i < 8; ++i)
            v1[i] = v[base + (size_t)(kv0 + vrc + 8 + i) * 64 + vd];
        *(u16x8*)&Vt[vd][vrc] = v0;
        *(u16x8*)&Vt[vd][vrc + 8] = v1;
        if (tid < 64) madd[tid] = (1.0f - mask[b * S_ + kv0 + tid]) * -1e9f;
        __syncthreads();

        // S = Q K^T
        f32x4 sfr[4] = {};
#pragma unroll
        for (int fc = 0; fc < 4; ++fc)
#pragma unroll
            for (int kk = 0; kk < 2; ++kk) {
                bf16x8 kf = __builtin_bit_cast(bf16x8,
                            *(const u16x8*)&Kl[(fc << 4) + lr][kk * 32 + lk]);
                sfr[fc] = __builtin_amdgcn_mfma_f32_16x16x32_bf16(qf[kk], kf, sfr[fc], 0, 0, 0);
            }
        float ma[4];
#pragma unroll
        for (int fc = 0; fc < 4; ++fc) ma[fc] = madd[(fc << 4) + lr];

        // online softmax, rows (lane>>4)*4+j, cols fc*16+lr
#pragma unroll
        for (int j = 0; j < 4; ++j) {
            float sv[4];
            float tm = -1e30f;
#pragma unroll
            for (int fc = 0; fc < 4; ++fc) {
                sv[fc] = sfr[fc][j] * 0.125f + ma[fc];
                tm = fmaxf(tm, sv[fc]);
            }
#pragma unroll
            for (int off = 1; off < 16; off <<= 1) tm = fmaxf(tm, __shfl_xor(tm, off));
            float mnew = fmaxf(mr[j], tm);
            float alpha = __expf(mr[j] - mnew);
            float ls = 0.f;
#pragma unroll
            for (int fc = 0; fc < 4; ++fc) {
                float p = __expf(sv[fc] - mnew);
                ls += p;
                Pl[wave][((lane >> 4) << 2) + j][(fc << 4) + lr] = f2bf(p);
            }
#pragma unroll
            for (int off = 1; off < 16; off <<= 1) ls += __shfl_xor(ls, off);
            lsum_[j] = lsum_[j] * alpha + ls;
            mr[j] = mnew;
#pragma unroll
            for (int fc = 0; fc < 4; ++fc) acc[fc][j] *= alpha;
        }
        // O += P V
#pragma unroll
        for (int kk = 0; kk < 2; ++kk) {
            bf16x8 pf = __builtin_bit_cast(bf16x8,
                        *(const u16x8*)&Pl[wave][lr][kk * 32 + lk]);
#pragma unroll
            for (int fc = 0; fc < 4; ++fc) {
                bf16x8 vf = __builtin_bit_cast(bf16x8,
                            *(const u16x8*)&Vt[(fc << 4) + lr][kk * 32 + lk]);
                acc[fc] = __builtin_amdgcn_mfma_f32_16x16x32_bf16(pf, vf, acc[fc], 0, 0, 0);
            }
        }
    }

    // epilogue -> [b][s][h*64+d] bf16
#pragma unroll
    for (int fc = 0; fc < 4; ++fc)
#pragma unroll
        for (int j = 0; j < 4; ++j) {
            int qr = q0 + ((lane >> 4) << 2) + j;
            int d = (fc << 4) + lr;
            float val = acc[fc][j] / lsum_[j];
            outp[((size_t)(b * S_ + qr)) * DM + h * 64 + d] = f2bf(val);
        }
}

extern "C" void kernel_launch(void* const* d_in, const int* in_sizes, int n_in,
                              void* d_out, int out_size, void* d_ws, size_t ws_size,
                              hipStream_t stream) {
    const float* x    = (const float*)d_in[0];
    const float* mask = (const float*)d_in[1];
    const float* Wqkv = (const float*)d_in[2];
    const float* Wout = (const float*)d_in[3];
    float* out = (float*)d_out;
    char* ws = (char*)d_ws;
    const size_t MB = 1u << 20;
    u16* xb    = (u16*)(ws);            // 16 MB: x bf16 [8192][1024]
    u16* WqkvT = (u16*)(ws + 16 * MB);  // 6 MB: [3072][1024]
    u16* WoutT = (u16*)(ws + 22 * MB);  // 2 MB: [1024][1024]
    u16* qb    = (u16*)(ws + 24 * MB);  // 16 MB each, [bh=64][2048][64]
    u16* kb    = (u16*)(ws + 40 * MB);
    u16* vb    = (u16*)(ws + 56 * MB);  // ends at 72 MB
    u16* ao    = xb;                    // attention out aliases xb (xb dead after GEMM1)

    f32_to_bf16_kernel<<<8192, 256, 0, stream>>>(x, xb, 8192 * 1024);
    transpose_w<<<dim3(96, 32), 256, 0, stream>>>(Wqkv, WqkvT, 1024, 3072);
    transpose_w<<<dim3(32, 32), 256, 0, stream>>>(Wout, WoutT, 1024, 1024);
    gemm_bt<0><<<64 * 24, 256, 0, stream>>>(xb, WqkvT, nullptr, qb, kb, vb, 8192, 3072, 1024);
    rope_kernel<<<16384, 256, 0, stream>>>(qb, kb);
    attn_kernel<<<2048, 256, 0, stream>>>(qb, kb, vb, mask, ao);
    gemm_bt<1><<<64 * 8, 256, 0, stream>>>(ao, WoutT, out, nullptr, nullptr, nullptr, 8192, 1024, 1024);
}

// Round 2
// 295.399 us; speedup vs baseline: 1.2344x; 1.2344x over previous
//
#include <hip/hip_runtime.h>

typedef unsigned short u16;
typedef unsigned int u32;
typedef float f32x4 __attribute__((ext_vector_type(4)));
typedef float f32x16 __attribute__((ext_vector_type(16)));
typedef __bf16 bf16x8 __attribute__((ext_vector_type(8)));
typedef unsigned short u16x8 __attribute__((ext_vector_type(8)));
typedef unsigned short u16x4 __attribute__((ext_vector_type(4)));
typedef unsigned int u32x4 __attribute__((ext_vector_type(4)));

#define S_ 2048
#define DM 1024

__device__ __forceinline__ u16 f2bf(float f) {
    unsigned int u = __float_as_uint(f);
    u += 0x7fffu + ((u >> 16) & 1u);
    return (u16)(u >> 16);
}
__device__ __forceinline__ float bf2f(u16 s) {
    return __uint_as_float(((unsigned int)s) << 16);
}

// ---------------- f32 -> bf16 convert ----------------
__global__ __launch_bounds__(256) void f32_to_bf16_kernel(const float* __restrict__ in,
                                                          u16* __restrict__ o, int n) {
    int i = (blockIdx.x * 256 + threadIdx.x) << 2;
    if (i >= n) return;
    float4 f = *(const float4*)&in[i];
    u16x4 r;
    r[0] = f2bf(f.x); r[1] = f2bf(f.y); r[2] = f2bf(f.z); r[3] = f2bf(f.w);
    *(u16x4*)&o[i] = r;
}

// ---------------- W [K][N] f32 -> Wt [N][K] bf16 ----------------
__global__ __launch_bounds__(256) void transpose_w(const float* __restrict__ W,
                                                   u16* __restrict__ Wt, int K, int N) {
    __shared__ float tile[32][33];
    int nb = blockIdx.x << 5, kb = blockIdx.y << 5;
    int tx = threadIdx.x & 31, ty = threadIdx.x >> 5;
#pragma unroll
    for (int r = 0; r < 32; r += 8)
        tile[ty + r][tx] = W[(size_t)(kb + ty + r) * N + nb + tx];
    __syncthreads();
#pragma unroll
    for (int r = 0; r < 32; r += 8)
        Wt[(size_t)(nb + ty + r) * K + kb + tx] = f2bf(tile[tx][ty + r]);
}

// ---------------- GEMM: C[M][N] = A[M][K](bf16) @ Bt[N][K](bf16)^T ----------------
template <int MODE>
__global__ __launch_bounds__(256) void gemm_bt(const u16* __restrict__ A,
                                               const u16* __restrict__ Bt,
                                               float* __restrict__ Cf,
                                               u16* __restrict__ Qp, u16* __restrict__ Kp,
                                               u16* __restrict__ Vp,
                                               int M, int N, int K) {
    __shared__ __align__(16) u16 Al[128][40];
    __shared__ __align__(16) u16 Bl[128][40];
    const int tid = threadIdx.x;
    const int Ntiles = N >> 7;
    const int mt = blockIdx.x / Ntiles, nt = blockIdx.x % Ntiles;
    const int m0 = mt << 7, n0 = nt << 7;
    const int wave = tid >> 6, lane = tid & 63;
    const int wm = (wave >> 1) << 6, wn = (wave & 1) << 6;
    const int lr = lane & 15, lk = (lane >> 4) << 3;
    const int srow = tid >> 2, scol = (tid & 3) << 3;

    f32x4 acc[4][4] = {};

    for (int k0 = 0; k0 < K; k0 += 32) {
        __syncthreads();
#pragma unroll
        for (int r = 0; r < 2; ++r) {
            int row = srow + (r << 6);
            *(u16x8*)&Al[row][scol] = *(const u16x8*)&A[(size_t)(m0 + row) * K + k0 + scol];
            *(u16x8*)&Bl[row][scol] = *(const u16x8*)&Bt[(size_t)(n0 + row) * K + k0 + scol];
        }
        __syncthreads();
        bf16x8 af[4], bfr[4];
#pragma unroll
        for (int i = 0; i < 4; ++i) {
            af[i]  = __builtin_bit_cast(bf16x8, *(const u16x8*)&Al[wm + (i << 4) + lr][lk]);
            bfr[i] = __builtin_bit_cast(bf16x8, *(const u16x8*)&Bl[wn + (i << 4) + lr][lk]);
        }
#pragma unroll
        for (int i = 0; i < 4; ++i)
#pragma unroll
            for (int j = 0; j < 4; ++j)
                acc[i][j] = __builtin_amdgcn_mfma_f32_16x16x32_bf16(af[i], bfr[j], acc[i][j], 0, 0, 0);
    }

#pragma unroll
    for (int i = 0; i < 4; ++i) {
#pragma unroll
        for (int j = 0; j < 4; ++j) {
            int rbase = m0 + wm + (i << 4) + ((lane >> 4) << 2);
            int col = n0 + wn + (j << 4) + lr;
#pragma unroll
            for (int jj = 0; jj < 4; ++jj) {
                float val = acc[i][j][jj];
                int row = rbase + jj;
                if (MODE == 0) {
                    int t = col >> 10, rem = col & 1023;
                    int h = rem >> 6, d = rem & 63;
                    int b = row >> 11, s = row & 2047;
                    size_t dst = ((size_t)((b << 4) + h) * S_ + s) * 64 + d;
                    u16 bv = f2bf(val);
                    if (t == 0) Qp[dst] = bv;
                    else if (t == 1) Kp[dst] = bv;
                    else Vp[dst] = bv;
                } else {
                    Cf[(size_t)row * N + col] = val;
                }
            }
        }
    }
}

// ---------------- RoPE in-place on q,k  [bh][s][64] bf16 ----------------
__global__ __launch_bounds__(256) void rope_kernel(u16* __restrict__ q, u16* __restrict__ k) {
    int idx = blockIdx.x * 256 + threadIdx.x;
    int j = idx & 31;
    int row = idx >> 5;
    int s = row & (S_ - 1);
    float invf = expf(-(float)j * (9.210340371976184f / 32.0f));
    float ang = (float)s * invf;
    float c = cosf(ang), sn = sinf(ang);
    size_t base = (size_t)row * 64;
    float q0 = bf2f(q[base + j]), q1 = bf2f(q[base + j + 32]);
    q[base + j]      = f2bf(q0 * c - q1 * sn);
    q[base + j + 32] = f2bf(q1 * c + q0 * sn);
    float k0 = bf2f(k[base + j]), k1 = bf2f(k[base + j + 32]);
    k[base + j]      = f2bf(k0 * c - k1 * sn);
    k[base + j + 32] = f2bf(k1 * c + k0 * sn);
}

// ---------------- V [bh][s][64] -> Vt [bh][64][s]  (bf16 tiled transpose) ----------------
__global__ __launch_bounds__(256) void vtrans_kernel(const u16* __restrict__ v,
                                                     u16* __restrict__ vt) {
    __shared__ __align__(16) u16 t[64][72];
    const int bh = blockIdx.x >> 5, st = blockIdx.x & 31;
    const size_t base = (size_t)bh * (S_ * 64);
    const int s0 = st << 6;
    const int r = threadIdx.x >> 2, c0 = (threadIdx.x & 3) << 4;
    *(u16x8*)&t[r][c0]     = *(const u16x8*)&v[base + (size_t)(s0 + r) * 64 + c0];
    *(u16x8*)&t[r][c0 + 8] = *(const u16x8*)&v[base + (size_t)(s0 + r) * 64 + c0 + 8];
    __syncthreads();
    u16x8 w0, w1;
#pragma unroll
    for (int i = 0; i < 8; ++i) w0[i] = t[c0 + i][r];
#pragma unroll
    for (int i = 0; i < 8; ++i) w1[i] = t[c0 + 8 + i][r];
    *(u16x8*)&vt[base + (size_t)r * S_ + s0 + c0]     = w0;
    *(u16x8*)&vt[base + (size_t)r * S_ + s0 + c0 + 8] = w1;
}

// ---------------- flash attention: 4 waves x 32 q-rows, swapped QK^T, KVBLK=64 ----------------
// grid: bh = blockIdx&63 (XCD-local KV), qt = blockIdx>>6 (16 q-tiles of 128 rows)
__global__ __launch_bounds__(256) void attn_kernel(const u16* __restrict__ q,
                                                   const u16* __restrict__ k,
                                                   const u16* __restrict__ vt,
                                                   const float* __restrict__ mask,
                                                   u16* __restrict__ outp) {
    __shared__ __align__(16) u16 Kl[64 * 64];     // [kv][d], 16B-unit XOR swizzle
    __shared__ __align__(16) u16 Vl[64 * 64];     // [d][kv], 16B-unit XOR swizzle
    __shared__ __align__(16) float madd2[64];     // mask add, log2 domain
    __shared__ __align__(16) float bcast[4][32];  // per-wave alpha / l broadcast

    const int tid = threadIdx.x, wave = tid >> 6, lane = tid & 63;
    const int c = lane & 31, hi = lane >> 5, c7 = c & 7;
    const int bh = blockIdx.x & 63, qt = blockIdx.x >> 6;
    const int b = bh >> 4, h = bh & 15;
    const size_t base = (size_t)bh * (S_ * 64);
    const int qrow = (qt << 7) + (wave << 5) + c;

    const float QS = 0.18033688f;  // 0.125 * log2(e): softmax in exp2 domain

    // Q fragments (B-operand of swapped QK^T), prescaled
    bf16x8 qf[4];
#pragma unroll
    for (int j = 0; j < 4; ++j) {
        u16x8 raw = *(const u16x8*)&q[base + (size_t)qrow * 64 + j * 16 + hi * 8];
        u16x8 sc;
#pragma unroll
        for (int e = 0; e < 8; ++e) sc[e] = f2bf(bf2f(raw[e]) * QS);
        qf[j] = __builtin_bit_cast(bf16x8, sc);
    }

    f32x16 acc[2] = {};                 // O[q 32][d 64], dt tiles
    float m_run = -1e30f, l_run = 0.f;  // per-lane (per-q) running max/sum

    const int sr = tid >> 2, su = (tid & 3) << 1;           // staging row / 16B-unit
    const int so0 = sr * 64 + ((su ^ (sr & 7)) << 3);       // swizzled LDS elem offsets
    const int so1 = sr * 64 + (((su + 1) ^ (sr & 7)) << 3);

    for (int kv0 = 0; kv0 < S_; kv0 += 64) {
        // issue global loads before the barrier (latency hides under it)
        u16x8 kc0 = *(const u16x8*)&k[base + (size_t)(kv0 + sr) * 64 + su * 8];
        u16x8 kc1 = *(const u16x8*)&k[base + (size_t)(kv0 + sr) * 64 + su * 8 + 8];
        u16x8 vc0 = *(const u16x8*)&vt[base + (size_t)sr * S_ + kv0 + su * 8];
        u16x8 vc1 = *(const u16x8*)&vt[base + (size_t)sr * S_ + kv0 + su * 8 + 8];
        float mval = (tid < 64) ? mask[b * S_ + kv0 + tid] : 1.0f;
        __syncthreads();  // all waves done reading previous tile
        *(u16x8*)&Kl[so0] = kc0;
        *(u16x8*)&Kl[so1] = kc1;
        *(u16x8*)&Vl[so0] = vc0;
        *(u16x8*)&Vl[so1] = vc1;
        if (tid < 64) madd2[tid] = (1.0f - mval) * -1.44269504e9f;
        __syncthreads();  // tile ready

        // S^T = K * Q^T : p[t] holds P^T[kv 32t..][q=c], rows spread over regs
        f32x16 p[2] = {};
#pragma unroll
        for (int j = 0; j < 4; ++j) {
            const int uo = ((2 * j + hi) ^ c7) << 3;
            bf16x8 ka  = __builtin_bit_cast(bf16x8, *(const u16x8*)&Kl[c * 64 + uo]);
            bf16x8 kb2 = __builtin_bit_cast(bf16x8, *(const u16x8*)&Kl[(32 + c) * 64 + uo]);
            p[0] = __builtin_amdgcn_mfma_f32_32x32x16_bf16(ka,  qf[j], p[0], 0, 0, 0);
            p[1] = __builtin_amdgcn_mfma_f32_32x32x16_bf16(kb2, qf[j], p[1], 0, 0, 0);
        }

        // mask add (kv = 32t + 8rq + 4hi + i)
#pragma unroll
        for (int t = 0; t < 2; ++t)
#pragma unroll
            for (int rq = 0; rq < 4; ++rq) {
                float4 mf = *(const float4*)&madd2[t * 32 + rq * 8 + hi * 4];
                p[t][4 * rq + 0] += mf.x;
                p[t][4 * rq + 1] += mf.y;
                p[t][4 * rq + 2] += mf.z;
                p[t][4 * rq + 3] += mf.w;
            }

        // online softmax: in-lane reduce + single cross-32 shuffle
        float mx = p[0][0];
#pragma unroll
        for (int r = 1; r < 16; ++r) mx = fmaxf(mx, p[0][r]);
#pragma unroll
        for (int r = 0; r < 16; ++r) mx = fmaxf(mx, p[1][r]);
        mx = fmaxf(mx, __shfl_xor(mx, 32));
        float mnew = fmaxf(m_run, mx);
        float alpha = __builtin_exp2f(m_run - mnew);
        m_run = mnew;

        float ls = 0.f;
#pragma unroll
        for (int t = 0; t < 2; ++t)
#pragma unroll
            for (int r = 0; r < 16; ++r) {
                float e = __builtin_exp2f(p[t][r] - mnew);
                p[t][r] = e;
                ls += e;
            }
        ls += __shfl_xor(ls, 32);
        l_run = l_run * alpha + ls;

        // rescale O by alpha[q-row] (broadcast per-lane alpha -> per-reg rows)
        bcast[wave][c] = alpha;
        float avf[16];
#pragma unroll
        for (int rq = 0; rq < 4; ++rq) {
            float4 t4 = *(const float4*)&bcast[wave][rq * 8 + hi * 4];
            avf[4 * rq + 0] = t4.x; avf[4 * rq + 1] = t4.y;
            avf[4 * rq + 2] = t4.z; avf[4 * rq + 3] = t4.w;
        }
#pragma unroll
        for (int r = 0; r < 16; ++r) {
            acc[0][r] *= avf[r];
            acc[1][r] *= avf[r];
        }

        // P -> bf16 A-fragments: cvt_pk pairs, exchange halves with lane^32
        u32 wa[8], wb[8];
#pragma unroll
        for (int t = 0; t < 2; ++t)
#pragma unroll
            for (int rq = 0; rq < 4; ++rq) {
                float e0 = p[t][4 * rq + 0], e1 = p[t][4 * rq + 1];
                float e2 = p[t][4 * rq + 2], e3 = p[t][4 * rq + 3];
                u32 w0, w1;
                asm("v_cvt_pk_bf16_f32 %0, %1, %2" : "=v"(w0) : "v"(e0), "v"(e1));
                asm("v_cvt_pk_bf16_f32 %0, %1, %2" : "=v"(w1) : "v"(e2), "v"(e3));
                wa[4 * t + rq] = w0;
                wb[4 * t + rq] = w1;
            }

        // O += P * V
#pragma unroll
        for (int ks = 0; ks < 4; ++ks) {
            u32 a0 = wa[2 * ks], a1 = wa[2 * ks + 1];
            u32 b0 = wb[2 * ks], b1 = wb[2 * ks + 1];
            u32 a0s = (u32)__shfl_xor((int)a0, 32);
            u32 a1s = (u32)__shfl_xor((int)a1, 32);
            u32 b0s = (u32)__shfl_xor((int)b0, 32);
            u32 b1s = (u32)__shfl_xor((int)b1, 32);
            u32x4 pw;
            pw[0] = hi ? a1s : a0;   // kv 16ks+8hi+{0,1}
            pw[1] = hi ? b1s : b0;   // +{2,3}
            pw[2] = hi ? a1 : a0s;   // +{4,5}
            pw[3] = hi ? b1 : b0s;   // +{6,7}
            bf16x8 paf = __builtin_bit_cast(bf16x8, pw);
            const int uo = ((2 * ks + hi) ^ c7) << 3;
#pragma unroll
            for (int dt = 0; dt < 2; ++dt) {
                bf16x8 vf = __builtin_bit_cast(bf16x8,
                            *(const u16x8*)&Vl[(32 * dt + c) * 64 + uo]);
                acc[dt] = __builtin_amdgcn_mfma_f32_32x32x16_bf16(paf, vf, acc[dt], 0, 0, 0);
            }
        }
    }

    // epilogue: divide by l[q-row], write [b][s][h*64+d]
    bcast[wave][c] = l_run;
    float lvf[16];
#pragma unroll
    for (int rq = 0; rq < 4; ++rq) {
        float4 t4 = *(const float4*)&bcast[wave][rq * 8 + hi * 4];
        lvf[4 * rq + 0] = __builtin_amdgcn_rcpf(t4.x);
        lvf[4 * rq + 1] = __builtin_amdgcn_rcpf(t4.y);
        lvf[4 * rq + 2] = __builtin_amdgcn_rcpf(t4.z);
        lvf[4 * rq + 3] = __builtin_amdgcn_rcpf(t4.w);
    }
    const size_t orow0 = (size_t)b * S_ + (qt << 7) + (wave << 5);
#pragma unroll
    for (int dt = 0; dt < 2; ++dt)
#pragma unroll
        for (int r = 0; r < 16; ++r) {
            int qr = (r & 3) + 8 * (r >> 2) + 4 * hi;
            outp[(orow0 + qr) * DM + h * 64 + dt * 32 + c] = f2bf(acc[dt][r] * lvf[r]);
        }
}

extern "C" void kernel_launch(void* const* d_in, const int* in_sizes, int n_in,
                              void* d_out, int out_size, void* d_ws, size_t ws_size,
                              hipStream_t stream) {
    const float* x    = (const float*)d_in[0];
    const float* mask = (const float*)d_in[1];
    const float* Wqkv = (const float*)d_in[2];
    const float* Wout = (const float*)d_in[3];
    float* out = (float*)d_out;
    char* ws = (char*)d_ws;
    const size_t MB = 1u << 20;
    u16* xb    = (u16*)(ws);            // 16 MB: x bf16; later reused as Vt
    u16* WqkvT = (u16*)(ws + 16 * MB);  // 6 MB
    u16* WoutT = (u16*)(ws + 22 * MB);  // 2 MB
    u16* qb    = (u16*)(ws + 24 * MB);  // 16 MB [bh][s][64]
    u16* kb    = (u16*)(ws + 40 * MB);  // 16 MB [bh][s][64]
    u16* vb    = (u16*)(ws + 56 * MB);  // 16 MB [bh][s][64]; later reused as attn-out
    u16* vtb   = xb;                    // Vt [bh][64][s] (xb dead after GEMM1)
    u16* ao    = vb;                    // attention out (v dead after vtrans)

    f32_to_bf16_kernel<<<8192, 256, 0, stream>>>(x, xb, 8192 * 1024);
    transpose_w<<<dim3(96, 32), 256, 0, stream>>>(Wqkv, WqkvT, 1024, 3072);
    transpose_w<<<dim3(32, 32), 256, 0, stream>>>(Wout, WoutT, 1024, 1024);
    gemm_bt<0><<<64 * 24, 256, 0, stream>>>(xb, WqkvT, nullptr, qb, kb, vb, 8192, 3072, 1024);
    rope_kernel<<<16384, 256, 0, stream>>>(qb, kb);
    vtrans_kernel<<<2048, 256, 0, stream>>>(vb, vtb);
    attn_kernel<<<1024, 256, 0, stream>>>(qb, kb, vtb, mask, ao);
    gemm_bt<1><<<64 * 8, 256, 0, stream>>>(ao, WoutT, out, nullptr, nullptr, nullptr, 8192, 1024, 1024);
}

// Round 3
// 280.180 us; speedup vs baseline: 1.3015x; 1.0543x over previous
//
#include <hip/hip_runtime.h>

typedef unsigned short u16;
typedef unsigned int u32;
typedef int i32x2 __attribute__((ext_vector_type(2)));
typedef float f32x4 __attribute__((ext_vector_type(4)));
typedef float f32x16 __attribute__((ext_vector_type(16)));
typedef __bf16 bf16x8 __attribute__((ext_vector_type(8)));
typedef unsigned short u16x8 __attribute__((ext_vector_type(8)));
typedef unsigned short u16x4 __attribute__((ext_vector_type(4)));
typedef unsigned int u32x4 __attribute__((ext_vector_type(4)));

#define S_ 2048
#define DM 1024

#define LDS_U32(p) ((__attribute__((address_space(3))) unsigned int*)(p))
#define GLB_U32(p) ((const __attribute__((address_space(1))) unsigned int*)(p))

__device__ __forceinline__ u16 f2bf(float f) {
    unsigned int u = __float_as_uint(f);
    u += 0x7fffu + ((u >> 16) & 1u);
    return (u16)(u >> 16);
}
__device__ __forceinline__ float bf2f(u16 s) {
    return __uint_as_float(((unsigned int)s) << 16);
}

// ---------------- f32 -> bf16 convert ----------------
__global__ __launch_bounds__(256) void f32_to_bf16_kernel(const float* __restrict__ in,
                                                          u16* __restrict__ o, int n) {
    int i = (blockIdx.x * 256 + threadIdx.x) << 2;
    if (i >= n) return;
    float4 f = *(const float4*)&in[i];
    u16x4 r;
    r[0] = f2bf(f.x); r[1] = f2bf(f.y); r[2] = f2bf(f.z); r[3] = f2bf(f.w);
    *(u16x4*)&o[i] = r;
}

// ---------------- W [K][N] f32 -> Wt [N][K] bf16 ----------------
__global__ __launch_bounds__(256) void transpose_w(const float* __restrict__ W,
                                                   u16* __restrict__ Wt, int K, int N) {
    __shared__ float tile[32][33];
    int nb = blockIdx.x << 5, kb = blockIdx.y << 5;
    int tx = threadIdx.x & 31, ty = threadIdx.x >> 5;
#pragma unroll
    for (int r = 0; r < 32; r += 8)
        tile[ty + r][tx] = W[(size_t)(kb + ty + r) * N + nb + tx];
    __syncthreads();
#pragma unroll
    for (int r = 0; r < 32; r += 8)
        Wt[(size_t)(nb + ty + r) * K + kb + tx] = f2bf(tile[tx][ty + r]);
}

// ---------------- GEMM: C[M][N] = A[M][K](bf16) @ Bt[N][K](bf16)^T ----------------
// m97-style staging: linear LDS + global_load_lds dwordx4, 2-barrier K-loop.
template <int MODE>
__global__ __launch_bounds__(256) void gemm_bt(const u16* __restrict__ A,
                                               const u16* __restrict__ Bt,
                                               float* __restrict__ Cf,
                                               u16* __restrict__ Qp, u16* __restrict__ Kp,
                                               u16* __restrict__ Vp,
                                               int M, int N, int K) {
    __shared__ __align__(16) u16 Al[128 * 32];
    __shared__ __align__(16) u16 Bl[128 * 32];
    const int tid = threadIdx.x;
    const int Ntiles = N >> 7;
    // bijective XCD swizzle (gridDim.x % 8 == 0 for both call sites)
    const int cpx = gridDim.x >> 3;
    const int bid = (int)blockIdx.x;
    const int wg = (bid & 7) * cpx + (bid >> 3);
    const int mt = wg / Ntiles, nt = wg % Ntiles;
    const int m0 = mt << 7, n0 = nt << 7;
    const int wave = tid >> 6, lane = tid & 63;
    const int wm = (wave >> 1) << 6, wn = (wave & 1) << 6;
    const int lr = lane & 15, lk = (lane >> 4) << 3;

    // staging geometry: wave w, issue i covers rows [i*64 + w*16, +16), 1KB chunk
    const int srow = (wave << 4) + (lane >> 2);   // + i*64
    const int scol = (lane & 3) << 3;

    f32x4 acc[4][4] = {};

    for (int k0 = 0; k0 < K; k0 += 32) {
        __syncthreads();
#pragma unroll
        for (int i = 0; i < 2; ++i) {
            const u16* ga = &A[(size_t)(m0 + srow + (i << 6)) * K + k0 + scol];
            const u16* gb = &Bt[(size_t)(n0 + srow + (i << 6)) * K + k0 + scol];
            // LDS base is wave-uniform; HW scatters lane i at base + i*16B
            __builtin_amdgcn_global_load_lds(GLB_U32(ga), LDS_U32(&Al[(wave << 9) + (i << 11)]), 16, 0, 0);
            __builtin_amdgcn_global_load_lds(GLB_U32(gb), LDS_U32(&Bl[(wave << 9) + (i << 11)]), 16, 0, 0);
        }
        __syncthreads();
        bf16x8 af[4], bfr[4];
#pragma unroll
        for (int i = 0; i < 4; ++i) {
            af[i]  = __builtin_bit_cast(bf16x8, *(const u16x8*)&Al[(wm + (i << 4) + lr) * 32 + lk]);
            bfr[i] = __builtin_bit_cast(bf16x8, *(const u16x8*)&Bl[(wn + (i << 4) + lr) * 32 + lk]);
        }
#pragma unroll
        for (int i = 0; i < 4; ++i)
#pragma unroll
            for (int j = 0; j < 4; ++j)
                acc[i][j] = __builtin_amdgcn_mfma_f32_16x16x32_bf16(af[i], bfr[j], acc[i][j], 0, 0, 0);
    }

#pragma unroll
    for (int i = 0; i < 4; ++i) {
#pragma unroll
        for (int j = 0; j < 4; ++j) {
            int rbase = m0 + wm + (i << 4) + ((lane >> 4) << 2);
            int col = n0 + wn + (j << 4) + lr;
#pragma unroll
            for (int jj = 0; jj < 4; ++jj) {
                float val = acc[i][j][jj];
                int row = rbase + jj;
                if (MODE == 0) {
                    int t = col >> 10, rem = col & 1023;
                    int h = rem >> 6, d = rem & 63;
                    int b = row >> 11, s = row & 2047;
                    size_t dst = ((size_t)((b << 4) + h) * S_ + s) * 64 + d;
                    u16 bv = f2bf(val);
                    if (t == 0) Qp[dst] = bv;
                    else if (t == 1) Kp[dst] = bv;
                    else Vp[dst] = bv;
                } else {
                    Cf[(size_t)row * N + col] = val;
                }
            }
        }
    }
}

// ---------------- RoPE in-place on q,k  [bh][s][64] bf16 ----------------
__global__ __launch_bounds__(256) void rope_kernel(u16* __restrict__ q, u16* __restrict__ k) {
    int idx = blockIdx.x * 256 + threadIdx.x;
    int j = idx & 31;
    int row = idx >> 5;
    int s = row & (S_ - 1);
    float invf = expf(-(float)j * (9.210340371976184f / 32.0f));
    float ang = (float)s * invf;
    float c = cosf(ang), sn = sinf(ang);
    size_t base = (size_t)row * 64;
    float q0 = bf2f(q[base + j]), q1 = bf2f(q[base + j + 32]);
    q[base + j]      = f2bf(q0 * c - q1 * sn);
    q[base + j + 32] = f2bf(q1 * c + q0 * sn);
    float k0 = bf2f(k[base + j]), k1 = bf2f(k[base + j + 32]);
    k[base + j]      = f2bf(k0 * c - k1 * sn);
    k[base + j + 32] = f2bf(k1 * c + k0 * sn);
}

// ---------------- V [bh][s][64] -> Vt [bh][64][s]  (bf16 tiled transpose) ----------------
__global__ __launch_bounds__(256) void vtrans_kernel(const u16* __restrict__ v,
                                                     u16* __restrict__ vt) {
    __shared__ __align__(16) u16 t[64][72];
    const int bh = blockIdx.x >> 5, st = blockIdx.x & 31;
    const size_t base = (size_t)bh * (S_ * 64);
    const int s0 = st << 6;
    const int r = threadIdx.x >> 2, c0 = (threadIdx.x & 3) << 4;
    *(u16x8*)&t[r][c0]     = *(const u16x8*)&v[base + (size_t)(s0 + r) * 64 + c0];
    *(u16x8*)&t[r][c0 + 8] = *(const u16x8*)&v[base + (size_t)(s0 + r) * 64 + c0 + 8];
    __syncthreads();
    u16x8 w0, w1;
#pragma unroll
    for (int i = 0; i < 8; ++i) w0[i] = t[c0 + i][r];
#pragma unroll
    for (int i = 0; i < 8; ++i) w1[i] = t[c0 + 8 + i][r];
    *(u16x8*)&vt[base + (size_t)r * S_ + s0 + c0]     = w0;
    *(u16x8*)&vt[base + (size_t)r * S_ + s0 + c0 + 8] = w1;
}

// ---------------- flash attention: 4 waves x 32 q-rows, swapped QK^T, KVBLK=64 ----------------
__global__ __launch_bounds__(256) void attn_kernel(const u16* __restrict__ q,
                                                   const u16* __restrict__ k,
                                                   const u16* __restrict__ vt,
                                                   const float* __restrict__ mask,
                                                   u16* __restrict__ outp) {
    __shared__ __align__(16) u16 Kl[64 * 64];
    __shared__ __align__(16) u16 Vl[64 * 64];
    __shared__ __align__(16) float madd2[64];
    __shared__ __align__(16) float bcast[4][32];

    const int tid = threadIdx.x, wave = tid >> 6, lane = tid & 63;
    const int c = lane & 31, hi = lane >> 5, c7 = c & 7;
    const int bh = blockIdx.x & 63, qt = blockIdx.x >> 6;
    const int b = bh >> 4, h = bh & 15;
    const size_t base = (size_t)bh * (S_ * 64);
    const int qrow = (qt << 7) + (wave << 5) + c;

    const float QS = 0.18033688f;  // 0.125 * log2(e)

    bf16x8 qf[4];
#pragma unroll
    for (int j = 0; j < 4; ++j) {
        u16x8 raw = *(const u16x8*)&q[base + (size_t)qrow * 64 + j * 16 + hi * 8];
        u16x8 sc;
#pragma unroll
        for (int e = 0; e < 8; ++e) sc[e] = f2bf(bf2f(raw[e]) * QS);
        qf[j] = __builtin_bit_cast(bf16x8, sc);
    }

    f32x16 acc[2] = {};
    float m_run = -1e30f, l_run = 0.f;

    const int sr = tid >> 2, su = (tid & 3) << 1;
    const int so0 = sr * 64 + ((su ^ (sr & 7)) << 3);
    const int so1 = sr * 64 + (((su + 1) ^ (sr & 7)) << 3);

    for (int kv0 = 0; kv0 < S_; kv0 += 64) {
        u16x8 kc0 = *(const u16x8*)&k[base + (size_t)(kv0 + sr) * 64 + su * 8];
        u16x8 kc1 = *(const u16x8*)&k[base + (size_t)(kv0 + sr) * 64 + su * 8 + 8];
        u16x8 vc0 = *(const u16x8*)&vt[base + (size_t)sr * S_ + kv0 + su * 8];
        u16x8 vc1 = *(const u16x8*)&vt[base + (size_t)sr * S_ + kv0 + su * 8 + 8];
        float mval = (tid < 64) ? mask[b * S_ + kv0 + tid] : 1.0f;
        __syncthreads();
        *(u16x8*)&Kl[so0] = kc0;
        *(u16x8*)&Kl[so1] = kc1;
        *(u16x8*)&Vl[so0] = vc0;
        *(u16x8*)&Vl[so1] = vc1;
        if (tid < 64) madd2[tid] = (1.0f - mval) * -1.44269504e9f;
        __syncthreads();

        // S^T = K * Q^T
        f32x16 p[2] = {};
#pragma unroll
        for (int j = 0; j < 4; ++j) {
            const int uo = ((2 * j + hi) ^ c7) << 3;
            bf16x8 ka  = __builtin_bit_cast(bf16x8, *(const u16x8*)&Kl[c * 64 + uo]);
            bf16x8 kb2 = __builtin_bit_cast(bf16x8, *(const u16x8*)&Kl[(32 + c) * 64 + uo]);
            p[0] = __builtin_amdgcn_mfma_f32_32x32x16_bf16(ka,  qf[j], p[0], 0, 0, 0);
            p[1] = __builtin_amdgcn_mfma_f32_32x32x16_bf16(kb2, qf[j], p[1], 0, 0, 0);
        }

        // mask add only when mask is active anywhere in this tile (wave-uniform)
        bool hasmask = __any(madd2[lane] != 0.0f);
        if (hasmask) {
#pragma unroll
            for (int t = 0; t < 2; ++t)
#pragma unroll
                for (int rq = 0; rq < 4; ++rq) {
                    float4 mf = *(const float4*)&madd2[t * 32 + rq * 8 + hi * 4];
                    p[t][4 * rq + 0] += mf.x;
                    p[t][4 * rq + 1] += mf.y;
                    p[t][4 * rq + 2] += mf.z;
                    p[t][4 * rq + 3] += mf.w;
                }
        }

        // tree max (depth 5) + cross-half merge
        float tm[16];
#pragma unroll
        for (int r = 0; r < 16; ++r) tm[r] = fmaxf(p[0][r], p[1][r]);
#pragma unroll
        for (int s = 8; s > 0; s >>= 1)
#pragma unroll
            for (int r = 0; r < s; ++r) tm[r] = fmaxf(tm[r], tm[r + s]);
        float mx = fmaxf(tm[0], __shfl_xor(tm[0], 32));

        // defer-rescale (T13): only rescale when max grew by > 8 (log2 domain)
        if (!__all(mx - m_run <= 8.0f)) {
            float mnew = fmaxf(m_run, mx);
            float alpha = exp2f(m_run - mnew);
            m_run = mnew;
            l_run *= alpha;
            bcast[wave][c] = alpha;
            float avf[16];
#pragma unroll
            for (int rq = 0; rq < 4; ++rq) {
                float4 t4 = *(const float4*)&bcast[wave][rq * 8 + hi * 4];
                avf[4 * rq + 0] = t4.x; avf[4 * rq + 1] = t4.y;
                avf[4 * rq + 2] = t4.z; avf[4 * rq + 3] = t4.w;
            }
#pragma unroll
            for (int r = 0; r < 16; ++r) {
                acc[0][r] *= avf[r];
                acc[1][r] *= avf[r];
            }
        }

        // exp + 4-way tree sum
        float s4[4] = {0.f, 0.f, 0.f, 0.f};
#pragma unroll
        for (int t = 0; t < 2; ++t)
#pragma unroll
            for (int r = 0; r < 16; ++r) {
                float e = exp2f(p[t][r] - m_run);
                p[t][r] = e;
                s4[r & 3] += e;
            }
        float ls = (s4[0] + s4[1]) + (s4[2] + s4[3]);
        ls += __shfl_xor(ls, 32);
        l_run += ls;

        // P -> bf16 packed pairs
        u32 wa[8], wb[8];
#pragma unroll
        for (int t = 0; t < 2; ++t)
#pragma unroll
            for (int rq = 0; rq < 4; ++rq) {
                float e0 = p[t][4 * rq + 0], e1 = p[t][4 * rq + 1];
                float e2 = p[t][4 * rq + 2], e3 = p[t][4 * rq + 3];
                u32 w0, w1;
                asm("v_cvt_pk_bf16_f32 %0, %1, %2" : "=v"(w0) : "v"(e0), "v"(e1));
                asm("v_cvt_pk_bf16_f32 %0, %1, %2" : "=v"(w1) : "v"(e2), "v"(e3));
                wa[4 * t + rq] = w0;
                wb[4 * t + rq] = w1;
            }

        // O += P * V : half-exchange via permlane32_swap (T12)
#pragma unroll
        for (int ks = 0; ks < 4; ++ks) {
            i32x2 ra = __builtin_amdgcn_permlane32_swap((int)wa[2 * ks], (int)wa[2 * ks + 1], false, false);
            i32x2 rb = __builtin_amdgcn_permlane32_swap((int)wb[2 * ks], (int)wb[2 * ks + 1], false, false);
            u32x4 pw;
            pw[0] = (u32)ra[0];  // [a0.lo | a1.lo]
            pw[1] = (u32)rb[0];
            pw[2] = (u32)ra[1];  // [a0.hi | a1.hi]
            pw[3] = (u32)rb[1];
            bf16x8 paf = __builtin_bit_cast(bf16x8, pw);
            const int uo = ((2 * ks + hi) ^ c7) << 3;
#pragma unroll
            for (int dt = 0; dt < 2; ++dt) {
                bf16x8 vf = __builtin_bit_cast(bf16x8,
                            *(const u16x8*)&Vl[(32 * dt + c) * 64 + uo]);
                acc[dt] = __builtin_amdgcn_mfma_f32_32x32x16_bf16(paf, vf, acc[dt], 0, 0, 0);
            }
        }
    }

    // epilogue
    bcast[wave][c] = l_run;
    float lvf[16];
#pragma unroll
    for (int rq = 0; rq < 4; ++rq) {
        float4 t4 = *(const float4*)&bcast[wave][rq * 8 + hi * 4];
        lvf[4 * rq + 0] = __builtin_amdgcn_rcpf(t4.x);
        lvf[4 * rq + 1] = __builtin_amdgcn_rcpf(t4.y);
        lvf[4 * rq + 2] = __builtin_amdgcn_rcpf(t4.z);
        lvf[4 * rq + 3] = __builtin_amdgcn_rcpf(t4.w);
    }
    const size_t orow0 = (size_t)b * S_ + (qt << 7) + (wave << 5);
#pragma unroll
    for (int dt = 0; dt < 2; ++dt)
#pragma unroll
        for (int r = 0; r < 16; ++r) {
            int qr = (r & 3) + 8 * (r >> 2) + 4 * hi;
            outp[(orow0 + qr) * DM + h * 64 + dt * 32 + c] = f2bf(acc[dt][r] * lvf[r]);
        }
}

extern "C" void kernel_launch(void* const* d_in, const int* in_sizes, int n_in,
                              void* d_out, int out_size, void* d_ws, size_t ws_size,
                              hipStream_t stream) {
    const float* x    = (const float*)d_in[0];
    const float* mask = (const float*)d_in[1];
    const float* Wqkv = (const float*)d_in[2];
    const float* Wout = (const float*)d_in[3];
    float* out = (float*)d_out;
    char* ws = (char*)d_ws;
    const size_t MB = 1u << 20;
    u16* xb    = (u16*)(ws);            // 16 MB: x bf16; later reused as Vt
    u16* WqkvT = (u16*)(ws + 16 * MB);  // 6 MB
    u16* WoutT = (u16*)(ws + 22 * MB);  // 2 MB
    u16* qb    = (u16*)(ws + 24 * MB);  // 16 MB
    u16* kb    = (u16*)(ws + 40 * MB);  // 16 MB
    u16* vb    = (u16*)(ws + 56 * MB);  // 16 MB; later reused as attn-out
    u16* vtb   = xb;
    u16* ao    = vb;

    f32_to_bf16_kernel<<<8192, 256, 0, stream>>>(x, xb, 8192 * 1024);
    transpose_w<<<dim3(96, 32), 256, 0, stream>>>(Wqkv, WqkvT, 1024, 3072);
    transpose_w<<<dim3(32, 32), 256, 0, stream>>>(Wout, WoutT, 1024, 1024);
    gemm_bt<0><<<64 * 24, 256, 0, stream>>>(xb, WqkvT, nullptr, qb, kb, vb, 8192, 3072, 1024);
    rope_kernel<<<16384, 256, 0, stream>>>(qb, kb);
    vtrans_kernel<<<2048, 256, 0, stream>>>(vb, vtb);
    attn_kernel<<<1024, 256, 0, stream>>>(qb, kb, vtb, mask, ao);
    gemm_bt<1><<<64 * 8, 256, 0, stream>>>(ao, WoutT, out, nullptr, nullptr, nullptr, 8192, 1024, 1024);
}

// Round 4
// 254.042 us; speedup vs baseline: 1.4354x; 1.1029x over previous
//
#include <hip/hip_runtime.h>

typedef unsigned short u16;
typedef unsigned int u32;
typedef int i32x2 __attribute__((ext_vector_type(2)));
typedef float f32x4 __attribute__((ext_vector_type(4)));
typedef float f32x16 __attribute__((ext_vector_type(16)));
typedef __bf16 bf16x8 __attribute__((ext_vector_type(8)));
typedef unsigned short u16x8 __attribute__((ext_vector_type(8)));
typedef unsigned short u16x4 __attribute__((ext_vector_type(4)));
typedef unsigned int u32x4 __attribute__((ext_vector_type(4)));

#define S_ 2048
#define DM 1024

#define LDS_U32(p) ((__attribute__((address_space(3))) unsigned int*)(p))
#define GLB_U32(p) ((const __attribute__((address_space(1))) unsigned int*)(p))

__device__ __forceinline__ u16 f2bf(float f) {
    unsigned int u = __float_as_uint(f);
    u += 0x7fffu + ((u >> 16) & 1u);
    return (u16)(u >> 16);
}
__device__ __forceinline__ float bf2f(u16 s) {
    return __uint_as_float(((unsigned int)s) << 16);
}
// raw v_exp_f32 — exp2f w/o fast-math lowers to a ~27-instr ocml polynomial
__device__ __forceinline__ float fast_exp2(float x) {
#if __has_builtin(__builtin_amdgcn_exp2f)
    return __builtin_amdgcn_exp2f(x);
#else
    return __expf(x * 0.69314718056f);
#endif
}

// ---------------- f32 -> bf16 convert ----------------
__global__ __launch_bounds__(256) void f32_to_bf16_kernel(const float* __restrict__ in,
                                                          u16* __restrict__ o, int n) {
    int i = (blockIdx.x * 256 + threadIdx.x) << 2;
    if (i >= n) return;
    float4 f = *(const float4*)&in[i];
    u16x4 r;
    r[0] = f2bf(f.x); r[1] = f2bf(f.y); r[2] = f2bf(f.z); r[3] = f2bf(f.w);
    *(u16x4*)&o[i] = r;
}

// ---------------- W [K][N] f32 -> Wt [N][K] bf16 ----------------
__global__ __launch_bounds__(256) void transpose_w(const float* __restrict__ W,
                                                   u16* __restrict__ Wt, int K, int N) {
    __shared__ float tile[32][33];
    int nb = blockIdx.x << 5, kb = blockIdx.y << 5;
    int tx = threadIdx.x & 31, ty = threadIdx.x >> 5;
#pragma unroll
    for (int r = 0; r < 32; r += 8)
        tile[ty + r][tx] = W[(size_t)(kb + ty + r) * N + nb + tx];
    __syncthreads();
#pragma unroll
    for (int r = 0; r < 32; r += 8)
        Wt[(size_t)(nb + ty + r) * K + kb + tx] = f2bf(tile[tx][ty + r]);
}

// ---------------- GEMM: C[M][N] = A[M][K](bf16) @ Bt[N][K](bf16)^T ----------------
template <int MODE>
__global__ __launch_bounds__(256) void gemm_bt(const u16* __restrict__ A,
                                               const u16* __restrict__ Bt,
                                               float* __restrict__ Cf,
                                               u16* __restrict__ Qp, u16* __restrict__ Kp,
                                               u16* __restrict__ Vp,
                                               int M, int N, int K) {
    __shared__ __align__(16) u16 Al[128 * 32];
    __shared__ __align__(16) u16 Bl[128 * 32];
    const int tid = threadIdx.x;
    const int Ntiles = N >> 7;
    const int cpx = gridDim.x >> 3;
    const int bid = (int)blockIdx.x;
    const int wg = (bid & 7) * cpx + (bid >> 3);
    const int mt = wg / Ntiles, nt = wg % Ntiles;
    const int m0 = mt << 7, n0 = nt << 7;
    const int wave = tid >> 6, lane = tid & 63;
    const int wm = (wave >> 1) << 6, wn = (wave & 1) << 6;
    const int lr = lane & 15, lk = (lane >> 4) << 3;

    const int srow = (wave << 4) + (lane >> 2);
    const int scol = (lane & 3) << 3;

    f32x4 acc[4][4] = {};

    for (int k0 = 0; k0 < K; k0 += 32) {
        __syncthreads();
#pragma unroll
        for (int i = 0; i < 2; ++i) {
            const u16* ga = &A[(size_t)(m0 + srow + (i << 6)) * K + k0 + scol];
            const u16* gb = &Bt[(size_t)(n0 + srow + (i << 6)) * K + k0 + scol];
            __builtin_amdgcn_global_load_lds(GLB_U32(ga), LDS_U32(&Al[(wave << 9) + (i << 11)]), 16, 0, 0);
            __builtin_amdgcn_global_load_lds(GLB_U32(gb), LDS_U32(&Bl[(wave << 9) + (i << 11)]), 16, 0, 0);
        }
        __syncthreads();
        bf16x8 af[4], bfr[4];
#pragma unroll
        for (int i = 0; i < 4; ++i) {
            af[i]  = __builtin_bit_cast(bf16x8, *(const u16x8*)&Al[(wm + (i << 4) + lr) * 32 + lk]);
            bfr[i] = __builtin_bit_cast(bf16x8, *(const u16x8*)&Bl[(wn + (i << 4) + lr) * 32 + lk]);
        }
#pragma unroll
        for (int i = 0; i < 4; ++i)
#pragma unroll
            for (int j = 0; j < 4; ++j)
                acc[i][j] = __builtin_amdgcn_mfma_f32_16x16x32_bf16(af[i], bfr[j], acc[i][j], 0, 0, 0);
    }

#pragma unroll
    for (int i = 0; i < 4; ++i) {
#pragma unroll
        for (int j = 0; j < 4; ++j) {
            int rbase = m0 + wm + (i << 4) + ((lane >> 4) << 2);
            int col = n0 + wn + (j << 4) + lr;
#pragma unroll
            for (int jj = 0; jj < 4; ++jj) {
                float val = acc[i][j][jj];
                int row = rbase + jj;
                if (MODE == 0) {
                    int t = col >> 10, rem = col & 1023;
                    int h = rem >> 6, d = rem & 63;
                    int b = row >> 11, s = row & 2047;
                    size_t dst = ((size_t)((b << 4) + h) * S_ + s) * 64 + d;
                    u16 bv = f2bf(val);
                    if (t == 0) Qp[dst] = bv;
                    else if (t == 1) Kp[dst] = bv;
                    else Vp[dst] = bv;
                } else {
                    Cf[(size_t)row * N + col] = val;
                }
            }
        }
    }
}

// ---------------- RoPE in-place on q,k  [bh][s][64] bf16 ----------------
__global__ __launch_bounds__(256) void rope_kernel(u16* __restrict__ q, u16* __restrict__ k) {
    int idx = blockIdx.x * 256 + threadIdx.x;
    int j = idx & 31;
    int row = idx >> 5;
    int s = row & (S_ - 1);
    float invf = __expf(-(float)j * (9.210340371976184f / 32.0f));
    float ang = (float)s * invf;
    float c = __cosf(ang), sn = __sinf(ang);
    size_t base = (size_t)row * 64;
    float q0 = bf2f(q[base + j]), q1 = bf2f(q[base + j + 32]);
    q[base + j]      = f2bf(q0 * c - q1 * sn);
    q[base + j + 32] = f2bf(q1 * c + q0 * sn);
    float k0 = bf2f(k[base + j]), k1 = bf2f(k[base + j + 32]);
    k[base + j]      = f2bf(k0 * c - k1 * sn);
    k[base + j + 32] = f2bf(k1 * c + k0 * sn);
}

// ---------------- V [bh][s][64] -> Vt [bh][64][s] ----------------
__global__ __launch_bounds__(256) void vtrans_kernel(const u16* __restrict__ v,
                                                     u16* __restrict__ vt) {
    __shared__ __align__(16) u16 t[64][72];
    const int bh = blockIdx.x >> 5, st = blockIdx.x & 31;
    const size_t base = (size_t)bh * (S_ * 64);
    const int s0 = st << 6;
    const int r = threadIdx.x >> 2, c0 = (threadIdx.x & 3) << 4;
    *(u16x8*)&t[r][c0]     = *(const u16x8*)&v[base + (size_t)(s0 + r) * 64 + c0];
    *(u16x8*)&t[r][c0 + 8] = *(const u16x8*)&v[base + (size_t)(s0 + r) * 64 + c0 + 8];
    __syncthreads();
    u16x8 w0, w1;
#pragma unroll
    for (int i = 0; i < 8; ++i) w0[i] = t[c0 + i][r];
#pragma unroll
    for (int i = 0; i < 8; ++i) w1[i] = t[c0 + 8 + i][r];
    *(u16x8*)&vt[base + (size_t)r * S_ + s0 + c0]     = w0;
    *(u16x8*)&vt[base + (size_t)r * S_ + s0 + c0 + 8] = w1;
}

// ---------------- flash attention: 4 waves x 32 q-rows, swapped QK^T, KVBLK=64 ----------------
__global__ __launch_bounds__(256) void attn_kernel(const u16* __restrict__ q,
                                                   const u16* __restrict__ k,
                                                   const u16* __restrict__ vt,
                                                   const float* __restrict__ mask,
                                                   u16* __restrict__ outp) {
    __shared__ __align__(16) u16 Kl[64 * 64];
    __shared__ __align__(16) u16 Vl[64 * 64];
    __shared__ __align__(16) float madd2[64];
    __shared__ __align__(16) float bcast[4][32];

    const int tid = threadIdx.x, wave = tid >> 6, lane = tid & 63;
    const int c = lane & 31, hi = lane >> 5, c7 = c & 7;
    const int bh = blockIdx.x & 63, qt = blockIdx.x >> 6;
    const int b = bh >> 4, h = bh & 15;
    const size_t base = (size_t)bh * (S_ * 64);
    const int qrow = (qt << 7) + (wave << 5) + c;

    const float QS = 0.18033688f;  // 0.125 * log2(e)

    bf16x8 qf[4];
#pragma unroll
    for (int j = 0; j < 4; ++j) {
        u16x8 raw = *(const u16x8*)&q[base + (size_t)qrow * 64 + j * 16 + hi * 8];
        u16x8 sc;
#pragma unroll
        for (int e = 0; e < 8; ++e) sc[e] = f2bf(bf2f(raw[e]) * QS);
        qf[j] = __builtin_bit_cast(bf16x8, sc);
    }

    f32x16 acc[2] = {};
    float m_run = -1e30f, l_run = 0.f;

    const int sr = tid >> 2, su = (tid & 3) << 1;
    const int so0 = sr * 64 + ((su ^ (sr & 7)) << 3);
    const int so1 = sr * 64 + (((su + 1) ^ (sr & 7)) << 3);

    for (int kv0 = 0; kv0 < S_; kv0 += 64) {
        u16x8 kc0 = *(const u16x8*)&k[base + (size_t)(kv0 + sr) * 64 + su * 8];
        u16x8 kc1 = *(const u16x8*)&k[base + (size_t)(kv0 + sr) * 64 + su * 8 + 8];
        u16x8 vc0 = *(const u16x8*)&vt[base + (size_t)sr * S_ + kv0 + su * 8];
        u16x8 vc1 = *(const u16x8*)&vt[base + (size_t)sr * S_ + kv0 + su * 8 + 8];
        float mval = (tid < 64) ? mask[b * S_ + kv0 + tid] : 1.0f;
        __syncthreads();
        *(u16x8*)&Kl[so0] = kc0;
        *(u16x8*)&Kl[so1] = kc1;
        *(u16x8*)&Vl[so0] = vc0;
        *(u16x8*)&Vl[so1] = vc1;
        if (tid < 64) madd2[tid] = (1.0f - mval) * -1.44269504e9f;
        __syncthreads();

        // S^T = K * Q^T
        f32x16 p[2] = {};
#pragma unroll
        for (int j = 0; j < 4; ++j) {
            const int uo = ((2 * j + hi) ^ c7) << 3;
            bf16x8 ka  = __builtin_bit_cast(bf16x8, *(const u16x8*)&Kl[c * 64 + uo]);
            bf16x8 kb2 = __builtin_bit_cast(bf16x8, *(const u16x8*)&Kl[(32 + c) * 64 + uo]);
            p[0] = __builtin_amdgcn_mfma_f32_32x32x16_bf16(ka,  qf[j], p[0], 0, 0, 0);
            p[1] = __builtin_amdgcn_mfma_f32_32x32x16_bf16(kb2, qf[j], p[1], 0, 0, 0);
        }

        bool hasmask = __any(madd2[lane] != 0.0f);
        if (hasmask) {
#pragma unroll
            for (int t = 0; t < 2; ++t)
#pragma unroll
                for (int rq = 0; rq < 4; ++rq) {
                    float4 mf = *(const float4*)&madd2[t * 32 + rq * 8 + hi * 4];
                    p[t][4 * rq + 0] += mf.x;
                    p[t][4 * rq + 1] += mf.y;
                    p[t][4 * rq + 2] += mf.z;
                    p[t][4 * rq + 3] += mf.w;
                }
        }

        // max reduce via v_max3 folding (nested fmaxf triples fuse to v_max3)
        float tm[16];
#pragma unroll
        for (int r = 0; r < 16; ++r) tm[r] = fmaxf(p[0][r], p[1][r]);
        float a0 = fmaxf(fmaxf(tm[0], tm[1]), tm[2]);
        float a1 = fmaxf(fmaxf(tm[3], tm[4]), tm[5]);
        float a2 = fmaxf(fmaxf(tm[6], tm[7]), tm[8]);
        float a3 = fmaxf(fmaxf(tm[9], tm[10]), tm[11]);
        float a4 = fmaxf(fmaxf(tm[12], tm[13]), tm[14]);
        float b0 = fmaxf(fmaxf(a0, a1), a2);
        float b1 = fmaxf(fmaxf(a3, a4), tm[15]);
        float mx = fmaxf(b0, b1);
        mx = fmaxf(mx, __shfl_xor(mx, 32));

        // defer-rescale (T13)
        if (!__all(mx - m_run <= 8.0f)) {
            float mnew = fmaxf(m_run, mx);
            float alpha = fast_exp2(m_run - mnew);
            m_run = mnew;
            l_run *= alpha;
            bcast[wave][c] = alpha;
            float avf[16];
#pragma unroll
            for (int rq = 0; rq < 4; ++rq) {
                float4 t4 = *(const float4*)&bcast[wave][rq * 8 + hi * 4];
                avf[4 * rq + 0] = t4.x; avf[4 * rq + 1] = t4.y;
                avf[4 * rq + 2] = t4.z; avf[4 * rq + 3] = t4.w;
            }
#pragma unroll
            for (int r = 0; r < 16; ++r) {
                acc[0][r] *= avf[r];
                acc[1][r] *= avf[r];
            }
        }

        // exp (raw v_exp_f32) + 4-way tree sum
        float s4[4] = {0.f, 0.f, 0.f, 0.f};
#pragma unroll
        for (int t = 0; t < 2; ++t)
#pragma unroll
            for (int r = 0; r < 16; ++r) {
                float e = fast_exp2(p[t][r] - m_run);
                p[t][r] = e;
                s4[r & 3] += e;
            }
        float ls = (s4[0] + s4[1]) + (s4[2] + s4[3]);
        ls += __shfl_xor(ls, 32);
        l_run += ls;

        // P -> bf16 packed pairs
        u32 wa[8], wb[8];
#pragma unroll
        for (int t = 0; t < 2; ++t)
#pragma unroll
            for (int rq = 0; rq < 4; ++rq) {
                float e0 = p[t][4 * rq + 0], e1 = p[t][4 * rq + 1];
                float e2 = p[t][4 * rq + 2], e3 = p[t][4 * rq + 3];
                u32 w0, w1;
                asm("v_cvt_pk_bf16_f32 %0, %1, %2" : "=v"(w0) : "v"(e0), "v"(e1));
                asm("v_cvt_pk_bf16_f32 %0, %1, %2" : "=v"(w1) : "v"(e2), "v"(e3));
                wa[4 * t + rq] = w0;
                wb[4 * t + rq] = w1;
            }

        // O += P * V : half-exchange via permlane32_swap
#pragma unroll
        for (int ks = 0; ks < 4; ++ks) {
            i32x2 ra = __builtin_amdgcn_permlane32_swap((int)wa[2 * ks], (int)wa[2 * ks + 1], false, false);
            i32x2 rb = __builtin_amdgcn_permlane32_swap((int)wb[2 * ks], (int)wb[2 * ks + 1], false, false);
            u32x4 pw;
            pw[0] = (u32)ra[0];
            pw[1] = (u32)rb[0];
            pw[2] = (u32)ra[1];
            pw[3] = (u32)rb[1];
            bf16x8 paf = __builtin_bit_cast(bf16x8, pw);
            const int uo = ((2 * ks + hi) ^ c7) << 3;
#pragma unroll
            for (int dt = 0; dt < 2; ++dt) {
                bf16x8 vf = __builtin_bit_cast(bf16x8,
                            *(const u16x8*)&Vl[(32 * dt + c) * 64 + uo]);
                acc[dt] = __builtin_amdgcn_mfma_f32_32x32x16_bf16(paf, vf, acc[dt], 0, 0, 0);
            }
        }
    }

    // epilogue
    bcast[wave][c] = l_run;
    float lvf[16];
#pragma unroll
    for (int rq = 0; rq < 4; ++rq) {
        float4 t4 = *(const float4*)&bcast[wave][rq * 8 + hi * 4];
        lvf[4 * rq + 0] = __builtin_amdgcn_rcpf(t4.x);
        lvf[4 * rq + 1] = __builtin_amdgcn_rcpf(t4.y);
        lvf[4 * rq + 2] = __builtin_amdgcn_rcpf(t4.z);
        lvf[4 * rq + 3] = __builtin_amdgcn_rcpf(t4.w);
    }
    const size_t orow0 = (size_t)b * S_ + (qt << 7) + (wave << 5);
#pragma unroll
    for (int dt = 0; dt < 2; ++dt)
#pragma unroll
        for (int r = 0; r < 16; ++r) {
            int qr = (r & 3) + 8 * (r >> 2) + 4 * hi;
            outp[(orow0 + qr) * DM + h * 64 + dt * 32 + c] = f2bf(acc[dt][r] * lvf[r]);
        }
}

extern "C" void kernel_launch(void* const* d_in, const int* in_sizes, int n_in,
                              void* d_out, int out_size, void* d_ws, size_t ws_size,
                              hipStream_t stream) {
    const float* x    = (const float*)d_in[0];
    const float* mask = (const float*)d_in[1];
    const float* Wqkv = (const float*)d_in[2];
    const float* Wout = (const float*)d_in[3];
    float* out = (float*)d_out;
    char* ws = (char*)d_ws;
    const size_t MB = 1u << 20;
    u16* xb    = (u16*)(ws);
    u16* WqkvT = (u16*)(ws + 16 * MB);
    u16* WoutT = (u16*)(ws + 22 * MB);
    u16* qb    = (u16*)(ws + 24 * MB);
    u16* kb    = (u16*)(ws + 40 * MB);
    u16* vb    = (u16*)(ws + 56 * MB);
    u16* vtb   = xb;
    u16* ao    = vb;

    f32_to_bf16_kernel<<<8192, 256, 0, stream>>>(x, xb, 8192 * 1024);
    transpose_w<<<dim3(96, 32), 256, 0, stream>>>(Wqkv, WqkvT, 1024, 3072);
    transpose_w<<<dim3(32, 32), 256, 0, stream>>>(Wout, WoutT, 1024, 1024);
    gemm_bt<0><<<64 * 24, 256, 0, stream>>>(xb, WqkvT, nullptr, qb, kb, vb, 8192, 3072, 1024);
    rope_kernel<<<16384, 256, 0, stream>>>(qb, kb);
    vtrans_kernel<<<2048, 256, 0, stream>>>(vb, vtb);
    attn_kernel<<<1024, 256, 0, stream>>>(qb, kb, vtb, mask, ao);
    gemm_bt<1><<<64 * 8, 256, 0, stream>>>(ao, WoutT, out, nullptr, nullptr, nullptr, 8192, 1024, 1024);
}

// Round 5
// 243.955 us; speedup vs baseline: 1.4947x; 1.0413x over previous
//
#include <hip/hip_runtime.h>

typedef unsigned short u16;
typedef unsigned int u32;
typedef int i32x2 __attribute__((ext_vector_type(2)));
typedef float f32x4 __attribute__((ext_vector_type(4)));
typedef float f32x16 __attribute__((ext_vector_type(16)));
typedef __bf16 bf16x8 __attribute__((ext_vector_type(8)));
typedef unsigned short u16x8 __attribute__((ext_vector_type(8)));
typedef unsigned short u16x4 __attribute__((ext_vector_type(4)));
typedef unsigned int u32x4 __attribute__((ext_vector_type(4)));

#define S_ 2048
#define DM 1024

#define LDS_U32(p) ((__attribute__((address_space(3))) unsigned int*)(p))
#define GLB_U32(p) ((const __attribute__((address_space(1))) unsigned int*)(p))

__device__ __forceinline__ u16 f2bf(float f) {
    unsigned int u = __float_as_uint(f);
    u += 0x7fffu + ((u >> 16) & 1u);
    return (u16)(u >> 16);
}
__device__ __forceinline__ float bf2f(u16 s) {
    return __uint_as_float(((unsigned int)s) << 16);
}
// raw v_exp_f32 — exp2f w/o fast-math lowers to a ~27-instr ocml polynomial
__device__ __forceinline__ float fast_exp2(float x) {
#if __has_builtin(__builtin_amdgcn_exp2f)
    return __builtin_amdgcn_exp2f(x);
#else
    return __expf(x * 0.69314718056f);
#endif
}

// ---------------- f32 -> bf16 convert ----------------
__global__ __launch_bounds__(256) void f32_to_bf16_kernel(const float* __restrict__ in,
                                                          u16* __restrict__ o, int n) {
    int i = (blockIdx.x * 256 + threadIdx.x) << 2;
    if (i >= n) return;
    float4 f = *(const float4*)&in[i];
    u16x4 r;
    r[0] = f2bf(f.x); r[1] = f2bf(f.y); r[2] = f2bf(f.z); r[3] = f2bf(f.w);
    *(u16x4*)&o[i] = r;
}

// ---------------- W [K][N] f32 -> Wt [N][K] bf16 ----------------
__global__ __launch_bounds__(256) void transpose_w(const float* __restrict__ W,
                                                   u16* __restrict__ Wt, int K, int N) {
    __shared__ float tile[32][33];
    int nb = blockIdx.x << 5, kb = blockIdx.y << 5;
    int tx = threadIdx.x & 31, ty = threadIdx.x >> 5;
#pragma unroll
    for (int r = 0; r < 32; r += 8)
        tile[ty + r][tx] = W[(size_t)(kb + ty + r) * N + nb + tx];
    __syncthreads();
#pragma unroll
    for (int r = 0; r < 32; r += 8)
        Wt[(size_t)(nb + ty + r) * K + kb + tx] = f2bf(tile[tx][ty + r]);
}

// ---------------- GEMM: C[M][N] = A[M][K](bf16) @ Bt[N][K](bf16)^T ----------------
template <int MODE>
__global__ __launch_bounds__(256) void gemm_bt(const u16* __restrict__ A,
                                               const u16* __restrict__ Bt,
                                               float* __restrict__ Cf,
                                               u16* __restrict__ Qp, u16* __restrict__ Kp,
                                               u16* __restrict__ Vp,
                                               int M, int N, int K) {
    __shared__ __align__(16) u16 Al[128 * 32];
    __shared__ __align__(16) u16 Bl[128 * 32];
    const int tid = threadIdx.x;
    const int Ntiles = N >> 7;
    const int cpx = gridDim.x >> 3;
    const int bid = (int)blockIdx.x;
    const int wg = (bid & 7) * cpx + (bid >> 3);
    const int mt = wg / Ntiles, nt = wg % Ntiles;
    const int m0 = mt << 7, n0 = nt << 7;
    const int wave = tid >> 6, lane = tid & 63;
    const int wm = (wave >> 1) << 6, wn = (wave & 1) << 6;
    const int lr = lane & 15, lk = (lane >> 4) << 3;

    const int srow = (wave << 4) + (lane >> 2);
    const int scol = (lane & 3) << 3;

    f32x4 acc[4][4] = {};

    for (int k0 = 0; k0 < K; k0 += 32) {
        __syncthreads();
#pragma unroll
        for (int i = 0; i < 2; ++i) {
            const u16* ga = &A[(size_t)(m0 + srow + (i << 6)) * K + k0 + scol];
            const u16* gb = &Bt[(size_t)(n0 + srow + (i << 6)) * K + k0 + scol];
            __builtin_amdgcn_global_load_lds(GLB_U32(ga), LDS_U32(&Al[(wave << 9) + (i << 11)]), 16, 0, 0);
            __builtin_amdgcn_global_load_lds(GLB_U32(gb), LDS_U32(&Bl[(wave << 9) + (i << 11)]), 16, 0, 0);
        }
        __syncthreads();
        bf16x8 af[4], bfr[4];
#pragma unroll
        for (int i = 0; i < 4; ++i) {
            af[i]  = __builtin_bit_cast(bf16x8, *(const u16x8*)&Al[(wm + (i << 4) + lr) * 32 + lk]);
            bfr[i] = __builtin_bit_cast(bf16x8, *(const u16x8*)&Bl[(wn + (i << 4) + lr) * 32 + lk]);
        }
#pragma unroll
        for (int i = 0; i < 4; ++i)
#pragma unroll
            for (int j = 0; j < 4; ++j)
                acc[i][j] = __builtin_amdgcn_mfma_f32_16x16x32_bf16(af[i], bfr[j], acc[i][j], 0, 0, 0);
    }

#pragma unroll
    for (int i = 0; i < 4; ++i) {
#pragma unroll
        for (int j = 0; j < 4; ++j) {
            int rbase = m0 + wm + (i << 4) + ((lane >> 4) << 2);
            int col = n0 + wn + (j << 4) + lr;
#pragma unroll
            for (int jj = 0; jj < 4; ++jj) {
                float val = acc[i][j][jj];
                int row = rbase + jj;
                if (MODE == 0) {
                    int t = col >> 10, rem = col & 1023;
                    int h = rem >> 6, d = rem & 63;
                    int b = row >> 11, s = row & 2047;
                    size_t dst = ((size_t)((b << 4) + h) * S_ + s) * 64 + d;
                    u16 bv = f2bf(val);
                    if (t == 0) Qp[dst] = bv;
                    else if (t == 1) Kp[dst] = bv;
                    else Vp[dst] = bv;
                } else {
                    Cf[(size_t)row * N + col] = val;
                }
            }
        }
    }
}

// ---------------- RoPE in-place on q,k  [bh][s][64] bf16 ----------------
__global__ __launch_bounds__(256) void rope_kernel(u16* __restrict__ q, u16* __restrict__ k) {
    int idx = blockIdx.x * 256 + threadIdx.x;
    int j = idx & 31;
    int row = idx >> 5;
    int s = row & (S_ - 1);
    float invf = __expf(-(float)j * (9.210340371976184f / 32.0f));
    float ang = (float)s * invf;
    float c = __cosf(ang), sn = __sinf(ang);
    size_t base = (size_t)row * 64;
    float q0 = bf2f(q[base + j]), q1 = bf2f(q[base + j + 32]);
    q[base + j]      = f2bf(q0 * c - q1 * sn);
    q[base + j + 32] = f2bf(q1 * c + q0 * sn);
    float k0 = bf2f(k[base + j]), k1 = bf2f(k[base + j + 32]);
    k[base + j]      = f2bf(k0 * c - k1 * sn);
    k[base + j + 32] = f2bf(k1 * c + k0 * sn);
}

// ---------------- V [bh][s][64] -> Vt [bh][64][s] ----------------
__global__ __launch_bounds__(256) void vtrans_kernel(const u16* __restrict__ v,
                                                     u16* __restrict__ vt) {
    __shared__ __align__(16) u16 t[64][72];
    const int bh = blockIdx.x >> 5, st = blockIdx.x & 31;
    const size_t base = (size_t)bh * (S_ * 64);
    const int s0 = st << 6;
    const int r = threadIdx.x >> 2, c0 = (threadIdx.x & 3) << 4;
    *(u16x8*)&t[r][c0]     = *(const u16x8*)&v[base + (size_t)(s0 + r) * 64 + c0];
    *(u16x8*)&t[r][c0 + 8] = *(const u16x8*)&v[base + (size_t)(s0 + r) * 64 + c0 + 8];
    __syncthreads();
    u16x8 w0, w1;
#pragma unroll
    for (int i = 0; i < 8; ++i) w0[i] = t[c0 + i][r];
#pragma unroll
    for (int i = 0; i < 8; ++i) w1[i] = t[c0 + 8 + i][r];
    *(u16x8*)&vt[base + (size_t)r * S_ + s0 + c0]     = w0;
    *(u16x8*)&vt[base + (size_t)r * S_ + s0 + c0 + 8] = w1;
}

// ---------------- flash attention: 4 waves x 32 q-rows, swapped QK^T, KVBLK=64 ----------------
// single-barrier double-buffered pipeline: write buf[t&1] -> issue t+1 loads -> barrier -> compute
__global__ __launch_bounds__(256, 4) void attn_kernel(const u16* __restrict__ q,
                                                      const u16* __restrict__ k,
                                                      const u16* __restrict__ vt,
                                                      const float* __restrict__ mask,
                                                      u16* __restrict__ outp) {
    __shared__ __align__(16) u16 Kl[2][64 * 64];
    __shared__ __align__(16) u16 Vl[2][64 * 64];
    __shared__ float madd2[2][64];
    __shared__ float bcast[4][32];

    const int tid = threadIdx.x, wave = tid >> 6, lane = tid & 63;
    const int c = lane & 31, hi = lane >> 5, c7 = c & 7;
    const int bh = blockIdx.x & 63, qt = blockIdx.x >> 6;
    const int b = bh >> 4, h = bh & 15;
    const size_t base = (size_t)bh * (S_ * 64);
    const int qrow = (qt << 7) + (wave << 5) + c;

    const float QS = 0.18033688f;  // 0.125 * log2(e)

    bf16x8 qf[4];
#pragma unroll
    for (int j = 0; j < 4; ++j) {
        u16x8 raw = *(const u16x8*)&q[base + (size_t)qrow * 64 + j * 16 + hi * 8];
        u16x8 sc;
#pragma unroll
        for (int e = 0; e < 8; ++e) sc[e] = f2bf(bf2f(raw[e]) * QS);
        qf[j] = __builtin_bit_cast(bf16x8, sc);
    }

    f32x16 acc[2] = {};
    float m_run = -1e30f, l_run = 0.f;

    const int sr = tid >> 2, su = (tid & 3) << 1;
    const int so0 = sr * 64 + ((su ^ (sr & 7)) << 3);
    const int so1 = sr * 64 + (((su + 1) ^ (sr & 7)) << 3);

    // prologue: tile 0 into regs
    u16x8 kc0 = *(const u16x8*)&k[base + (size_t)sr * 64 + su * 8];
    u16x8 kc1 = *(const u16x8*)&k[base + (size_t)sr * 64 + su * 8 + 8];
    u16x8 vc0 = *(const u16x8*)&vt[base + (size_t)sr * S_ + su * 8];
    u16x8 vc1 = *(const u16x8*)&vt[base + (size_t)sr * S_ + su * 8 + 8];
    float mval = (tid < 64) ? mask[b * S_ + tid] : 1.0f;

    for (int t = 0; t < 32; ++t) {
        const int bi = t & 1;
        u16* Kb = &Kl[bi][0];
        u16* Vb = &Vl[bi][0];
        // write current tile to LDS (other waves at most computing buf[1-bi])
        *(u16x8*)&Kb[so0] = kc0;
        *(u16x8*)&Kb[so1] = kc1;
        *(u16x8*)&Vb[so0] = vc0;
        *(u16x8*)&Vb[so1] = vc1;
        if (tid < 64) madd2[bi][tid] = (1.0f - mval) * -1.44269504e9f;
        // issue next tile's global loads (latency hides under barrier+compute)
        if (t + 1 < 32) {
            const int kn = (t + 1) << 6;
            kc0 = *(const u16x8*)&k[base + (size_t)(kn + sr) * 64 + su * 8];
            kc1 = *(const u16x8*)&k[base + (size_t)(kn + sr) * 64 + su * 8 + 8];
            vc0 = *(const u16x8*)&vt[base + (size_t)sr * S_ + kn + su * 8];
            vc1 = *(const u16x8*)&vt[base + (size_t)sr * S_ + kn + su * 8 + 8];
            mval = (tid < 64) ? mask[b * S_ + kn + tid] : 1.0f;
        }
        __syncthreads();  // buf[bi] ready

        // S^T = K * Q^T
        f32x16 p[2] = {};
        __builtin_amdgcn_s_setprio(1);
#pragma unroll
        for (int j = 0; j < 4; ++j) {
            const int uo = ((2 * j + hi) ^ c7) << 3;
            bf16x8 ka  = __builtin_bit_cast(bf16x8, *(const u16x8*)&Kb[c * 64 + uo]);
            bf16x8 kb2 = __builtin_bit_cast(bf16x8, *(const u16x8*)&Kb[(32 + c) * 64 + uo]);
            p[0] = __builtin_amdgcn_mfma_f32_32x32x16_bf16(ka,  qf[j], p[0], 0, 0, 0);
            p[1] = __builtin_amdgcn_mfma_f32_32x32x16_bf16(kb2, qf[j], p[1], 0, 0, 0);
        }
        __builtin_amdgcn_s_setprio(0);

        bool hasmask = __any(madd2[bi][lane] != 0.0f);
        if (hasmask) {
#pragma unroll
            for (int tt = 0; tt < 2; ++tt)
#pragma unroll
                for (int rq = 0; rq < 4; ++rq) {
                    float4 mf = *(const float4*)&madd2[bi][tt * 32 + rq * 8 + hi * 4];
                    p[tt][4 * rq + 0] += mf.x;
                    p[tt][4 * rq + 1] += mf.y;
                    p[tt][4 * rq + 2] += mf.z;
                    p[tt][4 * rq + 3] += mf.w;
                }
        }

        // max reduce (v_max3 folding) + cross-half via permlane32_swap (VALU, no LDS round-trip)
        float tm[16];
#pragma unroll
        for (int r = 0; r < 16; ++r) tm[r] = fmaxf(p[0][r], p[1][r]);
        float a0 = fmaxf(fmaxf(tm[0], tm[1]), tm[2]);
        float a1 = fmaxf(fmaxf(tm[3], tm[4]), tm[5]);
        float a2 = fmaxf(fmaxf(tm[6], tm[7]), tm[8]);
        float a3 = fmaxf(fmaxf(tm[9], tm[10]), tm[11]);
        float a4 = fmaxf(fmaxf(tm[12], tm[13]), tm[14]);
        float b0 = fmaxf(fmaxf(a0, a1), a2);
        float b1 = fmaxf(fmaxf(a3, a4), tm[15]);
        float mx = fmaxf(b0, b1);
        {
            i32x2 mm = __builtin_amdgcn_permlane32_swap(__float_as_int(mx), __float_as_int(mx), false, false);
            mx = fmaxf(__int_as_float(mm[0]), __int_as_float(mm[1]));
        }

        // defer-rescale (T13)
        if (!__all(mx - m_run <= 8.0f)) {
            float mnew = fmaxf(m_run, mx);
            float alpha = fast_exp2(m_run - mnew);
            m_run = mnew;
            l_run *= alpha;
            bcast[wave][c] = alpha;
            float avf[16];
#pragma unroll
            for (int rq = 0; rq < 4; ++rq) {
                float4 t4 = *(const float4*)&bcast[wave][rq * 8 + hi * 4];
                avf[4 * rq + 0] = t4.x; avf[4 * rq + 1] = t4.y;
                avf[4 * rq + 2] = t4.z; avf[4 * rq + 3] = t4.w;
            }
#pragma unroll
            for (int r = 0; r < 16; ++r) {
                acc[0][r] *= avf[r];
                acc[1][r] *= avf[r];
            }
        }

        // exp (raw v_exp_f32) + 4-way tree sum
        float s4[4] = {0.f, 0.f, 0.f, 0.f};
#pragma unroll
        for (int tt = 0; tt < 2; ++tt)
#pragma unroll
            for (int r = 0; r < 16; ++r) {
                float e = fast_exp2(p[tt][r] - m_run);
                p[tt][r] = e;
                s4[r & 3] += e;
            }
        float ls = (s4[0] + s4[1]) + (s4[2] + s4[3]);
        {
            i32x2 ss = __builtin_amdgcn_permlane32_swap(__float_as_int(ls), __float_as_int(ls), false, false);
            ls = __int_as_float(ss[0]) + __int_as_float(ss[1]);
        }
        l_run += ls;

        // P -> bf16 packed pairs
        u32 wa[8], wb[8];
#pragma unroll
        for (int tt = 0; tt < 2; ++tt)
#pragma unroll
            for (int rq = 0; rq < 4; ++rq) {
                float e0 = p[tt][4 * rq + 0], e1 = p[tt][4 * rq + 1];
                float e2 = p[tt][4 * rq + 2], e3 = p[tt][4 * rq + 3];
                u32 w0, w1;
                asm("v_cvt_pk_bf16_f32 %0, %1, %2" : "=v"(w0) : "v"(e0), "v"(e1));
                asm("v_cvt_pk_bf16_f32 %0, %1, %2" : "=v"(w1) : "v"(e2), "v"(e3));
                wa[4 * tt + rq] = w0;
                wb[4 * tt + rq] = w1;
            }

        // O += P * V : half-exchange via permlane32_swap
        __builtin_amdgcn_s_setprio(1);
#pragma unroll
        for (int ks = 0; ks < 4; ++ks) {
            i32x2 ra = __builtin_amdgcn_permlane32_swap((int)wa[2 * ks], (int)wa[2 * ks + 1], false, false);
            i32x2 rb = __builtin_amdgcn_permlane32_swap((int)wb[2 * ks], (int)wb[2 * ks + 1], false, false);
            u32x4 pw;
            pw[0] = (u32)ra[0];
            pw[1] = (u32)rb[0];
            pw[2] = (u32)ra[1];
            pw[3] = (u32)rb[1];
            bf16x8 paf = __builtin_bit_cast(bf16x8, pw);
            const int uo = ((2 * ks + hi) ^ c7) << 3;
#pragma unroll
            for (int dt = 0; dt < 2; ++dt) {
                bf16x8 vf = __builtin_bit_cast(bf16x8,
                            *(const u16x8*)&Vb[(32 * dt + c) * 64 + uo]);
                acc[dt] = __builtin_amdgcn_mfma_f32_32x32x16_bf16(paf, vf, acc[dt], 0, 0, 0);
            }
        }
        __builtin_amdgcn_s_setprio(0);
        // no second barrier: next iter writes the other buffer
    }

    // epilogue
    bcast[wave][c] = l_run;
    __builtin_amdgcn_wave_barrier();
    float lvf[16];
#pragma unroll
    for (int rq = 0; rq < 4; ++rq) {
        float4 t4 = *(const float4*)&bcast[wave][rq * 8 + hi * 4];
        lvf[4 * rq + 0] = __builtin_amdgcn_rcpf(t4.x);
        lvf[4 * rq + 1] = __builtin_amdgcn_rcpf(t4.y);
        lvf[4 * rq + 2] = __builtin_amdgcn_rcpf(t4.z);
        lvf[4 * rq + 3] = __builtin_amdgcn_rcpf(t4.w);
    }
    const size_t orow0 = (size_t)b * S_ + (qt << 7) + (wave << 5);
#pragma unroll
    for (int dt = 0; dt < 2; ++dt)
#pragma unroll
        for (int r = 0; r < 16; ++r) {
            int qr = (r & 3) + 8 * (r >> 2) + 4 * hi;
            outp[(orow0 + qr) * DM + h * 64 + dt * 32 + c] = f2bf(acc[dt][r] * lvf[r]);
        }
}

extern "C" void kernel_launch(void* const* d_in, const int* in_sizes, int n_in,
                              void* d_out, int out_size, void* d_ws, size_t ws_size,
                              hipStream_t stream) {
    const float* x    = (const float*)d_in[0];
    const float* mask = (const float*)d_in[1];
    const float* Wqkv = (const float*)d_in[2];
    const float* Wout = (const float*)d_in[3];
    float* out = (float*)d_out;
    char* ws = (char*)d_ws;
    const size_t MB = 1u << 20;
    u16* xb    = (u16*)(ws);
    u16* WqkvT = (u16*)(ws + 16 * MB);
    u16* WoutT = (u16*)(ws + 22 * MB);
    u16* qb    = (u16*)(ws + 24 * MB);
    u16* kb    = (u16*)(ws + 40 * MB);
    u16* vb    = (u16*)(ws + 56 * MB);
    u16* vtb   = xb;
    u16* ao    = vb;

    f32_to_bf16_kernel<<<8192, 256, 0, stream>>>(x, xb, 8192 * 1024);
    transpose_w<<<dim3(96, 32), 256, 0, stream>>>(Wqkv, WqkvT, 1024, 3072);
    transpose_w<<<dim3(32, 32), 256, 0, stream>>>(Wout, WoutT, 1024, 1024);
    gemm_bt<0><<<64 * 24, 256, 0, stream>>>(xb, WqkvT, nullptr, qb, kb, vb, 8192, 3072, 1024);
    rope_kernel<<<16384, 256, 0, stream>>>(qb, kb);
    vtrans_kernel<<<2048, 256, 0, stream>>>(vb, vtb);
    attn_kernel<<<1024, 256, 0, stream>>>(qb, kb, vtb, mask, ao);
    gemm_bt<1><<<64 * 8, 256, 0, stream>>>(ao, WoutT, out, nullptr, nullptr, nullptr, 8192, 1024, 1024);
}

// Round 6
// 233.962 us; speedup vs baseline: 1.5586x; 1.0427x over previous
//
#include <hip/hip_runtime.h>

typedef unsigned short u16;
typedef unsigned int u32;
typedef int i32x2 __attribute__((ext_vector_type(2)));
typedef float f32x4 __attribute__((ext_vector_type(4)));
typedef float f32x16 __attribute__((ext_vector_type(16)));
typedef __bf16 bf16x8 __attribute__((ext_vector_type(8)));
typedef unsigned short u16x8 __attribute__((ext_vector_type(8)));
typedef unsigned short u16x4 __attribute__((ext_vector_type(4)));
typedef unsigned int u32x4 __attribute__((ext_vector_type(4)));

#define S_ 2048
#define DM 1024

#define LDS_U32(p) ((__attribute__((address_space(3))) unsigned int*)(p))
#define GLB_U32(p) ((const __attribute__((address_space(1))) unsigned int*)(p))

__device__ __forceinline__ u16 f2bf(float f) {
    unsigned int u = __float_as_uint(f);
    u += 0x7fffu + ((u >> 16) & 1u);
    return (u16)(u >> 16);
}
__device__ __forceinline__ float bf2f(u16 s) {
    return __uint_as_float(((unsigned int)s) << 16);
}
// raw v_exp_f32 — exp2f w/o fast-math lowers to a ~27-instr ocml polynomial
__device__ __forceinline__ float fast_exp2(float x) {
#if __has_builtin(__builtin_amdgcn_exp2f)
    return __builtin_amdgcn_exp2f(x);
#else
    return __expf(x * 0.69314718056f);
#endif
}

// ---------------- f32 -> bf16 convert ----------------
__global__ __launch_bounds__(256) void f32_to_bf16_kernel(const float* __restrict__ in,
                                                          u16* __restrict__ o, int n) {
    int i = (blockIdx.x * 256 + threadIdx.x) << 2;
    if (i >= n) return;
    float4 f = *(const float4*)&in[i];
    u16x4 r;
    r[0] = f2bf(f.x); r[1] = f2bf(f.y); r[2] = f2bf(f.z); r[3] = f2bf(f.w);
    *(u16x4*)&o[i] = r;
}

// ---------------- W [K][N] f32 -> Wt [N][K] bf16 ----------------
__global__ __launch_bounds__(256) void transpose_w(const float* __restrict__ W,
                                                   u16* __restrict__ Wt, int K, int N) {
    __shared__ float tile[32][33];
    int nb = blockIdx.x << 5, kb = blockIdx.y << 5;
    int tx = threadIdx.x & 31, ty = threadIdx.x >> 5;
#pragma unroll
    for (int r = 0; r < 32; r += 8)
        tile[ty + r][tx] = W[(size_t)(kb + ty + r) * N + nb + tx];
    __syncthreads();
#pragma unroll
    for (int r = 0; r < 32; r += 8)
        Wt[(size_t)(nb + ty + r) * K + kb + tx] = f2bf(tile[tx][ty + r]);
}

// ---------------- GEMM: C[M][N] = A[M][K](bf16) @ Bt[N][K](bf16)^T ----------------
// MODE 0: scatter-epilogue to q,k,v with RoPE fused in-register for q,k.
// MODE 1: fp32 C out.
template <int MODE>
__global__ __launch_bounds__(256) void gemm_bt(const u16* __restrict__ A,
                                               const u16* __restrict__ Bt,
                                               float* __restrict__ Cf,
                                               u16* __restrict__ Qp, u16* __restrict__ Kp,
                                               u16* __restrict__ Vp,
                                               int M, int N, int K) {
    __shared__ __align__(16) u16 Al[128 * 32];
    __shared__ __align__(16) u16 Bl[128 * 32];
    const int tid = threadIdx.x;
    const int Ntiles = N >> 7;
    const int cpx = gridDim.x >> 3;
    const int bid = (int)blockIdx.x;
    const int wg = (bid & 7) * cpx + (bid >> 3);
    const int mt = wg / Ntiles, nt = wg % Ntiles;
    const int m0 = mt << 7, n0 = nt << 7;
    const int wave = tid >> 6, lane = tid & 63;
    const int wm = (wave >> 1) << 6, wn = (wave & 1) << 6;
    const int lr = lane & 15, lk = (lane >> 4) << 3;

    const int srow = (wave << 4) + (lane >> 2);
    const int scol = (lane & 3) << 3;

    f32x4 acc[4][4] = {};

    for (int k0 = 0; k0 < K; k0 += 32) {
        __syncthreads();
#pragma unroll
        for (int i = 0; i < 2; ++i) {
            const u16* ga = &A[(size_t)(m0 + srow + (i << 6)) * K + k0 + scol];
            const u16* gb = &Bt[(size_t)(n0 + srow + (i << 6)) * K + k0 + scol];
            __builtin_amdgcn_global_load_lds(GLB_U32(ga), LDS_U32(&Al[(wave << 9) + (i << 11)]), 16, 0, 0);
            __builtin_amdgcn_global_load_lds(GLB_U32(gb), LDS_U32(&Bl[(wave << 9) + (i << 11)]), 16, 0, 0);
        }
        __syncthreads();
        bf16x8 af[4], bfr[4];
#pragma unroll
        for (int i = 0; i < 4; ++i) {
            af[i]  = __builtin_bit_cast(bf16x8, *(const u16x8*)&Al[(wm + (i << 4) + lr) * 32 + lk]);
            bfr[i] = __builtin_bit_cast(bf16x8, *(const u16x8*)&Bl[(wn + (i << 4) + lr) * 32 + lk]);
        }
#pragma unroll
        for (int i = 0; i < 4; ++i)
#pragma unroll
            for (int j = 0; j < 4; ++j)
                acc[i][j] = __builtin_amdgcn_mfma_f32_16x16x32_bf16(af[i], bfr[j], acc[i][j], 0, 0, 0);
    }

    if (MODE == 0) {
        // wave-uniform q/k/v selector: col = n0 + wn + j*16 + lr, j*16+lr < 64
        const int t = (n0 + wn) >> 10;
        if (t < 2) {
            // fused RoPE on f32 accumulators.
            // d = col & 63 = (j&1)*16 + lr + 32*(j>>1); partner pairs: (j, j^2).
            const float LN1E4_32 = 9.210340371976184f / 32.0f;
            const float invf0 = __expf(-(float)lr * LN1E4_32);
            const float invf1 = __expf(-(float)(lr + 16) * LN1E4_32);
#pragma unroll
            for (int i = 0; i < 4; ++i) {
                const int rbase = m0 + wm + (i << 4) + ((lane >> 4) << 2);
#pragma unroll
                for (int jj = 0; jj < 4; ++jj) {
                    const float s = (float)((rbase + jj) & (S_ - 1));
                    float sn0, c0, sn1, c1;
                    __sincosf(s * invf0, &sn0, &c0);
                    __sincosf(s * invf1, &sn1, &c1);
                    const float v0 = acc[i][0][jj], v1 = acc[i][1][jj];
                    const float v2 = acc[i][2][jj], v3 = acc[i][3][jj];
                    acc[i][0][jj] = v0 * c0 - v2 * sn0;
                    acc[i][2][jj] = v2 * c0 + v0 * sn0;
                    acc[i][1][jj] = v1 * c1 - v3 * sn1;
                    acc[i][3][jj] = v3 * c1 + v1 * sn1;
                }
            }
        }
    }

#pragma unroll
    for (int i = 0; i < 4; ++i) {
#pragma unroll
        for (int j = 0; j < 4; ++j) {
            int rbase = m0 + wm + (i << 4) + ((lane >> 4) << 2);
            int col = n0 + wn + (j << 4) + lr;
#pragma unroll
            for (int jj = 0; jj < 4; ++jj) {
                float val = acc[i][j][jj];
                int row = rbase + jj;
                if (MODE == 0) {
                    int t = col >> 10, rem = col & 1023;
                    int h = rem >> 6, d = rem & 63;
                    int b = row >> 11, s = row & 2047;
                    size_t dst = ((size_t)((b << 4) + h) * S_ + s) * 64 + d;
                    u16 bv = f2bf(val);
                    if (t == 0) Qp[dst] = bv;
                    else if (t == 1) Kp[dst] = bv;
                    else Vp[dst] = bv;
                } else {
                    Cf[(size_t)row * N + col] = val;
                }
            }
        }
    }
}

// ---------------- V [bh][s][64] -> Vt [bh][64][s] ----------------
__global__ __launch_bounds__(256) void vtrans_kernel(const u16* __restrict__ v,
                                                     u16* __restrict__ vt) {
    __shared__ __align__(16) u16 t[64][72];
    const int bh = blockIdx.x >> 5, st = blockIdx.x & 31;
    const size_t base = (size_t)bh * (S_ * 64);
    const int s0 = st << 6;
    const int r = threadIdx.x >> 2, c0 = (threadIdx.x & 3) << 4;
    *(u16x8*)&t[r][c0]     = *(const u16x8*)&v[base + (size_t)(s0 + r) * 64 + c0];
    *(u16x8*)&t[r][c0 + 8] = *(const u16x8*)&v[base + (size_t)(s0 + r) * 64 + c0 + 8];
    __syncthreads();
    u16x8 w0, w1;
#pragma unroll
    for (int i = 0; i < 8; ++i) w0[i] = t[c0 + i][r];
#pragma unroll
    for (int i = 0; i < 8; ++i) w1[i] = t[c0 + 8 + i][r];
    *(u16x8*)&vt[base + (size_t)r * S_ + s0 + c0]     = w0;
    *(u16x8*)&vt[base + (size_t)r * S_ + s0 + c0 + 8] = w1;
}

// ---------------- flash attention: 4 waves x 32 q-rows, swapped QK^T, KVBLK=64 ----------------
// single-barrier double-buffered pipeline: write buf[t&1] -> issue t+1 loads -> barrier -> compute
__global__ __launch_bounds__(256, 4) void attn_kernel(const u16* __restrict__ q,
                                                      const u16* __restrict__ k,
                                                      const u16* __restrict__ vt,
                                                      const float* __restrict__ mask,
                                                      u16* __restrict__ outp) {
    __shared__ __align__(16) u16 Kl[2][64 * 64];
    __shared__ __align__(16) u16 Vl[2][64 * 64];
    __shared__ float madd2[2][64];
    __shared__ float bcast[4][32];

    const int tid = threadIdx.x, wave = tid >> 6, lane = tid & 63;
    const int c = lane & 31, hi = lane >> 5, c7 = c & 7;
    const int bh = blockIdx.x & 63, qt = blockIdx.x >> 6;
    const int b = bh >> 4, h = bh & 15;
    const size_t base = (size_t)bh * (S_ * 64);
    const int qrow = (qt << 7) + (wave << 5) + c;

    const float QS = 0.18033688f;  // 0.125 * log2(e)

    bf16x8 qf[4];
#pragma unroll
    for (int j = 0; j < 4; ++j) {
        u16x8 raw = *(const u16x8*)&q[base + (size_t)qrow * 64 + j * 16 + hi * 8];
        u16x8 sc;
#pragma unroll
        for (int e = 0; e < 8; ++e) sc[e] = f2bf(bf2f(raw[e]) * QS);
        qf[j] = __builtin_bit_cast(bf16x8, sc);
    }

    f32x16 acc[2] = {};
    float m_run = -1e30f, l_run = 0.f;

    const int sr = tid >> 2, su = (tid & 3) << 1;
    const int so0 = sr * 64 + ((su ^ (sr & 7)) << 3);
    const int so1 = sr * 64 + (((su + 1) ^ (sr & 7)) << 3);

    // prologue: tile 0 into regs
    u16x8 kc0 = *(const u16x8*)&k[base + (size_t)sr * 64 + su * 8];
    u16x8 kc1 = *(const u16x8*)&k[base + (size_t)sr * 64 + su * 8 + 8];
    u16x8 vc0 = *(const u16x8*)&vt[base + (size_t)sr * S_ + su * 8];
    u16x8 vc1 = *(const u16x8*)&vt[base + (size_t)sr * S_ + su * 8 + 8];
    float mval = (tid < 64) ? mask[b * S_ + tid] : 1.0f;

    for (int t = 0; t < 32; ++t) {
        const int bi = t & 1;
        u16* Kb = &Kl[bi][0];
        u16* Vb = &Vl[bi][0];
        // write current tile to LDS (other waves at most computing buf[1-bi])
        *(u16x8*)&Kb[so0] = kc0;
        *(u16x8*)&Kb[so1] = kc1;
        *(u16x8*)&Vb[so0] = vc0;
        *(u16x8*)&Vb[so1] = vc1;
        if (tid < 64) madd2[bi][tid] = (1.0f - mval) * -1.44269504e9f;
        // issue next tile's global loads (latency hides under barrier+compute)
        if (t + 1 < 32) {
            const int kn = (t + 1) << 6;
            kc0 = *(const u16x8*)&k[base + (size_t)(kn + sr) * 64 + su * 8];
            kc1 = *(const u16x8*)&k[base + (size_t)(kn + sr) * 64 + su * 8 + 8];
            vc0 = *(const u16x8*)&vt[base + (size_t)sr * S_ + kn + su * 8];
            vc1 = *(const u16x8*)&vt[base + (size_t)sr * S_ + kn + su * 8 + 8];
            mval = (tid < 64) ? mask[b * S_ + kn + tid] : 1.0f;
        }
        __syncthreads();  // buf[bi] ready

        // S^T = K * Q^T
        f32x16 p[2] = {};
        __builtin_amdgcn_s_setprio(1);
#pragma unroll
        for (int j = 0; j < 4; ++j) {
            const int uo = ((2 * j + hi) ^ c7) << 3;
            bf16x8 ka  = __builtin_bit_cast(bf16x8, *(const u16x8*)&Kb[c * 64 + uo]);
            bf16x8 kb2 = __builtin_bit_cast(bf16x8, *(const u16x8*)&Kb[(32 + c) * 64 + uo]);
            p[0] = __builtin_amdgcn_mfma_f32_32x32x16_bf16(ka,  qf[j], p[0], 0, 0, 0);
            p[1] = __builtin_amdgcn_mfma_f32_32x32x16_bf16(kb2, qf[j], p[1], 0, 0, 0);
        }
        __builtin_amdgcn_s_setprio(0);

        bool hasmask = __any(madd2[bi][lane] != 0.0f);
        if (hasmask) {
#pragma unroll
            for (int tt = 0; tt < 2; ++tt)
#pragma unroll
                for (int rq = 0; rq < 4; ++rq) {
                    float4 mf = *(const float4*)&madd2[bi][tt * 32 + rq * 8 + hi * 4];
                    p[tt][4 * rq + 0] += mf.x;
                    p[tt][4 * rq + 1] += mf.y;
                    p[tt][4 * rq + 2] += mf.z;
                    p[tt][4 * rq + 3] += mf.w;
                }
        }

        // max reduce (v_max3 folding) + cross-half via permlane32_swap
        float tm[16];
#pragma unroll
        for (int r = 0; r < 16; ++r) tm[r] = fmaxf(p[0][r], p[1][r]);
        float a0 = fmaxf(fmaxf(tm[0], tm[1]), tm[2]);
        float a1 = fmaxf(fmaxf(tm[3], tm[4]), tm[5]);
        float a2 = fmaxf(fmaxf(tm[6], tm[7]), tm[8]);
        float a3 = fmaxf(fmaxf(tm[9], tm[10]), tm[11]);
        float a4 = fmaxf(fmaxf(tm[12], tm[13]), tm[14]);
        float b0 = fmaxf(fmaxf(a0, a1), a2);
        float b1 = fmaxf(fmaxf(a3, a4), tm[15]);
        float mx = fmaxf(b0, b1);
        {
            i32x2 mm = __builtin_amdgcn_permlane32_swap(__float_as_int(mx), __float_as_int(mx), false, false);
            mx = fmaxf(__int_as_float(mm[0]), __int_as_float(mm[1]));
        }

        // defer-rescale (T13)
        if (!__all(mx - m_run <= 8.0f)) {
            float mnew = fmaxf(m_run, mx);
            float alpha = fast_exp2(m_run - mnew);
            m_run = mnew;
            l_run *= alpha;
            bcast[wave][c] = alpha;
            float avf[16];
#pragma unroll
            for (int rq = 0; rq < 4; ++rq) {
                float4 t4 = *(const float4*)&bcast[wave][rq * 8 + hi * 4];
                avf[4 * rq + 0] = t4.x; avf[4 * rq + 1] = t4.y;
                avf[4 * rq + 2] = t4.z; avf[4 * rq + 3] = t4.w;
            }
#pragma unroll
            for (int r = 0; r < 16; ++r) {
                acc[0][r] *= avf[r];
                acc[1][r] *= avf[r];
            }
        }

        // exp (raw v_exp_f32) + 4-way tree sum
        float s4[4] = {0.f, 0.f, 0.f, 0.f};
#pragma unroll
        for (int tt = 0; tt < 2; ++tt)
#pragma unroll
            for (int r = 0; r < 16; ++r) {
                float e = fast_exp2(p[tt][r] - m_run);
                p[tt][r] = e;
                s4[r & 3] += e;
            }
        float ls = (s4[0] + s4[1]) + (s4[2] + s4[3]);
        {
            i32x2 ss = __builtin_amdgcn_permlane32_swap(__float_as_int(ls), __float_as_int(ls), false, false);
            ls = __int_as_float(ss[0]) + __int_as_float(ss[1]);
        }
        l_run += ls;

        // P -> bf16 packed pairs
        u32 wa[8], wb[8];
#pragma unroll
        for (int tt = 0; tt < 2; ++tt)
#pragma unroll
            for (int rq = 0; rq < 4; ++rq) {
                float e0 = p[tt][4 * rq + 0], e1 = p[tt][4 * rq + 1];
                float e2 = p[tt][4 * rq + 2], e3 = p[tt][4 * rq + 3];
                u32 w0, w1;
                asm("v_cvt_pk_bf16_f32 %0, %1, %2" : "=v"(w0) : "v"(e0), "v"(e1));
                asm("v_cvt_pk_bf16_f32 %0, %1, %2" : "=v"(w1) : "v"(e2), "v"(e3));
                wa[4 * tt + rq] = w0;
                wb[4 * tt + rq] = w1;
            }

        // O += P * V : half-exchange via permlane32_swap
        __builtin_amdgcn_s_setprio(1);
#pragma unroll
        for (int ks = 0; ks < 4; ++ks) {
            i32x2 ra = __builtin_amdgcn_permlane32_swap((int)wa[2 * ks], (int)wa[2 * ks + 1], false, false);
            i32x2 rb = __builtin_amdgcn_permlane32_swap((int)wb[2 * ks], (int)wb[2 * ks + 1], false, false);
            u32x4 pw;
            pw[0] = (u32)ra[0];
            pw[1] = (u32)rb[0];
            pw[2] = (u32)ra[1];
            pw[3] = (u32)rb[1];
            bf16x8 paf = __builtin_bit_cast(bf16x8, pw);
            const int uo = ((2 * ks + hi) ^ c7) << 3;
#pragma unroll
            for (int dt = 0; dt < 2; ++dt) {
                bf16x8 vf = __builtin_bit_cast(bf16x8,
                            *(const u16x8*)&Vb[(32 * dt + c) * 64 + uo]);
                acc[dt] = __builtin_amdgcn_mfma_f32_32x32x16_bf16(paf, vf, acc[dt], 0, 0, 0);
            }
        }
        __builtin_amdgcn_s_setprio(0);
        // no second barrier: next iter writes the other buffer
    }

    // epilogue
    bcast[wave][c] = l_run;
    __builtin_amdgcn_wave_barrier();
    float lvf[16];
#pragma unroll
    for (int rq = 0; rq < 4; ++rq) {
        float4 t4 = *(const float4*)&bcast[wave][rq * 8 + hi * 4];
        lvf[4 * rq + 0] = __builtin_amdgcn_rcpf(t4.x);
        lvf[4 * rq + 1] = __builtin_amdgcn_rcpf(t4.y);
        lvf[4 * rq + 2] = __builtin_amdgcn_rcpf(t4.z);
        lvf[4 * rq + 3] = __builtin_amdgcn_rcpf(t4.w);
    }
    const size_t orow0 = (size_t)b * S_ + (qt << 7) + (wave << 5);
#pragma unroll
    for (int dt = 0; dt < 2; ++dt)
#pragma unroll
        for (int r = 0; r < 16; ++r) {
            int qr = (r & 3) + 8 * (r >> 2) + 4 * hi;
            outp[(orow0 + qr) * DM + h * 64 + dt * 32 + c] = f2bf(acc[dt][r] * lvf[r]);
        }
}

extern "C" void kernel_launch(void* const* d_in, const int* in_sizes, int n_in,
                              void* d_out, int out_size, void* d_ws, size_t ws_size,
                              hipStream_t stream) {
    const float* x    = (const float*)d_in[0];
    const float* mask = (const float*)d_in[1];
    const float* Wqkv = (const float*)d_in[2];
    const float* Wout = (const float*)d_in[3];
    float* out = (float*)d_out;
    char* ws = (char*)d_ws;
    const size_t MB = 1u << 20;
    u16* xb    = (u16*)(ws);
    u16* WqkvT = (u16*)(ws + 16 * MB);
    u16* WoutT = (u16*)(ws + 22 * MB);
    u16* qb    = (u16*)(ws + 24 * MB);
    u16* kb    = (u16*)(ws + 40 * MB);
    u16* vb    = (u16*)(ws + 56 * MB);
    u16* vtb   = xb;
    u16* ao    = vb;

    f32_to_bf16_kernel<<<8192, 256, 0, stream>>>(x, xb, 8192 * 1024);
    transpose_w<<<dim3(96, 32), 256, 0, stream>>>(Wqkv, WqkvT, 1024, 3072);
    transpose_w<<<dim3(32, 32), 256, 0, stream>>>(Wout, WoutT, 1024, 1024);
    gemm_bt<0><<<64 * 24, 256, 0, stream>>>(xb, WqkvT, nullptr, qb, kb, vb, 8192, 3072, 1024);
    vtrans_kernel<<<2048, 256, 0, stream>>>(vb, vtb);
    attn_kernel<<<1024, 256, 0, stream>>>(qb, kb, vtb, mask, ao);
    gemm_bt<1><<<64 * 8, 256, 0, stream>>>(ao, WoutT, out, nullptr, nullptr, nullptr, 8192, 1024, 1024);
}

// Round 7
// 222.986 us; speedup vs baseline: 1.6353x; 1.0492x over previous
//
#include <hip/hip_runtime.h>

typedef unsigned short u16;
typedef unsigned int u32;
typedef int i32x2 __attribute__((ext_vector_type(2)));
typedef float f32x4 __attribute__((ext_vector_type(4)));
typedef float f32x16 __attribute__((ext_vector_type(16)));
typedef __bf16 bf16x8 __attribute__((ext_vector_type(8)));
typedef unsigned short u16x8 __attribute__((ext_vector_type(8)));
typedef unsigned short u16x4 __attribute__((ext_vector_type(4)));
typedef unsigned int u32x4 __attribute__((ext_vector_type(4)));

#define S_ 2048
#define DM 1024

#define LDS_U32(p) ((__attribute__((address_space(3))) unsigned int*)(p))
#define GLB_U32(p) ((const __attribute__((address_space(1))) unsigned int*)(p))

__device__ __forceinline__ u16 f2bf(float f) {
    unsigned int u = __float_as_uint(f);
    u += 0x7fffu + ((u >> 16) & 1u);
    return (u16)(u >> 16);
}
__device__ __forceinline__ float bf2f(u16 s) {
    return __uint_as_float(((unsigned int)s) << 16);
}
// raw v_exp_f32 — exp2f w/o fast-math lowers to a ~27-instr ocml polynomial
__device__ __forceinline__ float fast_exp2(float x) {
#if __has_builtin(__builtin_amdgcn_exp2f)
    return __builtin_amdgcn_exp2f(x);
#else
    return __expf(x * 0.69314718056f);
#endif
}

// ---------------- f32 -> bf16 convert ----------------
__global__ __launch_bounds__(256) void f32_to_bf16_kernel(const float* __restrict__ in,
                                                          u16* __restrict__ o, int n) {
    int i = (blockIdx.x * 256 + threadIdx.x) << 2;
    if (i >= n) return;
    float4 f = *(const float4*)&in[i];
    u16x4 r;
    r[0] = f2bf(f.x); r[1] = f2bf(f.y); r[2] = f2bf(f.z); r[3] = f2bf(f.w);
    *(u16x4*)&o[i] = r;
}

// ---------------- W [K][N] f32 -> Wt [N][K] bf16 ----------------
__global__ __launch_bounds__(256) void transpose_w(const float* __restrict__ W,
                                                   u16* __restrict__ Wt, int K, int N) {
    __shared__ float tile[32][33];
    int nb = blockIdx.x << 5, kb = blockIdx.y << 5;
    int tx = threadIdx.x & 31, ty = threadIdx.x >> 5;
#pragma unroll
    for (int r = 0; r < 32; r += 8)
        tile[ty + r][tx] = W[(size_t)(kb + ty + r) * N + nb + tx];
    __syncthreads();
#pragma unroll
    for (int r = 0; r < 32; r += 8)
        Wt[(size_t)(nb + ty + r) * K + kb + tx] = f2bf(tile[tx][ty + r]);
}

// ---------------- GEMM: C[M][N] = A[M][K](bf16) @ Bt[N][K](bf16)^T ----------------
// MODE 0: scatter-epilogue to q,k,v with RoPE fused in-register for q,k.
// MODE 1: fp32 C out.
template <int MODE>
__global__ __launch_bounds__(256) void gemm_bt(const u16* __restrict__ A,
                                               const u16* __restrict__ Bt,
                                               float* __restrict__ Cf,
                                               u16* __restrict__ Qp, u16* __restrict__ Kp,
                                               u16* __restrict__ Vp,
                                               int M, int N, int K) {
    __shared__ __align__(16) u16 Al[128 * 32];
    __shared__ __align__(16) u16 Bl[128 * 32];
    const int tid = threadIdx.x;
    const int Ntiles = N >> 7;
    const int cpx = gridDim.x >> 3;
    const int bid = (int)blockIdx.x;
    const int wg = (bid & 7) * cpx + (bid >> 3);
    const int mt = wg / Ntiles, nt = wg % Ntiles;
    const int m0 = mt << 7, n0 = nt << 7;
    const int wave = tid >> 6, lane = tid & 63;
    const int wm = (wave >> 1) << 6, wn = (wave & 1) << 6;
    const int lr = lane & 15, lk = (lane >> 4) << 3;

    const int srow = (wave << 4) + (lane >> 2);
    const int scol = (lane & 3) << 3;

    f32x4 acc[4][4] = {};

    for (int k0 = 0; k0 < K; k0 += 32) {
        __syncthreads();
#pragma unroll
        for (int i = 0; i < 2; ++i) {
            const u16* ga = &A[(size_t)(m0 + srow + (i << 6)) * K + k0 + scol];
            const u16* gb = &Bt[(size_t)(n0 + srow + (i << 6)) * K + k0 + scol];
            __builtin_amdgcn_global_load_lds(GLB_U32(ga), LDS_U32(&Al[(wave << 9) + (i << 11)]), 16, 0, 0);
            __builtin_amdgcn_global_load_lds(GLB_U32(gb), LDS_U32(&Bl[(wave << 9) + (i << 11)]), 16, 0, 0);
        }
        __syncthreads();
        bf16x8 af[4], bfr[4];
#pragma unroll
        for (int i = 0; i < 4; ++i) {
            af[i]  = __builtin_bit_cast(bf16x8, *(const u16x8*)&Al[(wm + (i << 4) + lr) * 32 + lk]);
            bfr[i] = __builtin_bit_cast(bf16x8, *(const u16x8*)&Bl[(wn + (i << 4) + lr) * 32 + lk]);
        }
#pragma unroll
        for (int i = 0; i < 4; ++i)
#pragma unroll
            for (int j = 0; j < 4; ++j)
                acc[i][j] = __builtin_amdgcn_mfma_f32_16x16x32_bf16(af[i], bfr[j], acc[i][j], 0, 0, 0);
    }

    if (MODE == 0) {
        // wave-uniform q/k/v selector: col = n0 + wn + j*16 + lr, j*16+lr < 64
        const int t = (n0 + wn) >> 10;
        if (t < 2) {
            // fused RoPE on f32 accumulators.
            // d = col & 63 = (j&1)*16 + lr + 32*(j>>1); partner pairs: (j, j^2).
            const float LN1E4_32 = 9.210340371976184f / 32.0f;
            const float invf0 = __expf(-(float)lr * LN1E4_32);
            const float invf1 = __expf(-(float)(lr + 16) * LN1E4_32);
#pragma unroll
            for (int i = 0; i < 4; ++i) {
                const int rbase = m0 + wm + (i << 4) + ((lane >> 4) << 2);
#pragma unroll
                for (int jj = 0; jj < 4; ++jj) {
                    const float s = (float)((rbase + jj) & (S_ - 1));
                    float sn0, c0, sn1, c1;
                    __sincosf(s * invf0, &sn0, &c0);
                    __sincosf(s * invf1, &sn1, &c1);
                    const float v0 = acc[i][0][jj], v1 = acc[i][1][jj];
                    const float v2 = acc[i][2][jj], v3 = acc[i][3][jj];
                    acc[i][0][jj] = v0 * c0 - v2 * sn0;
                    acc[i][2][jj] = v2 * c0 + v0 * sn0;
                    acc[i][1][jj] = v1 * c1 - v3 * sn1;
                    acc[i][3][jj] = v3 * c1 + v1 * sn1;
                }
            }
        }
    }

#pragma unroll
    for (int i = 0; i < 4; ++i) {
#pragma unroll
        for (int j = 0; j < 4; ++j) {
            int rbase = m0 + wm + (i << 4) + ((lane >> 4) << 2);
            int col = n0 + wn + (j << 4) + lr;
#pragma unroll
            for (int jj = 0; jj < 4; ++jj) {
                float val = acc[i][j][jj];
                int row = rbase + jj;
                if (MODE == 0) {
                    int t = col >> 10, rem = col & 1023;
                    int h = rem >> 6, d = rem & 63;
                    int b = row >> 11, s = row & 2047;
                    size_t dst = ((size_t)((b << 4) + h) * S_ + s) * 64 + d;
                    u16 bv = f2bf(val);
                    if (t == 0) Qp[dst] = bv;
                    else if (t == 1) Kp[dst] = bv;
                    else Vp[dst] = bv;
                } else {
                    Cf[(size_t)row * N + col] = val;
                }
            }
        }
    }
}

// ---------------- V [bh][s][64] -> Vt [bh][64][s] ----------------
__global__ __launch_bounds__(256) void vtrans_kernel(const u16* __restrict__ v,
                                                     u16* __restrict__ vt) {
    __shared__ __align__(16) u16 t[64][72];
    const int bh = blockIdx.x >> 5, st = blockIdx.x & 31;
    const size_t base = (size_t)bh * (S_ * 64);
    const int s0 = st << 6;
    const int r = threadIdx.x >> 2, c0 = (threadIdx.x & 3) << 4;
    *(u16x8*)&t[r][c0]     = *(const u16x8*)&v[base + (size_t)(s0 + r) * 64 + c0];
    *(u16x8*)&t[r][c0 + 8] = *(const u16x8*)&v[base + (size_t)(s0 + r) * 64 + c0 + 8];
    __syncthreads();
    u16x8 w0, w1;
#pragma unroll
    for (int i = 0; i < 8; ++i) w0[i] = t[c0 + i][r];
#pragma unroll
    for (int i = 0; i < 8; ++i) w1[i] = t[c0 + 8 + i][r];
    *(u16x8*)&vt[base + (size_t)r * S_ + s0 + c0]     = w0;
    *(u16x8*)&vt[base + (size_t)r * S_ + s0 + c0 + 8] = w1;
}

// ---------------- online-softmax helper: one 32-q-row chain over a 64-kv tile ----------------
__device__ __forceinline__ void softmax_chain(f32x16* p, f32x16* acc,
                                              float& m_run, float& l_run,
                                              u32* wa, u32* wb,
                                              const float* madd_tile, bool hasmask,
                                              float* bcast_w, int c, int hi) {
    if (hasmask) {
#pragma unroll
        for (int tt = 0; tt < 2; ++tt)
#pragma unroll
            for (int rq = 0; rq < 4; ++rq) {
                float4 mf = *(const float4*)&madd_tile[tt * 32 + rq * 8 + hi * 4];
                p[tt][4 * rq + 0] += mf.x;
                p[tt][4 * rq + 1] += mf.y;
                p[tt][4 * rq + 2] += mf.z;
                p[tt][4 * rq + 3] += mf.w;
            }
    }

    // max reduce (v_max3 folding) + cross-half via permlane32_swap
    float tm[16];
#pragma unroll
    for (int r = 0; r < 16; ++r) tm[r] = fmaxf(p[0][r], p[1][r]);
    float a0 = fmaxf(fmaxf(tm[0], tm[1]), tm[2]);
    float a1 = fmaxf(fmaxf(tm[3], tm[4]), tm[5]);
    float a2 = fmaxf(fmaxf(tm[6], tm[7]), tm[8]);
    float a3 = fmaxf(fmaxf(tm[9], tm[10]), tm[11]);
    float a4 = fmaxf(fmaxf(tm[12], tm[13]), tm[14]);
    float b0 = fmaxf(fmaxf(a0, a1), a2);
    float b1 = fmaxf(fmaxf(a3, a4), tm[15]);
    float mx = fmaxf(b0, b1);
    {
        i32x2 mm = __builtin_amdgcn_permlane32_swap(__float_as_int(mx), __float_as_int(mx), false, false);
        mx = fmaxf(__int_as_float(mm[0]), __int_as_float(mm[1]));
    }

    // defer-rescale (T13)
    if (!__all(mx - m_run <= 8.0f)) {
        float mnew = fmaxf(m_run, mx);
        float alpha = fast_exp2(m_run - mnew);
        m_run = mnew;
        l_run *= alpha;
        bcast_w[c] = alpha;
        float avf[16];
#pragma unroll
        for (int rq = 0; rq < 4; ++rq) {
            float4 t4 = *(const float4*)&bcast_w[rq * 8 + hi * 4];
            avf[4 * rq + 0] = t4.x; avf[4 * rq + 1] = t4.y;
            avf[4 * rq + 2] = t4.z; avf[4 * rq + 3] = t4.w;
        }
#pragma unroll
        for (int r = 0; r < 16; ++r) {
            acc[0][r] *= avf[r];
            acc[1][r] *= avf[r];
        }
    }

    // exp (raw v_exp_f32) + 4-way tree sum
    float s4[4] = {0.f, 0.f, 0.f, 0.f};
#pragma unroll
    for (int tt = 0; tt < 2; ++tt)
#pragma unroll
        for (int r = 0; r < 16; ++r) {
            float e = fast_exp2(p[tt][r] - m_run);
            p[tt][r] = e;
            s4[r & 3] += e;
        }
    float ls = (s4[0] + s4[1]) + (s4[2] + s4[3]);
    {
        i32x2 ss = __builtin_amdgcn_permlane32_swap(__float_as_int(ls), __float_as_int(ls), false, false);
        ls = __int_as_float(ss[0]) + __int_as_float(ss[1]);
    }
    l_run += ls;

    // P -> bf16 packed pairs
#pragma unroll
    for (int tt = 0; tt < 2; ++tt)
#pragma unroll
        for (int rq = 0; rq < 4; ++rq) {
            float e0 = p[tt][4 * rq + 0], e1 = p[tt][4 * rq + 1];
            float e2 = p[tt][4 * rq + 2], e3 = p[tt][4 * rq + 3];
            u32 w0, w1;
            asm("v_cvt_pk_bf16_f32 %0, %1, %2" : "=v"(w0) : "v"(e0), "v"(e1));
            asm("v_cvt_pk_bf16_f32 %0, %1, %2" : "=v"(w1) : "v"(e2), "v"(e3));
            wa[4 * tt + rq] = w0;
            wb[4 * tt + rq] = w1;
        }
}

// ---------------- flash attention: 4 waves x 2x32 q-rows, swapped QK^T, KVBLK=64 ----------------
// single-barrier double-buffered pipeline; each wave owns TWO 32-row q-tiles (A: rows qt*256+w*32,
// B: +128) against the shared K/V tile -> staging/barrier/frag-reads amortized 2x, ILP doubled.
__global__ __launch_bounds__(256, 2) void attn_kernel(const u16* __restrict__ q,
                                                      const u16* __restrict__ k,
                                                      const u16* __restrict__ vt,
                                                      const float* __restrict__ mask,
                                                      u16* __restrict__ outp) {
    __shared__ __align__(16) u16 Kl[2][64 * 64];
    __shared__ __align__(16) u16 Vl[2][64 * 64];
    __shared__ float madd2[2][64];
    __shared__ float bcast[4][32];

    const int tid = threadIdx.x, wave = tid >> 6, lane = tid & 63;
    const int c = lane & 31, hi = lane >> 5, c7 = c & 7;
    const int bh = blockIdx.x & 63, qt = blockIdx.x >> 6;   // qt in [0,8)
    const int b = bh >> 4, h = bh & 15;
    const size_t base = (size_t)bh * (S_ * 64);
    const int qrowA = (qt << 8) + (wave << 5) + c;
    const int qrowB = qrowA + 128;

    const float QS = 0.18033688f;  // 0.125 * log2(e)

    bf16x8 qfA[4], qfB[4];
#pragma unroll
    for (int j = 0; j < 4; ++j) {
        u16x8 rawA = *(const u16x8*)&q[base + (size_t)qrowA * 64 + j * 16 + hi * 8];
        u16x8 rawB = *(const u16x8*)&q[base + (size_t)qrowB * 64 + j * 16 + hi * 8];
        u16x8 scA, scB;
#pragma unroll
        for (int e = 0; e < 8; ++e) {
            scA[e] = f2bf(bf2f(rawA[e]) * QS);
            scB[e] = f2bf(bf2f(rawB[e]) * QS);
        }
        qfA[j] = __builtin_bit_cast(bf16x8, scA);
        qfB[j] = __builtin_bit_cast(bf16x8, scB);
    }

    f32x16 accA[2] = {}, accB[2] = {};
    float m_runA = -1e30f, l_runA = 0.f;
    float m_runB = -1e30f, l_runB = 0.f;

    const int sr = tid >> 2, su = (tid & 3) << 1;
    const int so0 = sr * 64 + ((su ^ (sr & 7)) << 3);
    const int so1 = sr * 64 + (((su + 1) ^ (sr & 7)) << 3);

    // prologue: tile 0 into regs
    u16x8 kc0 = *(const u16x8*)&k[base + (size_t)sr * 64 + su * 8];
    u16x8 kc1 = *(const u16x8*)&k[base + (size_t)sr * 64 + su * 8 + 8];
    u16x8 vc0 = *(const u16x8*)&vt[base + (size_t)sr * S_ + su * 8];
    u16x8 vc1 = *(const u16x8*)&vt[base + (size_t)sr * S_ + su * 8 + 8];
    float mval = (tid < 64) ? mask[b * S_ + tid] : 1.0f;

    for (int t = 0; t < 32; ++t) {
        const int bi = t & 1;
        u16* Kb = &Kl[bi][0];
        u16* Vb = &Vl[bi][0];
        *(u16x8*)&Kb[so0] = kc0;
        *(u16x8*)&Kb[so1] = kc1;
        *(u16x8*)&Vb[so0] = vc0;
        *(u16x8*)&Vb[so1] = vc1;
        if (tid < 64) madd2[bi][tid] = (1.0f - mval) * -1.44269504e9f;
        if (t + 1 < 32) {
            const int kn = (t + 1) << 6;
            kc0 = *(const u16x8*)&k[base + (size_t)(kn + sr) * 64 + su * 8];
            kc1 = *(const u16x8*)&k[base + (size_t)(kn + sr) * 64 + su * 8 + 8];
            vc0 = *(const u16x8*)&vt[base + (size_t)sr * S_ + kn + su * 8];
            vc1 = *(const u16x8*)&vt[base + (size_t)sr * S_ + kn + su * 8 + 8];
            mval = (tid < 64) ? mask[b * S_ + kn + tid] : 1.0f;
        }
        __syncthreads();  // buf[bi] ready

        // S^T = K * Q^T : shared K-fragments feed both A and B chains
        f32x16 pA[2] = {}, pB[2] = {};
        __builtin_amdgcn_s_setprio(1);
#pragma unroll
        for (int j = 0; j < 4; ++j) {
            const int uo = ((2 * j + hi) ^ c7) << 3;
            bf16x8 ka  = __builtin_bit_cast(bf16x8, *(const u16x8*)&Kb[c * 64 + uo]);
            bf16x8 kb2 = __builtin_bit_cast(bf16x8, *(const u16x8*)&Kb[(32 + c) * 64 + uo]);
            pA[0] = __builtin_amdgcn_mfma_f32_32x32x16_bf16(ka,  qfA[j], pA[0], 0, 0, 0);
            pA[1] = __builtin_amdgcn_mfma_f32_32x32x16_bf16(kb2, qfA[j], pA[1], 0, 0, 0);
            pB[0] = __builtin_amdgcn_mfma_f32_32x32x16_bf16(ka,  qfB[j], pB[0], 0, 0, 0);
            pB[1] = __builtin_amdgcn_mfma_f32_32x32x16_bf16(kb2, qfB[j], pB[1], 0, 0, 0);
        }
        __builtin_amdgcn_s_setprio(0);

        bool hasmask = __any(madd2[bi][lane] != 0.0f);

        u32 waA[8], wbA[8], waB[8], wbB[8];
        softmax_chain(pA, accA, m_runA, l_runA, waA, wbA, &madd2[bi][0], hasmask, &bcast[wave][0], c, hi);
        softmax_chain(pB, accB, m_runB, l_runB, waB, wbB, &madd2[bi][0], hasmask, &bcast[wave][0], c, hi);

        // O += P * V : shared V-fragments feed both chains
        __builtin_amdgcn_s_setprio(1);
#pragma unroll
        for (int ks = 0; ks < 4; ++ks) {
            i32x2 raA = __builtin_amdgcn_permlane32_swap((int)waA[2 * ks], (int)waA[2 * ks + 1], false, false);
            i32x2 rbA = __builtin_amdgcn_permlane32_swap((int)wbA[2 * ks], (int)wbA[2 * ks + 1], false, false);
            i32x2 raB = __builtin_amdgcn_permlane32_swap((int)waB[2 * ks], (int)waB[2 * ks + 1], false, false);
            i32x2 rbB = __builtin_amdgcn_permlane32_swap((int)wbB[2 * ks], (int)wbB[2 * ks + 1], false, false);
            u32x4 pwA, pwB;
            pwA[0] = (u32)raA[0]; pwA[1] = (u32)rbA[0]; pwA[2] = (u32)raA[1]; pwA[3] = (u32)rbA[1];
            pwB[0] = (u32)raB[0]; pwB[1] = (u32)rbB[0]; pwB[2] = (u32)raB[1]; pwB[3] = (u32)rbB[1];
            bf16x8 pafA = __builtin_bit_cast(bf16x8, pwA);
            bf16x8 pafB = __builtin_bit_cast(bf16x8, pwB);
            const int uo = ((2 * ks + hi) ^ c7) << 3;
#pragma unroll
            for (int dt = 0; dt < 2; ++dt) {
                bf16x8 vf = __builtin_bit_cast(bf16x8,
                            *(const u16x8*)&Vb[(32 * dt + c) * 64 + uo]);
                accA[dt] = __builtin_amdgcn_mfma_f32_32x32x16_bf16(pafA, vf, accA[dt], 0, 0, 0);
                accB[dt] = __builtin_amdgcn_mfma_f32_32x32x16_bf16(pafB, vf, accB[dt], 0, 0, 0);
            }
        }
        __builtin_amdgcn_s_setprio(0);
        // no second barrier: next iter writes the other buffer
    }

    // epilogue A
    {
        bcast[wave][c] = l_runA;
        __builtin_amdgcn_wave_barrier();
        float lvf[16];
#pragma unroll
        for (int rq = 0; rq < 4; ++rq) {
            float4 t4 = *(const float4*)&bcast[wave][rq * 8 + hi * 4];
            lvf[4 * rq + 0] = __builtin_amdgcn_rcpf(t4.x);
            lvf[4 * rq + 1] = __builtin_amdgcn_rcpf(t4.y);
            lvf[4 * rq + 2] = __builtin_amdgcn_rcpf(t4.z);
            lvf[4 * rq + 3] = __builtin_amdgcn_rcpf(t4.w);
        }
        const size_t orow0 = (size_t)b * S_ + (qt << 8) + (wave << 5);
#pragma unroll
        for (int dt = 0; dt < 2; ++dt)
#pragma unroll
            for (int r = 0; r < 16; ++r) {
                int qr = (r & 3) + 8 * (r >> 2) + 4 * hi;
                outp[(orow0 + qr) * DM + h * 64 + dt * 32 + c] = f2bf(accA[dt][r] * lvf[r]);
            }
    }
    // epilogue B
    {
        __builtin_amdgcn_wave_barrier();
        bcast[wave][c] = l_runB;
        __builtin_amdgcn_wave_barrier();
        float lvf[16];
#pragma unroll
        for (int rq = 0; rq < 4; ++rq) {
            float4 t4 = *(const float4*)&bcast[wave][rq * 8 + hi * 4];
            lvf[4 * rq + 0] = __builtin_amdgcn_rcpf(t4.x);
            lvf[4 * rq + 1] = __builtin_amdgcn_rcpf(t4.y);
            lvf[4 * rq + 2] = __builtin_amdgcn_rcpf(t4.z);
            lvf[4 * rq + 3] = __builtin_amdgcn_rcpf(t4.w);
        }
        const size_t orow0 = (size_t)b * S_ + (qt << 8) + (wave << 5) + 128;
#pragma unroll
        for (int dt = 0; dt < 2; ++dt)
#pragma unroll
            for (int r = 0; r < 16; ++r) {
                int qr = (r & 3) + 8 * (r >> 2) + 4 * hi;
                outp[(orow0 + qr) * DM + h * 64 + dt * 32 + c] = f2bf(accB[dt][r] * lvf[r]);
            }
    }
}

extern "C" void kernel_launch(void* const* d_in, const int* in_sizes, int n_in,
                              void* d_out, int out_size, void* d_ws, size_t ws_size,
                              hipStream_t stream) {
    const float* x    = (const float*)d_in[0];
    const float* mask = (const float*)d_in[1];
    const float* Wqkv = (const float*)d_in[2];
    const float* Wout = (const float*)d_in[3];
    float* out = (float*)d_out;
    char* ws = (char*)d_ws;
    const size_t MB = 1u << 20;
    u16* xb    = (u16*)(ws);
    u16* WqkvT = (u16*)(ws + 16 * MB);
    u16* WoutT = (u16*)(ws + 22 * MB);
    u16* qb    = (u16*)(ws + 24 * MB);
    u16* kb    = (u16*)(ws + 40 * MB);
    u16* vb    = (u16*)(ws + 56 * MB);
    u16* vtb   = xb;
    u16* ao    = vb;

    f32_to_bf16_kernel<<<8192, 256, 0, stream>>>(x, xb, 8192 * 1024);
    transpose_w<<<dim3(96, 32), 256, 0, stream>>>(Wqkv, WqkvT, 1024, 3072);
    transpose_w<<<dim3(32, 32), 256, 0, stream>>>(Wout, WoutT, 1024, 1024);
    gemm_bt<0><<<64 * 24, 256, 0, stream>>>(xb, WqkvT, nullptr, qb, kb, vb, 8192, 3072, 1024);
    vtrans_kernel<<<2048, 256, 0, stream>>>(vb, vtb);
    attn_kernel<<<512, 256, 0, stream>>>(qb, kb, vtb, mask, ao);
    gemm_bt<1><<<64 * 8, 256, 0, stream>>>(ao, WoutT, out, nullptr, nullptr, nullptr, 8192, 1024, 1024);
}

// Round 8
// 218.465 us; speedup vs baseline: 1.6691x; 1.0207x over previous
//
#include <hip/hip_runtime.h>

typedef unsigned short u16;
typedef unsigned int u32;
typedef int i32x2 __attribute__((ext_vector_type(2)));
typedef float f32x4 __attribute__((ext_vector_type(4)));
typedef float f32x16 __attribute__((ext_vector_type(16)));
typedef __bf16 bf16x8 __attribute__((ext_vector_type(8)));
typedef unsigned short u16x8 __attribute__((ext_vector_type(8)));
typedef unsigned short u16x4 __attribute__((ext_vector_type(4)));
typedef unsigned int u32x4 __attribute__((ext_vector_type(4)));

#define S_ 2048
#define DM 1024

#define LDS_U32(p) ((__attribute__((address_space(3))) unsigned int*)(p))
#define GLB_U32(p) ((const __attribute__((address_space(1))) unsigned int*)(p))

__device__ __forceinline__ u16 f2bf(float f) {
    unsigned int u = __float_as_uint(f);
    u += 0x7fffu + ((u >> 16) & 1u);
    return (u16)(u >> 16);
}
__device__ __forceinline__ float bf2f(u16 s) {
    return __uint_as_float(((unsigned int)s) << 16);
}
// raw v_exp_f32 — exp2f w/o fast-math lowers to a ~27-instr ocml polynomial
__device__ __forceinline__ float fast_exp2(float x) {
#if __has_builtin(__builtin_amdgcn_exp2f)
    return __builtin_amdgcn_exp2f(x);
#else
    return __expf(x * 0.69314718056f);
#endif
}

// ---------------- f32 -> bf16 convert ----------------
__global__ __launch_bounds__(256) void f32_to_bf16_kernel(const float* __restrict__ in,
                                                          u16* __restrict__ o, int n) {
    int i = (blockIdx.x * 256 + threadIdx.x) << 2;
    if (i >= n) return;
    float4 f = *(const float4*)&in[i];
    u16x4 r;
    r[0] = f2bf(f.x); r[1] = f2bf(f.y); r[2] = f2bf(f.z); r[3] = f2bf(f.w);
    *(u16x4*)&o[i] = r;
}

// ---------------- W [K][N] f32 -> Wt [N][K] bf16 ----------------
__global__ __launch_bounds__(256) void transpose_w(const float* __restrict__ W,
                                                   u16* __restrict__ Wt, int K, int N) {
    __shared__ float tile[32][33];
    int nb = blockIdx.x << 5, kb = blockIdx.y << 5;
    int tx = threadIdx.x & 31, ty = threadIdx.x >> 5;
#pragma unroll
    for (int r = 0; r < 32; r += 8)
        tile[ty + r][tx] = W[(size_t)(kb + ty + r) * N + nb + tx];
    __syncthreads();
#pragma unroll
    for (int r = 0; r < 32; r += 8)
        Wt[(size_t)(nb + ty + r) * K + kb + tx] = f2bf(tile[tx][ty + r]);
}

// ---------------- GEMM: C[M][N] = A[M][K](bf16) @ Bt[N][K](bf16)^T ----------------
// MODE 0: scatter-epilogue to q,k (RoPE fused in-register) and V written TRANSPOSED
//         directly to vt[bh][64][s] (u16x4 stores, vtrans kernel eliminated).
// MODE 1: fp32 C out.
template <int MODE>
__global__ __launch_bounds__(256) void gemm_bt(const u16* __restrict__ A,
                                               const u16* __restrict__ Bt,
                                               float* __restrict__ Cf,
                                               u16* __restrict__ Qp, u16* __restrict__ Kp,
                                               u16* __restrict__ Vtp,
                                               int M, int N, int K) {
    __shared__ __align__(16) u16 Al[128 * 32];
    __shared__ __align__(16) u16 Bl[128 * 32];
    const int tid = threadIdx.x;
    const int Ntiles = N >> 7;
    const int cpx = gridDim.x >> 3;
    const int bid = (int)blockIdx.x;
    const int wg = (bid & 7) * cpx + (bid >> 3);
    const int mt = wg / Ntiles, nt = wg % Ntiles;
    const int m0 = mt << 7, n0 = nt << 7;
    const int wave = tid >> 6, lane = tid & 63;
    const int wm = (wave >> 1) << 6, wn = (wave & 1) << 6;
    const int lr = lane & 15, lk = (lane >> 4) << 3;

    const int srow = (wave << 4) + (lane >> 2);
    const int scol = (lane & 3) << 3;

    f32x4 acc[4][4] = {};

    for (int k0 = 0; k0 < K; k0 += 32) {
        __syncthreads();
#pragma unroll
        for (int i = 0; i < 2; ++i) {
            const u16* ga = &A[(size_t)(m0 + srow + (i << 6)) * K + k0 + scol];
            const u16* gb = &Bt[(size_t)(n0 + srow + (i << 6)) * K + k0 + scol];
            __builtin_amdgcn_global_load_lds(GLB_U32(ga), LDS_U32(&Al[(wave << 9) + (i << 11)]), 16, 0, 0);
            __builtin_amdgcn_global_load_lds(GLB_U32(gb), LDS_U32(&Bl[(wave << 9) + (i << 11)]), 16, 0, 0);
        }
        __syncthreads();
        bf16x8 af[4], bfr[4];
#pragma unroll
        for (int i = 0; i < 4; ++i) {
            af[i]  = __builtin_bit_cast(bf16x8, *(const u16x8*)&Al[(wm + (i << 4) + lr) * 32 + lk]);
            bfr[i] = __builtin_bit_cast(bf16x8, *(const u16x8*)&Bl[(wn + (i << 4) + lr) * 32 + lk]);
        }
#pragma unroll
        for (int i = 0; i < 4; ++i)
#pragma unroll
            for (int j = 0; j < 4; ++j)
                acc[i][j] = __builtin_amdgcn_mfma_f32_16x16x32_bf16(af[i], bfr[j], acc[i][j], 0, 0, 0);
    }

    if (MODE == 0) {
        // wave-uniform q/k/v selector
        const int t = (n0 + wn) >> 10;
        if (t < 2) {
            // fused RoPE on f32 accumulators; partner pairs (j, j^2).
            const float LN1E4_32 = 9.210340371976184f / 32.0f;
            const float invf0 = __expf(-(float)lr * LN1E4_32);
            const float invf1 = __expf(-(float)(lr + 16) * LN1E4_32);
#pragma unroll
            for (int i = 0; i < 4; ++i) {
                const int rbase = m0 + wm + (i << 4) + ((lane >> 4) << 2);
#pragma unroll
                for (int jj = 0; jj < 4; ++jj) {
                    const float s = (float)((rbase + jj) & (S_ - 1));
                    float sn0, c0, sn1, c1;
                    __sincosf(s * invf0, &sn0, &c0);
                    __sincosf(s * invf1, &sn1, &c1);
                    const float v0 = acc[i][0][jj], v1 = acc[i][1][jj];
                    const float v2 = acc[i][2][jj], v3 = acc[i][3][jj];
                    acc[i][0][jj] = v0 * c0 - v2 * sn0;
                    acc[i][2][jj] = v2 * c0 + v0 * sn0;
                    acc[i][1][jj] = v1 * c1 - v3 * sn1;
                    acc[i][3][jj] = v3 * c1 + v1 * sn1;
                }
            }
            u16* P = (t == 0) ? Qp : Kp;
#pragma unroll
            for (int i = 0; i < 4; ++i) {
#pragma unroll
                for (int j = 0; j < 4; ++j) {
                    int rbase = m0 + wm + (i << 4) + ((lane >> 4) << 2);
                    int col = n0 + wn + (j << 4) + lr;
                    int h = (col & 1023) >> 6, d = col & 63;
#pragma unroll
                    for (int jj = 0; jj < 4; ++jj) {
                        int row = rbase + jj;
                        int b = row >> 11, s = row & 2047;
                        P[((size_t)((b << 4) + h) * S_ + s) * 64 + d] = f2bf(acc[i][j][jj]);
                    }
                }
            }
        } else {
            // V: write transposed vt[bh][d][s], 4 consecutive s -> one u16x4 store
#pragma unroll
            for (int i = 0; i < 4; ++i) {
                const int rbase = m0 + wm + (i << 4) + ((lane >> 4) << 2);
                const int b = rbase >> 11, sb = rbase & 2047;
#pragma unroll
                for (int j = 0; j < 4; ++j) {
                    int col = n0 + wn + (j << 4) + lr;
                    int h = (col & 1023) >> 6, d = col & 63;
                    u16x4 pk;
#pragma unroll
                    for (int jj = 0; jj < 4; ++jj) pk[jj] = f2bf(acc[i][j][jj]);
                    *(u16x4*)&Vtp[((size_t)((b << 4) + h) * 64 + d) * S_ + sb] = pk;
                }
            }
        }
    } else {
#pragma unroll
        for (int i = 0; i < 4; ++i)
#pragma unroll
            for (int j = 0; j < 4; ++j) {
                int rbase = m0 + wm + (i << 4) + ((lane >> 4) << 2);
                int col = n0 + wn + (j << 4) + lr;
#pragma unroll
                for (int jj = 0; jj < 4; ++jj)
                    Cf[(size_t)(rbase + jj) * N + col] = acc[i][j][jj];
            }
    }
}

// ---------------- online-softmax helper: one 32-q-row chain over a 64-kv tile ----------------
// l is NOT tracked here: row-sums accumulate via MFMA(ones) in the PV loop (accS).
__device__ __forceinline__ void softmax_chain(f32x16* p, f32x16* acc, f32x16& accS,
                                              float& m_run, u32* wa, u32* wb,
                                              const float* madd_tile, bool hasmask,
                                              float* bcast_w, int c, int hi) {
    if (hasmask) {
#pragma unroll
        for (int tt = 0; tt < 2; ++tt)
#pragma unroll
            for (int rq = 0; rq < 4; ++rq) {
                float4 mf = *(const float4*)&madd_tile[tt * 32 + rq * 8 + hi * 4];
                p[tt][4 * rq + 0] += mf.x;
                p[tt][4 * rq + 1] += mf.y;
                p[tt][4 * rq + 2] += mf.z;
                p[tt][4 * rq + 3] += mf.w;
            }
    }

    // max reduce (v_max3 folding) + cross-half via permlane32_swap
    float tm[16];
#pragma unroll
    for (int r = 0; r < 16; ++r) tm[r] = fmaxf(p[0][r], p[1][r]);
    float a0 = fmaxf(fmaxf(tm[0], tm[1]), tm[2]);
    float a1 = fmaxf(fmaxf(tm[3], tm[4]), tm[5]);
    float a2 = fmaxf(fmaxf(tm[6], tm[7]), tm[8]);
    float a3 = fmaxf(fmaxf(tm[9], tm[10]), tm[11]);
    float a4 = fmaxf(fmaxf(tm[12], tm[13]), tm[14]);
    float b0 = fmaxf(fmaxf(a0, a1), a2);
    float b1 = fmaxf(fmaxf(a3, a4), tm[15]);
    float mx = fmaxf(b0, b1);
    {
        i32x2 mm = __builtin_amdgcn_permlane32_swap(__float_as_int(mx), __float_as_int(mx), false, false);
        mx = fmaxf(__int_as_float(mm[0]), __int_as_float(mm[1]));
    }

    // defer-rescale (T13): acc AND accS share the same [r] row layout
    if (!__all(mx - m_run <= 8.0f)) {
        float mnew = fmaxf(m_run, mx);
        float alpha = fast_exp2(m_run - mnew);
        m_run = mnew;
        bcast_w[c] = alpha;
        float avf[16];
#pragma unroll
        for (int rq = 0; rq < 4; ++rq) {
            float4 t4 = *(const float4*)&bcast_w[rq * 8 + hi * 4];
            avf[4 * rq + 0] = t4.x; avf[4 * rq + 1] = t4.y;
            avf[4 * rq + 2] = t4.z; avf[4 * rq + 3] = t4.w;
        }
#pragma unroll
        for (int r = 0; r < 16; ++r) {
            acc[0][r] *= avf[r];
            acc[1][r] *= avf[r];
            accS[r]   *= avf[r];
        }
    }

    // exp (raw v_exp_f32); sum handled by MFMA(ones) downstream
#pragma unroll
    for (int tt = 0; tt < 2; ++tt)
#pragma unroll
        for (int r = 0; r < 16; ++r)
            p[tt][r] = fast_exp2(p[tt][r] - m_run);

    // P -> bf16 packed pairs
#pragma unroll
    for (int tt = 0; tt < 2; ++tt)
#pragma unroll
        for (int rq = 0; rq < 4; ++rq) {
            float e0 = p[tt][4 * rq + 0], e1 = p[tt][4 * rq + 1];
            float e2 = p[tt][4 * rq + 2], e3 = p[tt][4 * rq + 3];
            u32 w0, w1;
            asm("v_cvt_pk_bf16_f32 %0, %1, %2" : "=v"(w0) : "v"(e0), "v"(e1));
            asm("v_cvt_pk_bf16_f32 %0, %1, %2" : "=v"(w1) : "v"(e2), "v"(e3));
            wa[4 * tt + rq] = w0;
            wb[4 * tt + rq] = w1;
        }
}

// ---------------- flash attention: 4 waves x 2x32 q-rows, swapped QK^T, KVBLK=64 ----------------
__global__ __launch_bounds__(256, 2) void attn_kernel(const u16* __restrict__ q,
                                                      const u16* __restrict__ k,
                                                      const u16* __restrict__ vt,
                                                      const float* __restrict__ mask,
                                                      u16* __restrict__ outp) {
    __shared__ __align__(16) u16 Kl[2][64 * 64];
    __shared__ __align__(16) u16 Vl[2][64 * 64];
    __shared__ float madd2[2][64];
    __shared__ float bcast[4][32];

    const int tid = threadIdx.x, wave = tid >> 6, lane = tid & 63;
    const int c = lane & 31, hi = lane >> 5, c7 = c & 7;
    const int bh = blockIdx.x & 63, qt = blockIdx.x >> 6;   // qt in [0,8)
    const int b = bh >> 4, h = bh & 15;
    const size_t base = (size_t)bh * (S_ * 64);
    const int qrowA = (qt << 8) + (wave << 5) + c;
    const int qrowB = qrowA + 128;

    const float QS = 0.18033688f;  // 0.125 * log2(e)

    bf16x8 qfA[4], qfB[4];
#pragma unroll
    for (int j = 0; j < 4; ++j) {
        u16x8 rawA = *(const u16x8*)&q[base + (size_t)qrowA * 64 + j * 16 + hi * 8];
        u16x8 rawB = *(const u16x8*)&q[base + (size_t)qrowB * 64 + j * 16 + hi * 8];
        u16x8 scA, scB;
#pragma unroll
        for (int e = 0; e < 8; ++e) {
            scA[e] = f2bf(bf2f(rawA[e]) * QS);
            scB[e] = f2bf(bf2f(rawB[e]) * QS);
        }
        qfA[j] = __builtin_bit_cast(bf16x8, scA);
        qfB[j] = __builtin_bit_cast(bf16x8, scB);
    }

    // ones B-fragment: every output col gets the row-sum (free broadcast)
    u16x8 ou;
#pragma unroll
    for (int e = 0; e < 8; ++e) ou[e] = 0x3F80;
    const bf16x8 onesf = __builtin_bit_cast(bf16x8, ou);

    f32x16 accA[2] = {}, accB[2] = {};
    f32x16 accSA = {}, accSB = {};
    float m_runA = -1e30f, m_runB = -1e30f;

    const int sr = tid >> 2, su = (tid & 3) << 1;
    const int so0 = sr * 64 + ((su ^ (sr & 7)) << 3);
    const int so1 = sr * 64 + (((su + 1) ^ (sr & 7)) << 3);

    // prologue: tile 0 into regs
    u16x8 kc0 = *(const u16x8*)&k[base + (size_t)sr * 64 + su * 8];
    u16x8 kc1 = *(const u16x8*)&k[base + (size_t)sr * 64 + su * 8 + 8];
    u16x8 vc0 = *(const u16x8*)&vt[base + (size_t)sr * S_ + su * 8];
    u16x8 vc1 = *(const u16x8*)&vt[base + (size_t)sr * S_ + su * 8 + 8];
    float mval = (tid < 64) ? mask[b * S_ + tid] : 1.0f;

    for (int t = 0; t < 32; ++t) {
        const int bi = t & 1;
        u16* Kb = &Kl[bi][0];
        u16* Vb = &Vl[bi][0];
        *(u16x8*)&Kb[so0] = kc0;
        *(u16x8*)&Kb[so1] = kc1;
        *(u16x8*)&Vb[so0] = vc0;
        *(u16x8*)&Vb[so1] = vc1;
        if (tid < 64) madd2[bi][tid] = (1.0f - mval) * -1.44269504e9f;
        if (t + 1 < 32) {
            const int kn = (t + 1) << 6;
            kc0 = *(const u16x8*)&k[base + (size_t)(kn + sr) * 64 + su * 8];
            kc1 = *(const u16x8*)&k[base + (size_t)(kn + sr) * 64 + su * 8 + 8];
            vc0 = *(const u16x8*)&vt[base + (size_t)sr * S_ + kn + su * 8];
            vc1 = *(const u16x8*)&vt[base + (size_t)sr * S_ + kn + su * 8 + 8];
            mval = (tid < 64) ? mask[b * S_ + kn + tid] : 1.0f;
        }
        __syncthreads();  // buf[bi] ready

        // S^T = K * Q^T : shared K-fragments feed both A and B chains
        f32x16 pA[2] = {}, pB[2] = {};
        __builtin_amdgcn_s_setprio(1);
#pragma unroll
        for (int j = 0; j < 4; ++j) {
            const int uo = ((2 * j + hi) ^ c7) << 3;
            bf16x8 ka  = __builtin_bit_cast(bf16x8, *(const u16x8*)&Kb[c * 64 + uo]);
            bf16x8 kb2 = __builtin_bit_cast(bf16x8, *(const u16x8*)&Kb[(32 + c) * 64 + uo]);
            pA[0] = __builtin_amdgcn_mfma_f32_32x32x16_bf16(ka,  qfA[j], pA[0], 0, 0, 0);
            pA[1] = __builtin_amdgcn_mfma_f32_32x32x16_bf16(kb2, qfA[j], pA[1], 0, 0, 0);
            pB[0] = __builtin_amdgcn_mfma_f32_32x32x16_bf16(ka,  qfB[j], pB[0], 0, 0, 0);
            pB[1] = __builtin_amdgcn_mfma_f32_32x32x16_bf16(kb2, qfB[j], pB[1], 0, 0, 0);
        }
        __builtin_amdgcn_s_setprio(0);

        bool hasmask = __any(madd2[bi][lane] != 0.0f);

        u32 waA[8], wbA[8], waB[8], wbB[8];
        softmax_chain(pA, accA, accSA, m_runA, waA, wbA, &madd2[bi][0], hasmask, &bcast[wave][0], c, hi);
        softmax_chain(pB, accB, accSB, m_runB, waB, wbB, &madd2[bi][0], hasmask, &bcast[wave][0], c, hi);

        // O += P * V ; l += P * 1 (MFMA row-sum, every lane gets it)
        __builtin_amdgcn_s_setprio(1);
#pragma unroll
        for (int ks = 0; ks < 4; ++ks) {
            i32x2 raA = __builtin_amdgcn_permlane32_swap((int)waA[2 * ks], (int)waA[2 * ks + 1], false, false);
            i32x2 rbA = __builtin_amdgcn_permlane32_swap((int)wbA[2 * ks], (int)wbA[2 * ks + 1], false, false);
            i32x2 raB = __builtin_amdgcn_permlane32_swap((int)waB[2 * ks], (int)waB[2 * ks + 1], false, false);
            i32x2 rbB = __builtin_amdgcn_permlane32_swap((int)wbB[2 * ks], (int)wbB[2 * ks + 1], false, false);
            u32x4 pwA, pwB;
            pwA[0] = (u32)raA[0]; pwA[1] = (u32)rbA[0]; pwA[2] = (u32)raA[1]; pwA[3] = (u32)rbA[1];
            pwB[0] = (u32)raB[0]; pwB[1] = (u32)rbB[0]; pwB[2] = (u32)raB[1]; pwB[3] = (u32)rbB[1];
            bf16x8 pafA = __builtin_bit_cast(bf16x8, pwA);
            bf16x8 pafB = __builtin_bit_cast(bf16x8, pwB);
            accSA = __builtin_amdgcn_mfma_f32_32x32x16_bf16(pafA, onesf, accSA, 0, 0, 0);
            accSB = __builtin_amdgcn_mfma_f32_32x32x16_bf16(pafB, onesf, accSB, 0, 0, 0);
            const int uo = ((2 * ks + hi) ^ c7) << 3;
#pragma unroll
            for (int dt = 0; dt < 2; ++dt) {
                bf16x8 vf = __builtin_bit_cast(bf16x8,
                            *(const u16x8*)&Vb[(32 * dt + c) * 64 + uo]);
                accA[dt] = __builtin_amdgcn_mfma_f32_32x32x16_bf16(pafA, vf, accA[dt], 0, 0, 0);
                accB[dt] = __builtin_amdgcn_mfma_f32_32x32x16_bf16(pafB, vf, accB[dt], 0, 0, 0);
            }
        }
        __builtin_amdgcn_s_setprio(0);
        // no second barrier: next iter writes the other buffer
    }

    // epilogues: l lives in accS[r] already in the acc layout — no LDS broadcast
    {
        const size_t orow0 = (size_t)b * S_ + (qt << 8) + (wave << 5);
#pragma unroll
        for (int dt = 0; dt < 2; ++dt)
#pragma unroll
            for (int r = 0; r < 16; ++r) {
                int qr = (r & 3) + 8 * (r >> 2) + 4 * hi;
                outp[(orow0 + qr) * DM + h * 64 + dt * 32 + c] =
                    f2bf(accA[dt][r] * __builtin_amdgcn_rcpf(accSA[r]));
            }
    }
    {
        const size_t orow0 = (size_t)b * S_ + (qt << 8) + (wave << 5) + 128;
#pragma unroll
        for (int dt = 0; dt < 2; ++dt)
#pragma unroll
            for (int r = 0; r < 16; ++r) {
                int qr = (r & 3) + 8 * (r >> 2) + 4 * hi;
                outp[(orow0 + qr) * DM + h * 64 + dt * 32 + c] =
                    f2bf(accB[dt][r] * __builtin_amdgcn_rcpf(accSB[r]));
            }
    }
}

extern "C" void kernel_launch(void* const* d_in, const int* in_sizes, int n_in,
                              void* d_out, int out_size, void* d_ws, size_t ws_size,
                              hipStream_t stream) {
    const float* x    = (const float*)d_in[0];
    const float* mask = (const float*)d_in[1];
    const float* Wqkv = (const float*)d_in[2];
    const float* Wout = (const float*)d_in[3];
    float* out = (float*)d_out;
    char* ws = (char*)d_ws;
    const size_t MB = 1u << 20;
    u16* xb    = (u16*)(ws);            // 16 MB: x bf16; reused as attn-out after gemm0
    u16* WqkvT = (u16*)(ws + 16 * MB);  // 6 MB
    u16* WoutT = (u16*)(ws + 22 * MB);  // 2 MB
    u16* qb    = (u16*)(ws + 24 * MB);  // 16 MB [bh][s][64]
    u16* kb    = (u16*)(ws + 40 * MB);  // 16 MB [bh][s][64]
    u16* vtb   = (u16*)(ws + 56 * MB);  // 16 MB [bh][64][s] (written directly by gemm0)
    u16* ao    = xb;                    // attention out (xb dead after gemm0)

    f32_to_bf16_kernel<<<8192, 256, 0, stream>>>(x, xb, 8192 * 1024);
    transpose_w<<<dim3(96, 32), 256, 0, stream>>>(Wqkv, WqkvT, 1024, 3072);
    transpose_w<<<dim3(32, 32), 256, 0, stream>>>(Wout, WoutT, 1024, 1024);
    gemm_bt<0><<<64 * 24, 256, 0, stream>>>(xb, WqkvT, nullptr, qb, kb, vtb, 8192, 3072, 1024);
    attn_kernel<<<512, 256, 0, stream>>>(qb, kb, vtb, mask, ao);
    gemm_bt<1><<<64 * 8, 256, 0, stream>>>(ao, WoutT, out, nullptr, nullptr, nullptr, 8192, 1024, 1024);
}

// Round 10
// 210.742 us; speedup vs baseline: 1.7303x; 1.0367x over previous
//
#include <hip/hip_runtime.h>

typedef unsigned short u16;
typedef unsigned int u32;
typedef int i32x2 __attribute__((ext_vector_type(2)));
typedef float f32x4 __attribute__((ext_vector_type(4)));
typedef float f32x16 __attribute__((ext_vector_type(16)));
typedef __bf16 bf16x8 __attribute__((ext_vector_type(8)));
typedef unsigned short u16x8 __attribute__((ext_vector_type(8)));
typedef unsigned short u16x4 __attribute__((ext_vector_type(4)));
typedef unsigned int u32x4 __attribute__((ext_vector_type(4)));

#define S_ 2048
#define DM 1024

#define LDS_U32(p) ((__attribute__((address_space(3))) unsigned int*)(p))
#define GLB_U32(p) ((const __attribute__((address_space(1))) unsigned int*)(p))

__device__ __forceinline__ u16 f2bf(float f) {
    unsigned int u = __float_as_uint(f);
    u += 0x7fffu + ((u >> 16) & 1u);
    return (u16)(u >> 16);
}
__device__ __forceinline__ float bf2f(u16 s) {
    return __uint_as_float(((unsigned int)s) << 16);
}
__device__ __forceinline__ float fast_exp2(float x) {
#if __has_builtin(__builtin_amdgcn_exp2f)
    return __builtin_amdgcn_exp2f(x);
#else
    return __expf(x * 0.69314718056f);
#endif
}

// ---------------- f32 -> bf16 convert ----------------
__global__ __launch_bounds__(256) void f32_to_bf16_kernel(const float* __restrict__ in,
                                                          u16* __restrict__ o, int n) {
    int i = (blockIdx.x * 256 + threadIdx.x) << 2;
    if (i >= n) return;
    float4 f = *(const float4*)&in[i];
    u16x4 r;
    r[0] = f2bf(f.x); r[1] = f2bf(f.y); r[2] = f2bf(f.z); r[3] = f2bf(f.w);
    *(u16x4*)&o[i] = r;
}

// ---------------- W [K][N] f32 -> Wt [N][K] bf16 ----------------
__global__ __launch_bounds__(256) void transpose_w(const float* __restrict__ W,
                                                   u16* __restrict__ Wt, int K, int N) {
    __shared__ float tile[32][33];
    int nb = blockIdx.x << 5, kb = blockIdx.y << 5;
    int tx = threadIdx.x & 31, ty = threadIdx.x >> 5;
#pragma unroll
    for (int r = 0; r < 32; r += 8)
        tile[ty + r][tx] = W[(size_t)(kb + ty + r) * N + nb + tx];
    __syncthreads();
#pragma unroll
    for (int r = 0; r < 32; r += 8)
        Wt[(size_t)(nb + ty + r) * K + kb + tx] = f2bf(tile[tx][ty + r]);
}

// ============ 256x256 8-phase GEMM: C[M][N] = A[M][K] @ Bt[N][K]^T (bf16) ============
// 512 thr (8 waves 2Mx4N), BK=64, 128KiB LDS (2 buf x {A,B} x {kk0,kk1} 16KB blocks),
// XOR swizzle (staging pre-swizzles GLOBAL src, LDS dest linear — rule #21).
// RACE-FIX vs R8: vmcnt(8) at END of even phases (before final barrier) so every block
// is drained by ALL waves one phase before its first read; prologue vmcnt(8)+barrier.
// MODE 0: q/k scatter with fused RoPE + V transposed store.  MODE 1: f32 C.

#define ABLK(B, KK) ((B) * 32768 + (KK) * 8192)
#define BBLK(B, KK) ((B) * 32768 + 16384 + (KK) * 8192)

template <int MODE>
__global__ __launch_bounds__(512, 2) void gemm256(const u16* __restrict__ A,
                                                  const u16* __restrict__ Bt,
                                                  float* __restrict__ Cf,
                                                  u16* __restrict__ Qp, u16* __restrict__ Kp,
                                                  u16* __restrict__ Vtp,
                                                  int M, int N, int K) {
    __shared__ __align__(16) u16 lds[65536];  // 128 KiB
    const int tid = threadIdx.x, wave = tid >> 6, lane = tid & 63;
    const int Ntiles = N >> 8;
    const int cpx = gridDim.x >> 3;
    const int bid = (int)blockIdx.x;
    const int wg = (bid & 7) * cpx + (bid >> 3);
    const int mt = wg / Ntiles, nt = wg % Ntiles;
    const int m0 = mt << 8, n0 = nt << 8;
    const int wm = (wave >> 2) << 7, wn = (wave & 3) << 6;
    const int lr = lane & 15, lu = lane >> 4;

    const int NT = K >> 6;    // 64-wide K tiles
    const int NIT = K >> 7;   // main-loop iters (2 tiles each)

    f32x4 acc[8][4] = {};

    // staging: dest element d = l*4096 + wave*512 + lane*8 (linear) -> row = wave*16+(lane>>2)+l*128,
    // phys unit = lane&3; source unit pre-swizzled: (lane&3) ^ key, key(row) = (row>>1)&3 = (lane>>3)&3
    const int srow0 = wave * 16 + (lane >> 2);
    const int scole = (((lane & 3) ^ ((lane >> 3) & 3)) << 3);  // u16 units

#define STAGE(BLK, MAT, ROW0, KCOL)                                                           \
    {                                                                                         \
        _Pragma("unroll") for (int l = 0; l < 2; ++l) {                                       \
            const u16* src = &(MAT)[(size_t)((ROW0) + srow0 + l * 128) * K + (KCOL) + scole];  \
            __builtin_amdgcn_global_load_lds(GLB_U32(src),                                    \
                LDS_U32(&lds[(BLK) + l * 4096 + wave * 512]), 16, 0, 0);                      \
        }                                                                                     \
    }

#define LDFRAG(BLK, ROW) \
    __builtin_bit_cast(bf16x8, *(const u16x8*)&lds[(BLK) + (ROW) * 32 + ((lu ^ (((ROW) >> 1) & 3)) << 3)])

    // PHASE: ds_read frags | stage 1 block | barrier | lgkm0 | 16 MFMA | [vmcnt(8)] | barrier
#define PHASE(BUF, IH, KK, LOADB, SBLK, SMAT, SROW0, SKT, SKK, DOVM_END)                  \
    {                                                                                     \
        _Pragma("unroll") for (int ii = 0; ii < 4; ++ii) {                                \
            int row = wm + ((IH) * 4 + ii) * 16 + lr;                                     \
            af[ii] = LDFRAG(ABLK(BUF, KK), row);                                          \
        }                                                                                 \
        if (LOADB) {                                                                      \
            _Pragma("unroll") for (int j = 0; j < 4; ++j) {                               \
                int row = wn + j * 16 + lr;                                               \
                bfv[j] = LDFRAG(BBLK(BUF, KK), row);                                      \
            }                                                                             \
        }                                                                                 \
        STAGE(SBLK, SMAT, SROW0, (((SKT) & (NT - 1)) << 6) + ((SKK) << 5));               \
        asm volatile("s_barrier" ::: "memory");                                           \
        asm volatile("s_waitcnt lgkmcnt(0)" ::: "memory");                                \
        __builtin_amdgcn_sched_barrier(0);                                                \
        __builtin_amdgcn_s_setprio(1);                                                    \
        _Pragma("unroll") for (int ii = 0; ii < 4; ++ii)                                  \
            _Pragma("unroll") for (int j = 0; j < 4; ++j)                                 \
                acc[(IH) * 4 + ii][j] = __builtin_amdgcn_mfma_f32_16x16x32_bf16(          \
                    af[ii], bfv[j], acc[(IH) * 4 + ii][j], 0, 0, 0);                      \
        __builtin_amdgcn_s_setprio(0);                                                    \
        if (DOVM_END) asm volatile("s_waitcnt vmcnt(8)" ::: "memory");                    \
        asm volatile("s_barrier" ::: "memory");                                           \
    }

    // prologue: tile0 all 4 blocks -> buf0; tile1 kk0 -> buf1 (12 loads/wave);
    // drain A00,B00 (oldest 4) then barrier so iter-0 ph1 reads are safe for ALL waves.
    STAGE(ABLK(0, 0), A, m0, 0);
    STAGE(BBLK(0, 0), Bt, n0, 0);
    STAGE(ABLK(0, 1), A, m0, 32);
    STAGE(BBLK(0, 1), Bt, n0, 32);
    STAGE(ABLK(1, 0), A, m0, 64);
    STAGE(BBLK(1, 0), Bt, n0, 64);
    asm volatile("s_waitcnt vmcnt(8)" ::: "memory");
    asm volatile("s_barrier" ::: "memory");

    for (int t = 0; t < NIT; ++t) {
        const int kt = 2 * t;
        bf16x8 af[4], bfv[4];
        // buf0 = tile kt, buf1 = tile kt+1. Drain deadlines (all-wave, via end-of-even-phase
        // vmcnt(8)+barrier): ph2->A01,B01 (read ph3); ph4->A10,B10 (ph5); ph6->A11,B11 (ph7);
        // ph8->A00',B00' (next ph1). In-flight stays 8-12 loads.
        PHASE(0, 0, 0, true,  ABLK(1, 1), A,  m0, kt + 1, 1, false);  // ph1
        PHASE(0, 1, 0, false, BBLK(1, 1), Bt, n0, kt + 1, 1, true);   // ph2
        PHASE(0, 0, 1, true,  ABLK(0, 0), A,  m0, kt + 2, 0, false);  // ph3
        PHASE(0, 1, 1, false, BBLK(0, 0), Bt, n0, kt + 2, 0, true);   // ph4
        PHASE(1, 0, 0, true,  ABLK(0, 1), A,  m0, kt + 2, 1, false);  // ph5
        PHASE(1, 1, 0, false, BBLK(0, 1), Bt, n0, kt + 2, 1, true);   // ph6
        PHASE(1, 0, 1, true,  ABLK(1, 0), A,  m0, kt + 3, 0, false);  // ph7
        PHASE(1, 1, 1, false, BBLK(1, 0), Bt, n0, kt + 3, 0, true);   // ph8
    }

    if (MODE == 0) {
        const int t = (n0 + wn) >> 10;
        if (t < 2) {
            // fused RoPE on f32 accumulators; partner pairs (j, j^2).
            const float LN1E4_32 = 9.210340371976184f / 32.0f;
            const float invf0 = __expf(-(float)lr * LN1E4_32);
            const float invf1 = __expf(-(float)(lr + 16) * LN1E4_32);
#pragma unroll
            for (int i = 0; i < 8; ++i) {
                const int rbase = m0 + wm + (i << 4) + ((lane >> 4) << 2);
#pragma unroll
                for (int jj = 0; jj < 4; ++jj) {
                    const float s = (float)((rbase + jj) & (S_ - 1));
                    float sn0, c0, sn1, c1;
                    __sincosf(s * invf0, &sn0, &c0);
                    __sincosf(s * invf1, &sn1, &c1);
                    const float v0 = acc[i][0][jj], v1 = acc[i][1][jj];
                    const float v2 = acc[i][2][jj], v3 = acc[i][3][jj];
                    acc[i][0][jj] = v0 * c0 - v2 * sn0;
                    acc[i][2][jj] = v2 * c0 + v0 * sn0;
                    acc[i][1][jj] = v1 * c1 - v3 * sn1;
                    acc[i][3][jj] = v3 * c1 + v1 * sn1;
                }
            }
            u16* P = (t == 0) ? Qp : Kp;
#pragma unroll
            for (int i = 0; i < 8; ++i) {
#pragma unroll
                for (int j = 0; j < 4; ++j) {
                    int rbase = m0 + wm + (i << 4) + ((lane >> 4) << 2);
                    int col = n0 + wn + (j << 4) + lr;
                    int h = (col & 1023) >> 6, d = col & 63;
#pragma unroll
                    for (int jj = 0; jj < 4; ++jj) {
                        int row = rbase + jj;
                        int b = row >> 11, s = row & 2047;
                        P[((size_t)((b << 4) + h) * S_ + s) * 64 + d] = f2bf(acc[i][j][jj]);
                    }
                }
            }
        } else {
            // V: write transposed vt[bh][d][s], 4 consecutive s -> one u16x4 store
#pragma unroll
            for (int i = 0; i < 8; ++i) {
                const int rbase = m0 + wm + (i << 4) + ((lane >> 4) << 2);
                const int b = rbase >> 11, sb = rbase & 2047;
#pragma unroll
                for (int j = 0; j < 4; ++j) {
                    int col = n0 + wn + (j << 4) + lr;
                    int h = (col & 1023) >> 6, d = col & 63;
                    u16x4 pk;
#pragma unroll
                    for (int jj = 0; jj < 4; ++jj) pk[jj] = f2bf(acc[i][j][jj]);
                    *(u16x4*)&Vtp[((size_t)((b << 4) + h) * 64 + d) * S_ + sb] = pk;
                }
            }
        }
    } else {
#pragma unroll
        for (int i = 0; i < 8; ++i)
#pragma unroll
            for (int j = 0; j < 4; ++j) {
                int rbase = m0 + wm + (i << 4) + ((lane >> 4) << 2);
                int col = n0 + wn + (j << 4) + lr;
#pragma unroll
                for (int jj = 0; jj < 4; ++jj)
                    Cf[(size_t)(rbase + jj) * N + col] = acc[i][j][jj];
            }
    }
#undef PHASE
#undef LDFRAG
#undef STAGE
}

// ---------------- online-softmax helper (unchanged) ----------------
__device__ __forceinline__ void softmax_chain(f32x16* p, f32x16* acc, f32x16& accS,
                                              float& m_run, u32* wa, u32* wb,
                                              const float* madd_tile, bool hasmask,
                                              float* bcast_w, int c, int hi) {
    if (hasmask) {
#pragma unroll
        for (int tt = 0; tt < 2; ++tt)
#pragma unroll
            for (int rq = 0; rq < 4; ++rq) {
                float4 mf = *(const float4*)&madd_tile[tt * 32 + rq * 8 + hi * 4];
                p[tt][4 * rq + 0] += mf.x;
                p[tt][4 * rq + 1] += mf.y;
                p[tt][4 * rq + 2] += mf.z;
                p[tt][4 * rq + 3] += mf.w;
            }
    }

    float tm[16];
#pragma unroll
    for (int r = 0; r < 16; ++r) tm[r] = fmaxf(p[0][r], p[1][r]);
    float a0 = fmaxf(fmaxf(tm[0], tm[1]), tm[2]);
    float a1 = fmaxf(fmaxf(tm[3], tm[4]), tm[5]);
    float a2 = fmaxf(fmaxf(tm[6], tm[7]), tm[8]);
    float a3 = fmaxf(fmaxf(tm[9], tm[10]), tm[11]);
    float a4 = fmaxf(fmaxf(tm[12], tm[13]), tm[14]);
    float b0 = fmaxf(fmaxf(a0, a1), a2);
    float b1 = fmaxf(fmaxf(a3, a4), tm[15]);
    float mx = fmaxf(b0, b1);
    {
        i32x2 mm = __builtin_amdgcn_permlane32_swap(__float_as_int(mx), __float_as_int(mx), false, false);
        mx = fmaxf(__int_as_float(mm[0]), __int_as_float(mm[1]));
    }

    if (!__all(mx - m_run <= 8.0f)) {
        float mnew = fmaxf(m_run, mx);
        float alpha = fast_exp2(m_run - mnew);
        m_run = mnew;
        bcast_w[c] = alpha;
        float avf[16];
#pragma unroll
        for (int rq = 0; rq < 4; ++rq) {
            float4 t4 = *(const float4*)&bcast_w[rq * 8 + hi * 4];
            avf[4 * rq + 0] = t4.x; avf[4 * rq + 1] = t4.y;
            avf[4 * rq + 2] = t4.z; avf[4 * rq + 3] = t4.w;
        }
#pragma unroll
        for (int r = 0; r < 16; ++r) {
            acc[0][r] *= avf[r];
            acc[1][r] *= avf[r];
            accS[r]   *= avf[r];
        }
    }

#pragma unroll
    for (int tt = 0; tt < 2; ++tt)
#pragma unroll
        for (int r = 0; r < 16; ++r)
            p[tt][r] = fast_exp2(p[tt][r] - m_run);

#pragma unroll
    for (int tt = 0; tt < 2; ++tt)
#pragma unroll
        for (int rq = 0; rq < 4; ++rq) {
            float e0 = p[tt][4 * rq + 0], e1 = p[tt][4 * rq + 1];
            float e2 = p[tt][4 * rq + 2], e3 = p[tt][4 * rq + 3];
            u32 w0, w1;
            asm("v_cvt_pk_bf16_f32 %0, %1, %2" : "=v"(w0) : "v"(e0), "v"(e1));
            asm("v_cvt_pk_bf16_f32 %0, %1, %2" : "=v"(w1) : "v"(e2), "v"(e3));
            wa[4 * tt + rq] = w0;
            wb[4 * tt + rq] = w1;
        }
}

// ---------------- flash attention (unchanged) ----------------
__global__ __launch_bounds__(256, 2) void attn_kernel(const u16* __restrict__ q,
                                                      const u16* __restrict__ k,
                                                      const u16* __restrict__ vt,
                                                      const float* __restrict__ mask,
                                                      u16* __restrict__ outp) {
    __shared__ __align__(16) u16 Kl[2][64 * 64];
    __shared__ __align__(16) u16 Vl[2][64 * 64];
    __shared__ float madd2[2][64];
    __shared__ float bcast[4][32];

    const int tid = threadIdx.x, wave = tid >> 6, lane = tid & 63;
    const int c = lane & 31, hi = lane >> 5, c7 = c & 7;
    const int bh = blockIdx.x & 63, qt = blockIdx.x >> 6;
    const int b = bh >> 4, h = bh & 15;
    const size_t base = (size_t)bh * (S_ * 64);
    const int qrowA = (qt << 8) + (wave << 5) + c;
    const int qrowB = qrowA + 128;

    const float QS = 0.18033688f;

    bf16x8 qfA[4], qfB[4];
#pragma unroll
    for (int j = 0; j < 4; ++j) {
        u16x8 rawA = *(const u16x8*)&q[base + (size_t)qrowA * 64 + j * 16 + hi * 8];
        u16x8 rawB = *(const u16x8*)&q[base + (size_t)qrowB * 64 + j * 16 + hi * 8];
        u16x8 scA, scB;
#pragma unroll
        for (int e = 0; e < 8; ++e) {
            scA[e] = f2bf(bf2f(rawA[e]) * QS);
            scB[e] = f2bf(bf2f(rawB[e]) * QS);
        }
        qfA[j] = __builtin_bit_cast(bf16x8, scA);
        qfB[j] = __builtin_bit_cast(bf16x8, scB);
    }

    u16x8 ou;
#pragma unroll
    for (int e = 0; e < 8; ++e) ou[e] = 0x3F80;
    const bf16x8 onesf = __builtin_bit_cast(bf16x8, ou);

    f32x16 accA[2] = {}, accB[2] = {};
    f32x16 accSA = {}, accSB = {};
    float m_runA = -1e30f, m_runB = -1e30f;

    const int sr = tid >> 2, su = (tid & 3) << 1;
    const int so0 = sr * 64 + ((su ^ (sr & 7)) << 3);
    const int so1 = sr * 64 + (((su + 1) ^ (sr & 7)) << 3);

    u16x8 kc0 = *(const u16x8*)&k[base + (size_t)sr * 64 + su * 8];
    u16x8 kc1 = *(const u16x8*)&k[base + (size_t)sr * 64 + su * 8 + 8];
    u16x8 vc0 = *(const u16x8*)&vt[base + (size_t)sr * S_ + su * 8];
    u16x8 vc1 = *(const u16x8*)&vt[base + (size_t)sr * S_ + su * 8 + 8];
    float mval = (tid < 64) ? mask[b * S_ + tid] : 1.0f;

    for (int t = 0; t < 32; ++t) {
        const int bi = t & 1;
        u16* Kb = &Kl[bi][0];
        u16* Vb = &Vl[bi][0];
        *(u16x8*)&Kb[so0] = kc0;
        *(u16x8*)&Kb[so1] = kc1;
        *(u16x8*)&Vb[so0] = vc0;
        *(u16x8*)&Vb[so1] = vc1;
        if (tid < 64) madd2[bi][tid] = (1.0f - mval) * -1.44269504e9f;
        if (t + 1 < 32) {
            const int kn = (t + 1) << 6;
            kc0 = *(const u16x8*)&k[base + (size_t)(kn + sr) * 64 + su * 8];
            kc1 = *(const u16x8*)&k[base + (size_t)(kn + sr) * 64 + su * 8 + 8];
            vc0 = *(const u16x8*)&vt[base + (size_t)sr * S_ + kn + su * 8];
            vc1 = *(const u16x8*)&vt[base + (size_t)sr * S_ + kn + su * 8 + 8];
            mval = (tid < 64) ? mask[b * S_ + kn + tid] : 1.0f;
        }
        __syncthreads();

        f32x16 pA[2] = {}, pB[2] = {};
        __builtin_amdgcn_s_setprio(1);
#pragma unroll
        for (int j = 0; j < 4; ++j) {
            const int uo = ((2 * j + hi) ^ c7) << 3;
            bf16x8 ka  = __builtin_bit_cast(bf16x8, *(const u16x8*)&Kb[c * 64 + uo]);
            bf16x8 kb2 = __builtin_bit_cast(bf16x8, *(const u16x8*)&Kb[(32 + c) * 64 + uo]);
            pA[0] = __builtin_amdgcn_mfma_f32_32x32x16_bf16(ka,  qfA[j], pA[0], 0, 0, 0);
            pA[1] = __builtin_amdgcn_mfma_f32_32x32x16_bf16(kb2, qfA[j], pA[1], 0, 0, 0);
            pB[0] = __builtin_amdgcn_mfma_f32_32x32x16_bf16(ka,  qfB[j], pB[0], 0, 0, 0);
            pB[1] = __builtin_amdgcn_mfma_f32_32x32x16_bf16(kb2, qfB[j], pB[1], 0, 0, 0);
        }
        __builtin_amdgcn_s_setprio(0);

        bool hasmask = __any(madd2[bi][lane] != 0.0f);

        u32 waA[8], wbA[8], waB[8], wbB[8];
        softmax_chain(pA, accA, accSA, m_runA, waA, wbA, &madd2[bi][0], hasmask, &bcast[wave][0], c, hi);
        softmax_chain(pB, accB, accSB, m_runB, waB, wbB, &madd2[bi][0], hasmask, &bcast[wave][0], c, hi);

        __builtin_amdgcn_s_setprio(1);
#pragma unroll
        for (int ks = 0; ks < 4; ++ks) {
            i32x2 raA = __builtin_amdgcn_permlane32_swap((int)waA[2 * ks], (int)waA[2 * ks + 1], false, false);
            i32x2 rbA = __builtin_amdgcn_permlane32_swap((int)wbA[2 * ks], (int)wbA[2 * ks + 1], false, false);
            i32x2 raB = __builtin_amdgcn_permlane32_swap((int)waB[2 * ks], (int)waB[2 * ks + 1], false, false);
            i32x2 rbB = __builtin_amdgcn_permlane32_swap((int)wbB[2 * ks], (int)wbB[2 * ks + 1], false, false);
            u32x4 pwA, pwB;
            pwA[0] = (u32)raA[0]; pwA[1] = (u32)rbA[0]; pwA[2] = (u32)raA[1]; pwA[3] = (u32)rbA[1];
            pwB[0] = (u32)raB[0]; pwB[1] = (u32)rbB[0]; pwB[2] = (u32)raB[1]; pwB[3] = (u32)rbB[1];
            bf16x8 pafA = __builtin_bit_cast(bf16x8, pwA);
            bf16x8 pafB = __builtin_bit_cast(bf16x8, pwB);
            accSA = __builtin_amdgcn_mfma_f32_32x32x16_bf16(pafA, onesf, accSA, 0, 0, 0);
            accSB = __builtin_amdgcn_mfma_f32_32x32x16_bf16(pafB, onesf, accSB, 0, 0, 0);
            const int uo = ((2 * ks + hi) ^ c7) << 3;
#pragma unroll
            for (int dt = 0; dt < 2; ++dt) {
                bf16x8 vf = __builtin_bit_cast(bf16x8,
                            *(const u16x8*)&Vb[(32 * dt + c) * 64 + uo]);
                accA[dt] = __builtin_amdgcn_mfma_f32_32x32x16_bf16(pafA, vf, accA[dt], 0, 0, 0);
                accB[dt] = __builtin_amdgcn_mfma_f32_32x32x16_bf16(pafB, vf, accB[dt], 0, 0, 0);
            }
        }
        __builtin_amdgcn_s_setprio(0);
    }

    {
        const size_t orow0 = (size_t)b * S_ + (qt << 8) + (wave << 5);
#pragma unroll
        for (int dt = 0; dt < 2; ++dt)
#pragma unroll
            for (int r = 0; r < 16; ++r) {
                int qr = (r & 3) + 8 * (r >> 2) + 4 * hi;
                outp[(orow0 + qr) * DM + h * 64 + dt * 32 + c] =
                    f2bf(accA[dt][r] * __builtin_amdgcn_rcpf(accSA[r]));
            }
    }
    {
        const size_t orow0 = (size_t)b * S_ + (qt << 8) + (wave << 5) + 128;
#pragma unroll
        for (int dt = 0; dt < 2; ++dt)
#pragma unroll
            for (int r = 0; r < 16; ++r) {
                int qr = (r & 3) + 8 * (r >> 2) + 4 * hi;
                outp[(orow0 + qr) * DM + h * 64 + dt * 32 + c] =
                    f2bf(accB[dt][r] * __builtin_amdgcn_rcpf(accSB[r]));
            }
    }
}

extern "C" void kernel_launch(void* const* d_in, const int* in_sizes, int n_in,
                              void* d_out, int out_size, void* d_ws, size_t ws_size,
                              hipStream_t stream) {
    const float* x    = (const float*)d_in[0];
    const float* mask = (const float*)d_in[1];
    const float* Wqkv = (const float*)d_in[2];
    const float* Wout = (const float*)d_in[3];
    float* out = (float*)d_out;
    char* ws = (char*)d_ws;
    const size_t MB = 1u << 20;
    u16* xb    = (u16*)(ws);            // 16 MB: x bf16; reused as attn-out after gemm0
    u16* WqkvT = (u16*)(ws + 16 * MB);  // 6 MB
    u16* WoutT = (u16*)(ws + 22 * MB);  // 2 MB
    u16* qb    = (u16*)(ws + 24 * MB);  // 16 MB [bh][s][64]
    u16* kb    = (u16*)(ws + 40 * MB);  // 16 MB [bh][s][64]
    u16* vtb   = (u16*)(ws + 56 * MB);  // 16 MB [bh][64][s] (written directly by gemm0)
    u16* ao    = xb;

    f32_to_bf16_kernel<<<8192, 256, 0, stream>>>(x, xb, 8192 * 1024);
    transpose_w<<<dim3(96, 32), 256, 0, stream>>>(Wqkv, WqkvT, 1024, 3072);
    transpose_w<<<dim3(32, 32), 256, 0, stream>>>(Wout, WoutT, 1024, 1024);
    gemm256<0><<<32 * 12, 512, 0, stream>>>(xb, WqkvT, nullptr, qb, kb, vtb, 8192, 3072, 1024);
    attn_kernel<<<512, 256, 0, stream>>>(qb, kb, vtb, mask, ao);
    gemm256<1><<<32 * 4, 512, 0, stream>>>(ao, WoutT, out, nullptr, nullptr, nullptr, 8192, 1024, 1024);
}

// Round 11
// 204.905 us; speedup vs baseline: 1.7796x; 1.0285x over previous
//
#include <hip/hip_runtime.h>

typedef unsigned short u16;
typedef unsigned int u32;
typedef int i32x2 __attribute__((ext_vector_type(2)));
typedef float f32x4 __attribute__((ext_vector_type(4)));
typedef float f32x16 __attribute__((ext_vector_type(16)));
typedef __bf16 bf16x8 __attribute__((ext_vector_type(8)));
typedef unsigned short u16x8 __attribute__((ext_vector_type(8)));
typedef unsigned short u16x4 __attribute__((ext_vector_type(4)));
typedef unsigned int u32x4 __attribute__((ext_vector_type(4)));

#define S_ 2048
#define DM 1024

#define LDS_U32(p) ((__attribute__((address_space(3))) unsigned int*)(p))
#define GLB_U32(p) ((const __attribute__((address_space(1))) unsigned int*)(p))

__device__ __forceinline__ u16 f2bf(float f) {
    unsigned int u = __float_as_uint(f);
    u += 0x7fffu + ((u >> 16) & 1u);
    return (u16)(u >> 16);
}
__device__ __forceinline__ float bf2f(u16 s) {
    return __uint_as_float(((unsigned int)s) << 16);
}
__device__ __forceinline__ float fast_exp2(float x) {
#if __has_builtin(__builtin_amdgcn_exp2f)
    return __builtin_amdgcn_exp2f(x);
#else
    return __expf(x * 0.69314718056f);
#endif
}

// ---------------- f32 -> bf16 convert ----------------
__global__ __launch_bounds__(256) void f32_to_bf16_kernel(const float* __restrict__ in,
                                                          u16* __restrict__ o, int n) {
    int i = (blockIdx.x * 256 + threadIdx.x) << 2;
    if (i >= n) return;
    float4 f = *(const float4*)&in[i];
    u16x4 r;
    r[0] = f2bf(f.x); r[1] = f2bf(f.y); r[2] = f2bf(f.z); r[3] = f2bf(f.w);
    *(u16x4*)&o[i] = r;
}

// ---------------- W [K][N] f32 -> Wt [N][K] bf16 ----------------
__global__ __launch_bounds__(256) void transpose_w(const float* __restrict__ W,
                                                   u16* __restrict__ Wt, int K, int N) {
    __shared__ float tile[32][33];
    int nb = blockIdx.x << 5, kb = blockIdx.y << 5;
    int tx = threadIdx.x & 31, ty = threadIdx.x >> 5;
#pragma unroll
    for (int r = 0; r < 32; r += 8)
        tile[ty + r][tx] = W[(size_t)(kb + ty + r) * N + nb + tx];
    __syncthreads();
#pragma unroll
    for (int r = 0; r < 32; r += 8)
        Wt[(size_t)(nb + ty + r) * K + kb + tx] = f2bf(tile[tx][ty + r]);
}

// ============ 128x256 4-phase GEMM: C[M][N] = A[M][K] @ Bt[N][K]^T (bf16) ============
// 512 thr (8 waves 2Mx4N, 64x64 out each), BK=64, 96 KiB LDS (2buf x {A 8KB, B 16KB} x 2kk).
// Grid geometry fix vs R10's 256^2: gemm0 = 64x12 = 768 blocks = 3 FULL rounds @1 block/CU
// (was 384 = 1.5 rounds, 25% idle); gemm1 = 64x4 = 256 = 1 full round (was 128 = half chip).
// Uniform pipeline: every phase stages 3 loads (A:1, B:2) and drains 3 via vmcnt(6) AFTER
// MFMA, before the phase-final barrier -> each block all-wave-drained one phase before read.
// MODE 0: q/k scatter with fused RoPE + V transposed store.  MODE 1: f32 C.

#define ABLK(B, KK) ((B) * 24576 + (KK) * 4096)
#define BBLK(B, KK) ((B) * 24576 + 8192 + (KK) * 8192)

template <int MODE>
__global__ __launch_bounds__(512, 2) void gemm256(const u16* __restrict__ A,
                                                  const u16* __restrict__ Bt,
                                                  float* __restrict__ Cf,
                                                  u16* __restrict__ Qp, u16* __restrict__ Kp,
                                                  u16* __restrict__ Vtp,
                                                  int M, int N, int K) {
    __shared__ __align__(16) u16 lds[49152];  // 96 KiB
    const int tid = threadIdx.x, wave = tid >> 6, lane = tid & 63;
    const int Ntiles = N >> 8;
    const int cpx = gridDim.x >> 3;
    const int bid = (int)blockIdx.x;
    const int wg = (bid & 7) * cpx + (bid >> 3);
    const int mt = wg / Ntiles, nt = wg % Ntiles;
    const int m0 = mt << 7, n0 = nt << 8;
    const int wm = (wave >> 2) << 6, wn = (wave & 3) << 6;
    const int lr = lane & 15, lu = lane >> 4;

    const int NT = K >> 6;    // 64-wide K tiles
    const int NIT = K >> 7;   // main-loop iters (2 tiles each)

    f32x4 acc[4][4] = {};

    // staging: dest elem d = (l*4096) + wave*512 + lane*8 (linear) -> row = wave*16+(lane>>2)+l*128;
    // phys unit lane&3 holds logical unit (lane&3)^key(row), key = (row>>1)&3 = (lane>>3)&3
    const int srow0 = wave * 16 + (lane >> 2);
    const int scole = (((lane & 3) ^ ((lane >> 3) & 3)) << 3);  // u16 units

#define STAGE_A(BLK, KCOL)                                                                \
    {                                                                                     \
        const u16* src = &A[(size_t)(m0 + srow0) * K + (KCOL) + scole];                   \
        __builtin_amdgcn_global_load_lds(GLB_U32(src),                                    \
            LDS_U32(&lds[(BLK) + wave * 512]), 16, 0, 0);                                 \
    }
#define STAGE_B(BLK, KCOL)                                                                \
    {                                                                                     \
        _Pragma("unroll") for (int l = 0; l < 2; ++l) {                                   \
            const u16* src = &Bt[(size_t)(n0 + srow0 + l * 128) * K + (KCOL) + scole];    \
            __builtin_amdgcn_global_load_lds(GLB_U32(src),                                \
                LDS_U32(&lds[(BLK) + l * 4096 + wave * 512]), 16, 0, 0);                  \
        }                                                                                 \
    }

#define LDFRAG(BLK, ROW) \
    __builtin_bit_cast(bf16x8, *(const u16x8*)&lds[(BLK) + (ROW) * 32 + ((lu ^ (((ROW) >> 1) & 3)) << 3)])

    // PHASE: 8 ds_read frags | stage A+B of (SBUF,SKK)<-tile SKT | barrier | lgkm0 |
    //        16 MFMA | vmcnt(6) | barrier
#define PHASE(BUF, KK, SBUF, SKK, SKT)                                                    \
    {                                                                                     \
        _Pragma("unroll") for (int ii = 0; ii < 4; ++ii)                                  \
            af[ii] = LDFRAG(ABLK(BUF, KK), wm + ii * 16 + lr);                            \
        _Pragma("unroll") for (int j = 0; j < 4; ++j)                                     \
            bfv[j] = LDFRAG(BBLK(BUF, KK), wn + j * 16 + lr);                             \
        {                                                                                 \
            const int kcol = (((SKT) & (NT - 1)) << 6) + ((SKK) << 5);                    \
            STAGE_A(ABLK(SBUF, SKK), kcol);                                               \
            STAGE_B(BBLK(SBUF, SKK), kcol);                                               \
        }                                                                                 \
        asm volatile("s_barrier" ::: "memory");                                           \
        asm volatile("s_waitcnt lgkmcnt(0)" ::: "memory");                                \
        __builtin_amdgcn_sched_barrier(0);                                                \
        __builtin_amdgcn_s_setprio(1);                                                    \
        _Pragma("unroll") for (int ii = 0; ii < 4; ++ii)                                  \
            _Pragma("unroll") for (int j = 0; j < 4; ++j)                                 \
                acc[ii][j] = __builtin_amdgcn_mfma_f32_16x16x32_bf16(                     \
                    af[ii], bfv[j], acc[ii][j], 0, 0, 0);                                 \
        __builtin_amdgcn_s_setprio(0);                                                    \
        asm volatile("s_waitcnt vmcnt(6)" ::: "memory");                                  \
        asm volatile("s_barrier" ::: "memory");                                           \
    }

    // prologue: 9 loads -> drain oldest 3 (A00,B00) -> barrier. Iter-0 P1 reads are safe.
    STAGE_A(ABLK(0, 0), 0);
    STAGE_B(BBLK(0, 0), 0);
    STAGE_A(ABLK(0, 1), 32);
    STAGE_B(BBLK(0, 1), 32);
    STAGE_A(ABLK(1, 0), 64);
    STAGE_B(BBLK(1, 0), 64);
    asm volatile("s_waitcnt vmcnt(6)" ::: "memory");
    asm volatile("s_barrier" ::: "memory");

    for (int t = 0; t < NIT; ++t) {
        const int kt = 2 * t;
        bf16x8 af[4], bfv[4];
        // drains (end-of-phase, all-wave): P1->A01,B01 (read P2); P2->A10,B10 (P3);
        // P3->A11,B11 (P4); P4->A00',B00' (next P1). In-flight 6-9, never 0.
        PHASE(0, 0, 1, 1, kt + 1);  // P1
        PHASE(0, 1, 0, 0, kt + 2);  // P2
        PHASE(1, 0, 0, 1, kt + 2);  // P3
        PHASE(1, 1, 1, 0, kt + 3);  // P4
    }

    if (MODE == 0) {
        const int t = (n0 + wn) >> 10;
        if (t < 2) {
            // fused RoPE on f32 accumulators; partner pairs (j, j^2).
            const float LN1E4_32 = 9.210340371976184f / 32.0f;
            const float invf0 = __expf(-(float)lr * LN1E4_32);
            const float invf1 = __expf(-(float)(lr + 16) * LN1E4_32);
#pragma unroll
            for (int i = 0; i < 4; ++i) {
                const int rbase = m0 + wm + (i << 4) + ((lane >> 4) << 2);
#pragma unroll
                for (int jj = 0; jj < 4; ++jj) {
                    const float s = (float)((rbase + jj) & (S_ - 1));
                    float sn0, c0, sn1, c1;
                    __sincosf(s * invf0, &sn0, &c0);
                    __sincosf(s * invf1, &sn1, &c1);
                    const float v0 = acc[i][0][jj], v1 = acc[i][1][jj];
                    const float v2 = acc[i][2][jj], v3 = acc[i][3][jj];
                    acc[i][0][jj] = v0 * c0 - v2 * sn0;
                    acc[i][2][jj] = v2 * c0 + v0 * sn0;
                    acc[i][1][jj] = v1 * c1 - v3 * sn1;
                    acc[i][3][jj] = v3 * c1 + v1 * sn1;
                }
            }
            u16* P = (t == 0) ? Qp : Kp;
#pragma unroll
            for (int i = 0; i < 4; ++i) {
#pragma unroll
                for (int j = 0; j < 4; ++j) {
                    int rbase = m0 + wm + (i << 4) + ((lane >> 4) << 2);
                    int col = n0 + wn + (j << 4) + lr;
                    int h = (col & 1023) >> 6, d = col & 63;
#pragma unroll
                    for (int jj = 0; jj < 4; ++jj) {
                        int row = rbase + jj;
                        int b = row >> 11, s = row & 2047;
                        P[((size_t)((b << 4) + h) * S_ + s) * 64 + d] = f2bf(acc[i][j][jj]);
                    }
                }
            }
        } else {
            // V: write transposed vt[bh][d][s], 4 consecutive s -> one u16x4 store
#pragma unroll
            for (int i = 0; i < 4; ++i) {
                const int rbase = m0 + wm + (i << 4) + ((lane >> 4) << 2);
                const int b = rbase >> 11, sb = rbase & 2047;
#pragma unroll
                for (int j = 0; j < 4; ++j) {
                    int col = n0 + wn + (j << 4) + lr;
                    int h = (col & 1023) >> 6, d = col & 63;
                    u16x4 pk;
#pragma unroll
                    for (int jj = 0; jj < 4; ++jj) pk[jj] = f2bf(acc[i][j][jj]);
                    *(u16x4*)&Vtp[((size_t)((b << 4) + h) * 64 + d) * S_ + sb] = pk;
                }
            }
        }
    } else {
#pragma unroll
        for (int i = 0; i < 4; ++i)
#pragma unroll
            for (int j = 0; j < 4; ++j) {
                int rbase = m0 + wm + (i << 4) + ((lane >> 4) << 2);
                int col = n0 + wn + (j << 4) + lr;
#pragma unroll
                for (int jj = 0; jj < 4; ++jj)
                    Cf[(size_t)(rbase + jj) * N + col] = acc[i][j][jj];
            }
    }
#undef PHASE
#undef LDFRAG
#undef STAGE_B
#undef STAGE_A
}

// ---------------- online-softmax helper (unchanged) ----------------
__device__ __forceinline__ void softmax_chain(f32x16* p, f32x16* acc, f32x16& accS,
                                              float& m_run, u32* wa, u32* wb,
                                              const float* madd_tile, bool hasmask,
                                              float* bcast_w, int c, int hi) {
    if (hasmask) {
#pragma unroll
        for (int tt = 0; tt < 2; ++tt)
#pragma unroll
            for (int rq = 0; rq < 4; ++rq) {
                float4 mf = *(const float4*)&madd_tile[tt * 32 + rq * 8 + hi * 4];
                p[tt][4 * rq + 0] += mf.x;
                p[tt][4 * rq + 1] += mf.y;
                p[tt][4 * rq + 2] += mf.z;
                p[tt][4 * rq + 3] += mf.w;
            }
    }

    float tm[16];
#pragma unroll
    for (int r = 0; r < 16; ++r) tm[r] = fmaxf(p[0][r], p[1][r]);
    float a0 = fmaxf(fmaxf(tm[0], tm[1]), tm[2]);
    float a1 = fmaxf(fmaxf(tm[3], tm[4]), tm[5]);
    float a2 = fmaxf(fmaxf(tm[6], tm[7]), tm[8]);
    float a3 = fmaxf(fmaxf(tm[9], tm[10]), tm[11]);
    float a4 = fmaxf(fmaxf(tm[12], tm[13]), tm[14]);
    float b0 = fmaxf(fmaxf(a0, a1), a2);
    float b1 = fmaxf(fmaxf(a3, a4), tm[15]);
    float mx = fmaxf(b0, b1);
    {
        i32x2 mm = __builtin_amdgcn_permlane32_swap(__float_as_int(mx), __float_as_int(mx), false, false);
        mx = fmaxf(__int_as_float(mm[0]), __int_as_float(mm[1]));
    }

    if (!__all(mx - m_run <= 8.0f)) {
        float mnew = fmaxf(m_run, mx);
        float alpha = fast_exp2(m_run - mnew);
        m_run = mnew;
        bcast_w[c] = alpha;
        float avf[16];
#pragma unroll
        for (int rq = 0; rq < 4; ++rq) {
            float4 t4 = *(const float4*)&bcast_w[rq * 8 + hi * 4];
            avf[4 * rq + 0] = t4.x; avf[4 * rq + 1] = t4.y;
            avf[4 * rq + 2] = t4.z; avf[4 * rq + 3] = t4.w;
        }
#pragma unroll
        for (int r = 0; r < 16; ++r) {
            acc[0][r] *= avf[r];
            acc[1][r] *= avf[r];
            accS[r]   *= avf[r];
        }
    }

#pragma unroll
    for (int tt = 0; tt < 2; ++tt)
#pragma unroll
        for (int r = 0; r < 16; ++r)
            p[tt][r] = fast_exp2(p[tt][r] - m_run);

#pragma unroll
    for (int tt = 0; tt < 2; ++tt)
#pragma unroll
        for (int rq = 0; rq < 4; ++rq) {
            float e0 = p[tt][4 * rq + 0], e1 = p[tt][4 * rq + 1];
            float e2 = p[tt][4 * rq + 2], e3 = p[tt][4 * rq + 3];
            u32 w0, w1;
            asm("v_cvt_pk_bf16_f32 %0, %1, %2" : "=v"(w0) : "v"(e0), "v"(e1));
            asm("v_cvt_pk_bf16_f32 %0, %1, %2" : "=v"(w1) : "v"(e2), "v"(e3));
            wa[4 * tt + rq] = w0;
            wb[4 * tt + rq] = w1;
        }
}

// ---------------- flash attention (unchanged) ----------------
__global__ __launch_bounds__(256, 2) void attn_kernel(const u16* __restrict__ q,
                                                      const u16* __restrict__ k,
                                                      const u16* __restrict__ vt,
                                                      const float* __restrict__ mask,
                                                      u16* __restrict__ outp) {
    __shared__ __align__(16) u16 Kl[2][64 * 64];
    __shared__ __align__(16) u16 Vl[2][64 * 64];
    __shared__ float madd2[2][64];
    __shared__ float bcast[4][32];

    const int tid = threadIdx.x, wave = tid >> 6, lane = tid & 63;
    const int c = lane & 31, hi = lane >> 5, c7 = c & 7;
    const int bh = blockIdx.x & 63, qt = blockIdx.x >> 6;
    const int b = bh >> 4, h = bh & 15;
    const size_t base = (size_t)bh * (S_ * 64);
    const int qrowA = (qt << 8) + (wave << 5) + c;
    const int qrowB = qrowA + 128;

    const float QS = 0.18033688f;

    bf16x8 qfA[4], qfB[4];
#pragma unroll
    for (int j = 0; j < 4; ++j) {
        u16x8 rawA = *(const u16x8*)&q[base + (size_t)qrowA * 64 + j * 16 + hi * 8];
        u16x8 rawB = *(const u16x8*)&q[base + (size_t)qrowB * 64 + j * 16 + hi * 8];
        u16x8 scA, scB;
#pragma unroll
        for (int e = 0; e < 8; ++e) {
            scA[e] = f2bf(bf2f(rawA[e]) * QS);
            scB[e] = f2bf(bf2f(rawB[e]) * QS);
        }
        qfA[j] = __builtin_bit_cast(bf16x8, scA);
        qfB[j] = __builtin_bit_cast(bf16x8, scB);
    }

    u16x8 ou;
#pragma unroll
    for (int e = 0; e < 8; ++e) ou[e] = 0x3F80;
    const bf16x8 onesf = __builtin_bit_cast(bf16x8, ou);

    f32x16 accA[2] = {}, accB[2] = {};
    f32x16 accSA = {}, accSB = {};
    float m_runA = -1e30f, m_runB = -1e30f;

    const int sr = tid >> 2, su = (tid & 3) << 1;
    const int so0 = sr * 64 + ((su ^ (sr & 7)) << 3);
    const int so1 = sr * 64 + (((su + 1) ^ (sr & 7)) << 3);

    u16x8 kc0 = *(const u16x8*)&k[base + (size_t)sr * 64 + su * 8];
    u16x8 kc1 = *(const u16x8*)&k[base + (size_t)sr * 64 + su * 8 + 8];
    u16x8 vc0 = *(const u16x8*)&vt[base + (size_t)sr * S_ + su * 8];
    u16x8 vc1 = *(const u16x8*)&vt[base + (size_t)sr * S_ + su * 8 + 8];
    float mval = (tid < 64) ? mask[b * S_ + tid] : 1.0f;

    for (int t = 0; t < 32; ++t) {
        const int bi = t & 1;
        u16* Kb = &Kl[bi][0];
        u16* Vb = &Vl[bi][0];
        *(u16x8*)&Kb[so0] = kc0;
        *(u16x8*)&Kb[so1] = kc1;
        *(u16x8*)&Vb[so0] = vc0;
        *(u16x8*)&Vb[so1] = vc1;
        if (tid < 64) madd2[bi][tid] = (1.0f - mval) * -1.44269504e9f;
        if (t + 1 < 32) {
            const int kn = (t + 1) << 6;
            kc0 = *(const u16x8*)&k[base + (size_t)(kn + sr) * 64 + su * 8];
            kc1 = *(const u16x8*)&k[base + (size_t)(kn + sr) * 64 + su * 8 + 8];
            vc0 = *(const u16x8*)&vt[base + (size_t)sr * S_ + kn + su * 8];
            vc1 = *(const u16x8*)&vt[base + (size_t)sr * S_ + kn + su * 8 + 8];
            mval = (tid < 64) ? mask[b * S_ + kn + tid] : 1.0f;
        }
        __syncthreads();

        f32x16 pA[2] = {}, pB[2] = {};
        __builtin_amdgcn_s_setprio(1);
#pragma unroll
        for (int j = 0; j < 4; ++j) {
            const int uo = ((2 * j + hi) ^ c7) << 3;
            bf16x8 ka  = __builtin_bit_cast(bf16x8, *(const u16x8*)&Kb[c * 64 + uo]);
            bf16x8 kb2 = __builtin_bit_cast(bf16x8, *(const u16x8*)&Kb[(32 + c) * 64 + uo]);
            pA[0] = __builtin_amdgcn_mfma_f32_32x32x16_bf16(ka,  qfA[j], pA[0], 0, 0, 0);
            pA[1] = __builtin_amdgcn_mfma_f32_32x32x16_bf16(kb2, qfA[j], pA[1], 0, 0, 0);
            pB[0] = __builtin_amdgcn_mfma_f32_32x32x16_bf16(ka,  qfB[j], pB[0], 0, 0, 0);
            pB[1] = __builtin_amdgcn_mfma_f32_32x32x16_bf16(kb2, qfB[j], pB[1], 0, 0, 0);
        }
        __builtin_amdgcn_s_setprio(0);

        bool hasmask = __any(madd2[bi][lane] != 0.0f);

        u32 waA[8], wbA[8], waB[8], wbB[8];
        softmax_chain(pA, accA, accSA, m_runA, waA, wbA, &madd2[bi][0], hasmask, &bcast[wave][0], c, hi);
        softmax_chain(pB, accB, accSB, m_runB, waB, wbB, &madd2[bi][0], hasmask, &bcast[wave][0], c, hi);

        __builtin_amdgcn_s_setprio(1);
#pragma unroll
        for (int ks = 0; ks < 4; ++ks) {
            i32x2 raA = __builtin_amdgcn_permlane32_swap((int)waA[2 * ks], (int)waA[2 * ks + 1], false, false);
            i32x2 rbA = __builtin_amdgcn_permlane32_swap((int)wbA[2 * ks], (int)wbA[2 * ks + 1], false, false);
            i32x2 raB = __builtin_amdgcn_permlane32_swap((int)waB[2 * ks], (int)waB[2 * ks + 1], false, false);
            i32x2 rbB = __builtin_amdgcn_permlane32_swap((int)wbB[2 * ks], (int)wbB[2 * ks + 1], false, false);
            u32x4 pwA, pwB;
            pwA[0] = (u32)raA[0]; pwA[1] = (u32)rbA[0]; pwA[2] = (u32)raA[1]; pwA[3] = (u32)rbA[1];
            pwB[0] = (u32)raB[0]; pwB[1] = (u32)rbB[0]; pwB[2] = (u32)raB[1]; pwB[3] = (u32)rbB[1];
            bf16x8 pafA = __builtin_bit_cast(bf16x8, pwA);
            bf16x8 pafB = __builtin_bit_cast(bf16x8, pwB);
            accSA = __builtin_amdgcn_mfma_f32_32x32x16_bf16(pafA, onesf, accSA, 0, 0, 0);
            accSB = __builtin_amdgcn_mfma_f32_32x32x16_bf16(pafB, onesf, accSB, 0, 0, 0);
            const int uo = ((2 * ks + hi) ^ c7) << 3;
#pragma unroll
            for (int dt = 0; dt < 2; ++dt) {
                bf16x8 vf = __builtin_bit_cast(bf16x8,
                            *(const u16x8*)&Vb[(32 * dt + c) * 64 + uo]);
                accA[dt] = __builtin_amdgcn_mfma_f32_32x32x16_bf16(pafA, vf, accA[dt], 0, 0, 0);
                accB[dt] = __builtin_amdgcn_mfma_f32_32x32x16_bf16(pafB, vf, accB[dt], 0, 0, 0);
            }
        }
        __builtin_amdgcn_s_setprio(0);
    }

    {
        const size_t orow0 = (size_t)b * S_ + (qt << 8) + (wave << 5);
#pragma unroll
        for (int dt = 0; dt < 2; ++dt)
#pragma unroll
            for (int r = 0; r < 16; ++r) {
                int qr = (r & 3) + 8 * (r >> 2) + 4 * hi;
                outp[(orow0 + qr) * DM + h * 64 + dt * 32 + c] =
                    f2bf(accA[dt][r] * __builtin_amdgcn_rcpf(accSA[r]));
            }
    }
    {
        const size_t orow0 = (size_t)b * S_ + (qt << 8) + (wave << 5) + 128;
#pragma unroll
        for (int dt = 0; dt < 2; ++dt)
#pragma unroll
            for (int r = 0; r < 16; ++r) {
                int qr = (r & 3) + 8 * (r >> 2) + 4 * hi;
                outp[(orow0 + qr) * DM + h * 64 + dt * 32 + c] =
                    f2bf(accB[dt][r] * __builtin_amdgcn_rcpf(accSB[r]));
            }
    }
}

extern "C" void kernel_launch(void* const* d_in, const int* in_sizes, int n_in,
                              void* d_out, int out_size, void* d_ws, size_t ws_size,
                              hipStream_t stream) {
    const float* x    = (const float*)d_in[0];
    const float* mask = (const float*)d_in[1];
    const float* Wqkv = (const float*)d_in[2];
    const float* Wout = (const float*)d_in[3];
    float* out = (float*)d_out;
    char* ws = (char*)d_ws;
    const size_t MB = 1u << 20;
    u16* xb    = (u16*)(ws);            // 16 MB: x bf16; reused as attn-out after gemm0
    u16* WqkvT = (u16*)(ws + 16 * MB);  // 6 MB
    u16* WoutT = (u16*)(ws + 22 * MB);  // 2 MB
    u16* qb    = (u16*)(ws + 24 * MB);  // 16 MB [bh][s][64]
    u16* kb    = (u16*)(ws + 40 * MB);  // 16 MB [bh][s][64]
    u16* vtb   = (u16*)(ws + 56 * MB);  // 16 MB [bh][64][s] (written directly by gemm0)
    u16* ao    = xb;

    f32_to_bf16_kernel<<<8192, 256, 0, stream>>>(x, xb, 8192 * 1024);
    transpose_w<<<dim3(96, 32), 256, 0, stream>>>(Wqkv, WqkvT, 1024, 3072);
    transpose_w<<<dim3(32, 32), 256, 0, stream>>>(Wout, WoutT, 1024, 1024);
    gemm256<0><<<64 * 12, 512, 0, stream>>>(xb, WqkvT, nullptr, qb, kb, vtb, 8192, 3072, 1024);
    attn_kernel<<<512, 256, 0, stream>>>(qb, kb, vtb, mask, ao);
    gemm256<1><<<64 * 4, 512, 0, stream>>>(ao, WoutT, out, nullptr, nullptr, nullptr, 8192, 1024, 1024);
}